// Round 1
// baseline (481.070 us; speedup 1.0000x reference)
//
#include <hip/hip_runtime.h>
#include <math.h>

#define HWP 16384   // 128*128 pooled plane

// ---------------- workspace layout (float offsets) ----------------
// Lifetimes (same-stream serialization):
//   pre   [0, 12,582,912)          pool_conv -> dw3x3
//   cov   [0, ~2.12M)              mean -> simsort      (inside dead pre)
//   khat  [0, 6,553,600)           stage -> attn        (inside dead pre)
//   vpk   [6,553,600, 10,747,904)  stage -> attn        (inside dead pre)
//   out3  [0, 4,194,304)           post -> final        (staging dead)
//   tail  [12,570,112, 12,582,912) idx/inv + MLP weights, written only
//                                  after dw3x3, live through post
//   qkv   [12,582,912, 25,165,824) dw3x3 -> post; its V planes are dead
//                                  after k_stage and are overwritten IN
//                                  PLACE by k_attn's output (read by post).
static const size_t PRE_OFF  = 0;          // 12,582,912
static const size_t QKV_OFF  = 12582912;
// wT lives at the START of the QKV region: written by k_prep_wt, read only by
// k_pool_conv (which writes PRE only), then overwritten by k_dw3x3_zero.
static const size_t WT_OFF   = QKV_OFF;    // 12,288 floats
static const size_t COVP_OFF = 0;          // 2,097,152
static const size_t MEAN_OFF = 2097152;    // 256
static const size_t COVS_OFF = 2097408;    // 16,384 -> ends 2,113,792
static const size_t KHAT_OFF = 0;          // 6,553,600 (4096 tiles *100*16)
static const size_t VPK_OFF  = 6553600;    // 4,194,304 -> ends 10,747,904
static const size_t OUT3_OFF = 0;          // 4,194,304
static const size_t IDX_OFF  = 12570112;   // 256 ints
static const size_t INV_OFF  = 12570368;   // 256 ints
static const size_t GT2_OFF  = 12570624;   // 4096
static const size_t DT2_OFF  = 12574720;   // 2048
static const size_t UT2_OFF  = 12576768;   // 2048
static const size_t PT2_OFF  = 12578816;   // 4096 -> ends 12,582,912 exactly

// ---------------- 0: transpose qkv_w -> wT[c*192+o] ----------------
__global__ __launch_bounds__(256) void k_prep_wt(
    const float* __restrict__ qkv_w, float* __restrict__ wT) {
  int i = blockIdx.x * 256 + threadIdx.x;   // 12288
  int o = i >> 6, c = i & 63;
  wT[c * 192 + o] = qkv_w[i];
}

// ---------------- 0b: transpose MLP weights to d-major ----------------
__global__ __launch_bounds__(256) void k_prep2(
    const float* __restrict__ gating_w, const float* __restrict__ down_w,
    const float* __restrict__ up_w, const float* __restrict__ proj_w,
    float* __restrict__ gT, float* __restrict__ dT,
    float* __restrict__ uT, float* __restrict__ pT) {
  int t = blockIdx.x * 256 + threadIdx.x;
  if (t < 4096) {
    int o = t >> 6, d = t & 63;
    gT[d * 64 + o] = gating_w[t];
    pT[d * 64 + o] = proj_w[t];
  }
  if (t < 2048) {
    int o = t >> 6, d = t & 63;      // down_w (32,64)
    dT[d * 32 + o] = down_w[t];
    int o2 = t >> 5, d2 = t & 31;    // up_w (64,32)
    uT[d2 * 64 + o2] = up_w[t];
  }
}

// ---------------- 1: maxpool2 + conv1x1 (x -> qkv_pre) ----------------
__global__ __launch_bounds__(256) void k_pool_conv(
    const float* __restrict__ x, const float* __restrict__ wT,
    float* __restrict__ pre) {
  int b = blockIdx.x >> 8;          // 256 tiles / batch
  int pix0 = (blockIdx.x & 255) * 64;
  __shared__ float xt[64 * 64];     // [c][p]
  int t = threadIdx.x;
  for (int i = 0; i < 16; ++i) {
    int f = i * 256 + t;
    int c = f >> 6, p = f & 63;
    int pix = pix0 + p;
    int y = pix >> 7, xx = pix & 127;
    const float* src = x + ((size_t)(b * 64 + c) * 65536) + (2 * y) * 256 + 2 * xx;
    float2 v01 = *(const float2*)src;
    float2 v23 = *(const float2*)(src + 256);
    xt[c * 64 + p] = fmaxf(fmaxf(v01.x, v01.y), fmaxf(v23.x, v23.y));
  }
  __syncthreads();
  int p = t & 63;
  int obase = __builtin_amdgcn_readfirstlane((t >> 6) * 48);  // wave-uniform
  const float* wbase = wT + obase;
  float acc[48];
#pragma unroll
  for (int j = 0; j < 48; ++j) acc[j] = 0.f;
  for (int c = 0; c < 64; ++c) {
    float xv = xt[c * 64 + p];
    const float* wc = wbase + c * 192;    // uniform -> s_load_dwordx16 x3
#pragma unroll
    for (int j = 0; j < 48; ++j) acc[j] = fmaf(wc[j], xv, acc[j]);
  }
  float* dst = pre + ((size_t)b * 192 + obase) * HWP + pix0 + p;
#pragma unroll
  for (int j = 0; j < 48; ++j) dst[(size_t)j * HWP] = acc[j];
}

// ---------------- 2: depthwise 3x3, zero pad (pre -> qkv) ----------------
__global__ __launch_bounds__(256) void k_dw3x3_zero(
    const float* __restrict__ pre, const float* __restrict__ lce_w,
    float* __restrict__ qkv) {
  int gid = blockIdx.x * 256 + threadIdx.x;   // 4*192*16384 total
  int pix = gid & (HWP - 1);
  int bc = gid >> 14;
  int ch = bc % 192;
  int y = pix >> 7, xx = pix & 127;
  const float* w = lce_w + ch * 9;
  const float* base = pre + (size_t)bc * HWP;
  float acc = 0.f;
#pragma unroll
  for (int dy = -1; dy <= 1; ++dy) {
    int yy = y + dy;
    if (yy < 0 || yy > 127) continue;
#pragma unroll
    for (int dx = -1; dx <= 1; ++dx) {
      int xc = xx + dx;
      if (xc < 0 || xc > 127) continue;
      acc = fmaf(w[(dy + 1) * 3 + dx + 1], base[yy * 128 + xc], acc);
    }
  }
  qkv[gid] = acc;
}

// ---------------- 3a: per-channel mean of q ----------------
__global__ __launch_bounds__(256) void k_mean(
    const float* __restrict__ qkv, float* __restrict__ mean) {
  int bc = blockIdx.x;              // b*64 + c
  int b = bc >> 6, c = bc & 63;
  const float* src = qkv + ((size_t)b * 192 + c) * HWP;
  float s = 0.f;
  for (int i = threadIdx.x; i < HWP; i += 256) s += src[i];
  __shared__ float red[4];
  for (int off = 32; off > 0; off >>= 1) s += __shfl_down(s, off);
  int t = threadIdx.x;
  if ((t & 63) == 0) red[t >> 6] = s;
  __syncthreads();
  if (t == 0) mean[bc] = (red[0] + red[1] + red[2] + red[3]) * (1.f / 16384.f);
}

// ---------------- 3b: centered cov partials (chunks of 128) ----------------
__global__ __launch_bounds__(256) void k_covpart(
    const float* __restrict__ qkv, const float* __restrict__ mean,
    float* __restrict__ covp) {
  int blk = blockIdx.x;             // b*128 + chunk
  int b = blk >> 7, chunk = blk & 127;
  int e0 = chunk * 128;
  __shared__ float qc[64 * 129];    // +1 pad breaks stride conflicts
  int t = threadIdx.x;
  for (int i = 0; i < 32; ++i) {
    int f = i * 256 + t;
    int c = f >> 7, e = f & 127;
    qc[c * 129 + e] = qkv[((size_t)b * 192 + c) * HWP + e0 + e] - mean[b * 64 + c];
  }
  __syncthreads();
  int d = t & 63;
  int crow = t >> 6;                // wave-uniform
  float acc[16];
#pragma unroll
  for (int i = 0; i < 16; ++i) acc[i] = 0.f;
  for (int e = 0; e < 128; ++e) {
    float qd = qc[d * 129 + e];
#pragma unroll
    for (int i = 0; i < 16; ++i) {
      int c = crow + 4 * i;
      acc[i] = fmaf(qc[c * 129 + e], qd, acc[i]);
    }
  }
  float* dst = covp + (size_t)blk * 4096;
#pragma unroll
  for (int i = 0; i < 16; ++i) {
    int c = crow + 4 * i;
    dst[c * 64 + d] = acc[i];       // == dst[i*256 + t], coalesced
  }
}

// ---------------- 3b2: reduce cov partials over 128 chunks ----------------
__global__ __launch_bounds__(256) void k_covred(
    const float* __restrict__ covp, float* __restrict__ covs) {
  int blk = blockIdx.x;             // b*16 + j
  int b = blk >> 4;
  int pp = (blk & 15) * 256 + threadIdx.x;
  const float* src = covp + (size_t)b * 524288 + pp;
  float s = 0.f;
  for (int ch = 0; ch < 128; ++ch) s += src[ch * 4096];   // chunk order preserved
  covs[b * 4096 + pp] = s;
}

// ---------------- 3c: correlation-mean sim, stable rank ----------------
__global__ __launch_bounds__(256) void k_simsort(
    const float* __restrict__ covs_g, int* __restrict__ idx, int* __restrict__ inv) {
  int b = blockIdx.x;               // 4 blocks
  __shared__ float covs[4096];
  __shared__ float stds[64];
  __shared__ float sims[64];
  int t = threadIdx.x;
  for (int i = 0; i < 16; ++i) covs[i * 256 + t] = covs_g[b * 4096 + i * 256 + t];
  __syncthreads();
  if (t < 64) stds[t] = sqrtf(covs[t * 64 + t] + 1e-8f);
  __syncthreads();
  if (t < 64) {
    float s = 0.f;
    float sc = stds[t];
    for (int d2 = 0; d2 < 64; ++d2) {
      float denom = fmaxf(sc * stds[d2], 1e-8f);
      s += covs[d2 * 64 + t] / denom;   // symmetric matrix: bitwise equal to [t][d2]
    }
    sims[t] = s * (1.f / 64.f);
  }
  __syncthreads();
  if (t < 64) {
    float sv = sims[t];
    int r = 0;
    for (int d2 = 0; d2 < 64; ++d2) {
      float o = sims[d2];
      if (o > sv || (o == sv && d2 < t)) r++;
    }
    idx[b * 64 + r] = t;
    inv[b * 64 + t] = r;
  }
}

// ---------------- 6: stage K-hat (rel-added, l2-normalized) + packed V ----
// khat: [tile=bi][key 0..99][16ch]  (64B rows, wave-uniform in k_attn)
// vpk : [b*4+head][pos 0..16383][16ch] (no halo duplication; each pooled
//       position is interior to exactly one tile -> that tile writes it)
__global__ __launch_bounds__(64) void k_stage(
    const float* __restrict__ qkv, const int* __restrict__ idx,
    const float* __restrict__ rel_h, const float* __restrict__ rel_w,
    float* __restrict__ khat, float* __restrict__ vpk) {
  int bi = blockIdx.x;
  int head = bi & 3;
  int wj = (bi >> 2) & 15;
  int hi = (bi >> 6) & 15;
  int b = bi >> 10;
  int t = threadIdx.x;
  const size_t bb = (size_t)b * 192 * HWP;
  int chg[16];
#pragma unroll
  for (int ch = 0; ch < 16; ++ch) chg[ch] = idx[b * 64 + head * 16 + ch];
  // K rows: 100 halo positions
  for (int i = 0; i < 2; ++i) {
    int pos = i * 64 + t;
    if (pos < 100) {
      int py = pos / 10, px = pos - py * 10;
      int ky = hi * 8 + py - 1, kx = wj * 8 + px - 1;
      bool ok = (ky >= 0) && (ky < 128) && (kx >= 0) && (kx < 128);
      int sp = ky * 128 + kx;
      float kv[16];
      float s = 0.f;
#pragma unroll
      for (int ch = 0; ch < 16; ++ch) {
        float k = ok ? qkv[bb + (size_t)(64 + chg[ch]) * HWP + sp] : 0.f;
        k += (ch < 8) ? rel_h[(head * 10 + py) * 8 + ch]
                      : rel_w[(head * 10 + px) * 8 + (ch - 8)];
        kv[ch] = k;
        s += k * k;
      }
      float rn = 1.f / fmaxf(sqrtf(s), 1e-12f);   // ref: l2norm(k+rel) before dot
      float* kd = khat + ((size_t)bi * 100 + pos) * 16;
#pragma unroll
      for (int ch = 0; ch < 16; ++ch) kd[ch] = kv[ch] * rn;
    }
  }
  // V rows: this tile's 64 interior positions, gathered channel-packed
  int qy = hi * 8 + (t >> 3), qx = wj * 8 + (t & 7);
  int spq = qy * 128 + qx;
  float* vd = vpk + ((size_t)(b * 4 + head) * 16384 + spq) * 16;
#pragma unroll
  for (int ch = 0; ch < 16; ++ch)
    vd[ch] = qkv[bb + (size_t)(128 + chg[ch]) * HWP + spq];
}

// ---------------- 7: halo block attention + gate ----------------
// No LDS, no barriers. K/V rows are wave-uniform 64B lines -> scalar loads
// (s_load_dwordx16); SGPR operands feed v_fmac directly. Output is scattered
// IN PLACE into the dead V planes of qkv (read by k_post as attn).
__global__ __launch_bounds__(64) void k_attn(
    const float* __restrict__ qkv, const int* __restrict__ idx,
    const float* __restrict__ khat, const float* __restrict__ vpk,
    const float* __restrict__ gate_w, const float* __restrict__ gate_b,
    const float* __restrict__ temp, float* __restrict__ attn_out) {
  int bi = blockIdx.x;
  int head = bi & 3;
  int wj = (bi >> 2) & 15;
  int hi = (bi >> 6) & 15;
  int b = bi >> 10;
  int t = threadIdx.x;
  const size_t bb = (size_t)b * 192 * HWP;
  int chg[16];
#pragma unroll
  for (int ch = 0; ch < 16; ++ch) chg[ch] = idx[b * 64 + head * 16 + ch];
  int qy = hi * 8 + (t >> 3), qx = wj * 8 + (t & 7);
  float q[16];
  float qs = 0.f;
#pragma unroll
  for (int ch = 0; ch < 16; ++ch) {
    q[ch] = qkv[bb + (size_t)chg[ch] * HWP + qy * 128 + qx];
    qs += q[ch] * q[ch];
  }
  float T = expf(temp[head]);
  float qnT = T / fmaxf(sqrtf(qs), 1e-12f);
  const float* kb = khat + (size_t)bi * 1600;
  const float* vb = vpk + (size_t)(b * 4 + head) * (16384 * 16);
  float out[16];
#pragma unroll
  for (int ch = 0; ch < 16; ++ch) out[ch] = 0.f;
  float wsum = 0.f;
  for (int py = 0; py < 10; ++py) {
    int ky = hi * 8 + py - 1;
    bool oky = (ky >= 0) && (ky < 128);
    const float* kprow = kb + py * 160;
    int spy = ky * 128;
    for (int px = 0; px < 10; ++px) {
      int kx = wj * 8 + px - 1;
      bool ok = oky && (kx >= 0) && (kx < 128);
      int sp = ok ? (spy + kx) : 0;               // clamp: OOB reads row 0, masked below
      const float* kp = kprow + px * 16;          // uniform -> s_load_dwordx16
      const float* vp = vb + (size_t)sp * 16;     // uniform -> s_load_dwordx16
      float dacc = 0.f;
#pragma unroll
      for (int ch = 0; ch < 16; ++ch) dacc = fmaf(q[ch], kp[ch], dacc);
      float e = expf(fmaf(dacc, qnT, -T));        // exp(d - T): exact softmax shift
      wsum += e;                                  // OOB keys DO count in denominator
      float ev = ok ? e : 0.f;                    // ...but contribute V=0
#pragma unroll
      for (int ch = 0; ch < 16; ++ch) out[ch] = fmaf(ev, vp[ch], out[ch]);
    }
  }
  float winv = 1.f / wsum;
#pragma unroll
  for (int o = 0; o < 16; ++o) {
    float gsv = gate_b[head * 16 + o];
#pragma unroll
    for (int c = 0; c < 16; ++c)
      gsv = fmaf(gate_w[head * 256 + o * 16 + c], q[c], gsv);
    float sig = 1.f / (1.f + expf(-gsv));
    attn_out[bb + (size_t)(128 + chg[o]) * HWP + qy * 128 + qx] = out[o] * winv * sig;
  }
}

// ---------------- 8: mixed -> gating -> down -> up -> (+attn) -> proj ----
// attn now lives in the qkv V planes: channel c of batch b at
// (b*192 + 128 + c)*HWP.
__global__ __launch_bounds__(64) void k_post(
    const float* __restrict__ attn, const float* __restrict__ qkv,
    const float* __restrict__ gT, const float* __restrict__ gating_b,
    const float* __restrict__ dT, const float* __restrict__ down_b,
    const float* __restrict__ uT, const float* __restrict__ up_b,
    const float* __restrict__ pT, float* __restrict__ out3) {
  __shared__ float xs[64 * 64];     // [d][lane]
  int t = threadIdx.x;
  int p = blockIdx.x * 64 + t;      // global pooled pixel id
  int b = p >> 14;
  int pix = p & 16383;
  const float* ap = attn + ((size_t)b * 192 + 128) * HWP + pix;
  const float* qp = qkv + (size_t)b * 192 * HWP + pix;
  float* op = out3 + (size_t)b * 64 * HWP + pix;
  // mixed = attn_out + (q + k)   (cache un-permutes to q+k)
  for (int c = 0; c < 64; ++c)
    xs[c * 64 + t] = ap[(size_t)c * HWP] + qp[(size_t)c * HWP] + qp[(size_t)(64 + c) * HWP];
  // ---- gating conv + exact gelu, * mixed ----
  {
    float acc[64];
#pragma unroll
    for (int o = 0; o < 64; ++o) acc[o] = gating_b[o];
    for (int d = 0; d < 64; ++d) {
      float xv = xs[d * 64 + t];
      const float* wd = gT + d * 64;          // wave-uniform -> s_load x16
#pragma unroll
      for (int o = 0; o < 64; ++o) acc[o] = fmaf(wd[o], xv, acc[o]);
    }
#pragma unroll
    for (int o = 0; o < 64; ++o) {
      float a = acc[o];
      float ge = 0.5f * a * (1.f + erff(a * 0.70710678118654752f));
      xs[o * 64 + t] = ge * xs[o * 64 + t];
    }
  }
  // ---- down 64->32 ----
  {
    float acc[32];
#pragma unroll
    for (int o = 0; o < 32; ++o) acc[o] = down_b[o];
    for (int d = 0; d < 64; ++d) {
      float xv = xs[d * 64 + t];
      const float* wd = dT + d * 32;
#pragma unroll
      for (int o = 0; o < 32; ++o) acc[o] = fmaf(wd[o], xv, acc[o]);
    }
#pragma unroll
    for (int o = 0; o < 32; ++o) xs[o * 64 + t] = acc[o];
  }
  // ---- up 32->64, + attn residual ----
  {
    float acc[64];
#pragma unroll
    for (int o = 0; o < 64; ++o) acc[o] = up_b[o];
    for (int d = 0; d < 32; ++d) {
      float xv = xs[d * 64 + t];
      const float* wd = uT + d * 64;
#pragma unroll
      for (int o = 0; o < 64; ++o) acc[o] = fmaf(wd[o], xv, acc[o]);
    }
#pragma unroll
    for (int o = 0; o < 64; ++o) xs[o * 64 + t] = acc[o] + ap[(size_t)o * HWP];
  }
  // ---- proj (no bias) ----
  {
    float acc[64];
#pragma unroll
    for (int o = 0; o < 64; ++o) acc[o] = 0.f;
    for (int d = 0; d < 64; ++d) {
      float xv = xs[d * 64 + t];
      const float* wd = pT + d * 64;
#pragma unroll
      for (int o = 0; o < 64; ++o) acc[o] = fmaf(wd[o], xv, acc[o]);
    }
#pragma unroll
    for (int o = 0; o < 64; ++o) op[(size_t)o * HWP] = acc[o];
  }
}

// ---------------- 9: dw3x3 reflect + bias + bilinear x2 (align-corners) ----
__global__ __launch_bounds__(256) void k_final(
    const float* __restrict__ out3, const float* __restrict__ lp_w,
    const float* __restrict__ lp_b, float* __restrict__ out) {
  int bi = blockIdx.x;                 // (b*64+ch)*8 + rt
  int rt = bi & 7;
  int bc = bi >> 3;
  int ch = bc & 63;
  int r0 = rt * 16;
  __shared__ float tin[20 * 128];      // input rows r0-2 .. r0+17 (reflected)
  __shared__ float tdw[18 * 128];      // dw rows r0-1 .. r0+16
  int t = threadIdx.x;
  const float* src = out3 + (size_t)bc * HWP;
  for (int i = 0; i < 10; ++i) {
    int f = i * 256 + t;               // 2560 exactly
    int r = f >> 7, xx = f & 127;
    int ry = r0 - 2 + r;
    ry = ry < 0 ? -ry : (ry > 127 ? 254 - ry : ry);
    tin[f] = src[ry * 128 + xx];
  }
  __syncthreads();
  float w0 = lp_w[ch * 9 + 0], w1 = lp_w[ch * 9 + 1], w2 = lp_w[ch * 9 + 2];
  float w3 = lp_w[ch * 9 + 3], w4 = lp_w[ch * 9 + 4], w5 = lp_w[ch * 9 + 5];
  float w6 = lp_w[ch * 9 + 6], w7 = lp_w[ch * 9 + 7], w8 = lp_w[ch * 9 + 8];
  float bias = lp_b[ch];
  for (int i = 0; i < 9; ++i) {
    int f = i * 256 + t;               // 2304 exactly
    int r = f >> 7, xx = f & 127;
    int xm = (xx == 0) ? 1 : xx - 1;
    int xp = (xx == 127) ? 126 : xx + 1;
    const float* r0p = tin + r * 128;
    const float* r1p = r0p + 128;
    const float* r2p = r1p + 128;
    float acc = bias;
    acc = fmaf(w0, r0p[xm], acc); acc = fmaf(w1, r0p[xx], acc); acc = fmaf(w2, r0p[xp], acc);
    acc = fmaf(w3, r1p[xm], acc); acc = fmaf(w4, r1p[xx], acc); acc = fmaf(w5, r1p[xp], acc);
    acc = fmaf(w6, r2p[xm], acc); acc = fmaf(w7, r2p[xx], acc); acc = fmaf(w8, r2p[xp], acc);
    tdw[f] = acc;
  }
  __syncthreads();
  const float s = (float)(127.0 / 255.0);
  float* dst = out + (size_t)bc * 65536;
  for (int i = 0; i < 32; ++i) {
    int f = i * 256 + t;               // 8192 exactly: rows 2r0..2r0+31, cols 0..255
    int vr = f >> 8, vx = f & 255;
    int v = 2 * r0 + vr;
    float cy = (float)v * s;
    int ly = (int)floorf(cy); if (ly > 126) ly = 126;
    float wy = cy - (float)ly;
    float cx = (float)vx * s;
    int lx = (int)floorf(cx); if (lx > 126) lx = 126;
    float wx = cx - (float)lx;
    int lr = ly - r0 + 1;              // tdw row index
    float a  = tdw[lr * 128 + lx];
    float bq = tdw[lr * 128 + lx + 1];
    float c2 = tdw[(lr + 1) * 128 + lx];
    float d2 = tdw[(lr + 1) * 128 + lx + 1];
    float t0 = a  * (1.f - wy) + c2 * wy;   // y-lerp first (matches ref order)
    float t1 = bq * (1.f - wy) + d2 * wy;
    dst[v * 256 + vx] = t0 * (1.f - wx) + t1 * wx;
  }
}

extern "C" void kernel_launch(void* const* d_in, const int* in_sizes, int n_in,
                              void* d_out, int out_size, void* d_ws, size_t ws_size,
                              hipStream_t stream) {
  (void)in_sizes; (void)n_in; (void)out_size; (void)ws_size;
  const float* x        = (const float*)d_in[0];
  const float* qkv_w    = (const float*)d_in[1];
  const float* lce_w    = (const float*)d_in[2];
  const float* gate_w   = (const float*)d_in[3];
  const float* gate_b   = (const float*)d_in[4];
  const float* temp     = (const float*)d_in[5];
  const float* rel_h    = (const float*)d_in[6];
  const float* rel_w    = (const float*)d_in[7];
  const float* down_w   = (const float*)d_in[8];
  const float* down_b   = (const float*)d_in[9];
  const float* up_w     = (const float*)d_in[10];
  const float* up_b     = (const float*)d_in[11];
  const float* gating_w = (const float*)d_in[12];
  const float* gating_b = (const float*)d_in[13];
  const float* proj_w   = (const float*)d_in[14];
  const float* lp_w     = (const float*)d_in[15];
  const float* lp_b     = (const float*)d_in[16];
  float* fws = (float*)d_ws;
  float* outp = (float*)d_out;

  float* pre  = fws + PRE_OFF;
  float* qkv  = fws + QKV_OFF;
  float* khat = fws + KHAT_OFF;
  float* vpk  = fws + VPK_OFF;
  float* out3 = fws + OUT3_OFF;
  float* covp = fws + COVP_OFF;
  float* mean = fws + MEAN_OFF;
  int* idx = (int*)(fws + IDX_OFF);
  int* inv = (int*)(fws + INV_OFF);
  float* covs = fws + COVS_OFF;
  float* wT   = fws + WT_OFF;
  float* gT   = fws + GT2_OFF;
  float* dT   = fws + DT2_OFF;
  float* uT   = fws + UT2_OFF;
  float* pT   = fws + PT2_OFF;

  k_prep_wt<<<48, 256, 0, stream>>>(qkv_w, wT);
  k_pool_conv<<<1024, 256, 0, stream>>>(x, wT, pre);
  k_dw3x3_zero<<<49152, 256, 0, stream>>>(pre, lce_w, qkv);
  k_prep2<<<16, 256, 0, stream>>>(gating_w, down_w, up_w, proj_w, gT, dT, uT, pT);
  k_mean<<<256, 256, 0, stream>>>(qkv, mean);
  k_covpart<<<512, 256, 0, stream>>>(qkv, mean, covp);
  k_covred<<<64, 256, 0, stream>>>(covp, covs);
  k_simsort<<<4, 256, 0, stream>>>(covs, idx, inv);
  k_stage<<<4096, 64, 0, stream>>>(qkv, idx, rel_h, rel_w, khat, vpk);
  k_attn<<<4096, 64, 0, stream>>>(qkv, idx, khat, vpk, gate_w, gate_b, temp, qkv);
  k_post<<<1024, 64, 0, stream>>>(qkv, qkv, gT, gating_b, dT, down_b,
                                  uT, up_b, pT, out3);
  k_final<<<2048, 256, 0, stream>>>(out3, lp_w, lp_b, outp);
  (void)inv;
}

// Round 2
// 443.849 us; speedup vs baseline: 1.0839x; 1.0839x over previous
//
#include <hip/hip_runtime.h>
#include <math.h>

#define HWP 16384   // 128*128 pooled plane

// ---------------- workspace layout (float offsets) ----------------
// Lifetimes (same-stream serialization):
//   pre   [0, 12,582,912)          pool_conv -> dw3x3
//   cov   [0, ~2.12M)              mean -> simsort      (inside dead pre)
//   khat  [0, 6,553,600)           stage -> attn        (inside dead pre)
//   vpk   [6,553,600, 10,747,904)  stage -> attn        (inside dead pre)
//   out3  [0, 4,194,304)           post -> final        (staging dead)
//   tail  [12,570,112, 12,582,912) idx/inv + MLP weights, written only
//                                  after dw3x3, live through post
//   qkv   [12,582,912, 25,165,824) dw3x3 -> post; its V planes are dead
//                                  after k_stage and are overwritten IN
//                                  PLACE by k_attn's output (read by post).
static const size_t PRE_OFF  = 0;          // 12,582,912
static const size_t QKV_OFF  = 12582912;
// wT lives at the START of the QKV region: written by k_prep_wt, read only by
// k_pool_conv (which writes PRE only), then overwritten by k_dw3x3_zero.
static const size_t WT_OFF   = QKV_OFF;    // 12,288 floats
static const size_t COVP_OFF = 0;          // 2,097,152
static const size_t MEAN_OFF = 2097152;    // 256
static const size_t COVS_OFF = 2097408;    // 16,384 -> ends 2,113,792
static const size_t KHAT_OFF = 0;          // 6,553,600 (4096 tiles *100*16)
static const size_t VPK_OFF  = 6553600;    // 4,194,304 -> ends 10,747,904
static const size_t OUT3_OFF = 0;          // 4,194,304
static const size_t IDX_OFF  = 12570112;   // 256 ints
static const size_t INV_OFF  = 12570368;   // 256 ints
static const size_t GT2_OFF  = 12570624;   // 4096
static const size_t DT2_OFF  = 12574720;   // 2048
static const size_t UT2_OFF  = 12576768;   // 2048
static const size_t PT2_OFF  = 12578816;   // 4096 -> ends 12,582,912 exactly

// ---------------- 0: transpose qkv_w -> wT[c*192+o] ----------------
__global__ __launch_bounds__(256) void k_prep_wt(
    const float* __restrict__ qkv_w, float* __restrict__ wT) {
  int i = blockIdx.x * 256 + threadIdx.x;   // 12288
  int o = i >> 6, c = i & 63;
  wT[c * 192 + o] = qkv_w[i];
}

// ---------------- 0b: transpose MLP weights to d-major ----------------
__global__ __launch_bounds__(256) void k_prep2(
    const float* __restrict__ gating_w, const float* __restrict__ down_w,
    const float* __restrict__ up_w, const float* __restrict__ proj_w,
    float* __restrict__ gT, float* __restrict__ dT,
    float* __restrict__ uT, float* __restrict__ pT) {
  int t = blockIdx.x * 256 + threadIdx.x;
  if (t < 4096) {
    int o = t >> 6, d = t & 63;
    gT[d * 64 + o] = gating_w[t];
    pT[d * 64 + o] = proj_w[t];
  }
  if (t < 2048) {
    int o = t >> 6, d = t & 63;      // down_w (32,64)
    dT[d * 32 + o] = down_w[t];
    int o2 = t >> 5, d2 = t & 31;    // up_w (64,32)
    uT[d2 * 64 + o2] = up_w[t];
  }
}

// ---------------- 1: maxpool2 + conv1x1 (x -> qkv_pre) ----------------
__global__ __launch_bounds__(256) void k_pool_conv(
    const float* __restrict__ x, const float* __restrict__ wT,
    float* __restrict__ pre) {
  int b = blockIdx.x >> 8;          // 256 tiles / batch
  int pix0 = (blockIdx.x & 255) * 64;
  __shared__ float xt[64 * 64];     // [c][p]
  int t = threadIdx.x;
  for (int i = 0; i < 16; ++i) {
    int f = i * 256 + t;
    int c = f >> 6, p = f & 63;
    int pix = pix0 + p;
    int y = pix >> 7, xx = pix & 127;
    const float* src = x + ((size_t)(b * 64 + c) * 65536) + (2 * y) * 256 + 2 * xx;
    float2 v01 = *(const float2*)src;
    float2 v23 = *(const float2*)(src + 256);
    xt[c * 64 + p] = fmaxf(fmaxf(v01.x, v01.y), fmaxf(v23.x, v23.y));
  }
  __syncthreads();
  int p = t & 63;
  int obase = __builtin_amdgcn_readfirstlane((t >> 6) * 48);  // wave-uniform
  const float* wbase = wT + obase;
  float acc[48];
#pragma unroll
  for (int j = 0; j < 48; ++j) acc[j] = 0.f;
  for (int c = 0; c < 64; ++c) {
    float xv = xt[c * 64 + p];
    const float* wc = wbase + c * 192;    // uniform -> s_load_dwordx16 x3
#pragma unroll
    for (int j = 0; j < 48; ++j) acc[j] = fmaf(wc[j], xv, acc[j]);
  }
  float* dst = pre + ((size_t)b * 192 + obase) * HWP + pix0 + p;
#pragma unroll
  for (int j = 0; j < 48; ++j) dst[(size_t)j * HWP] = acc[j];
}

// ---------------- 2: depthwise 3x3, zero pad (pre -> qkv) ----------------
__global__ __launch_bounds__(256) void k_dw3x3_zero(
    const float* __restrict__ pre, const float* __restrict__ lce_w,
    float* __restrict__ qkv) {
  int gid = blockIdx.x * 256 + threadIdx.x;   // 4*192*16384 total
  int pix = gid & (HWP - 1);
  int bc = gid >> 14;
  int ch = bc % 192;
  int y = pix >> 7, xx = pix & 127;
  const float* w = lce_w + ch * 9;
  const float* base = pre + (size_t)bc * HWP;
  float acc = 0.f;
#pragma unroll
  for (int dy = -1; dy <= 1; ++dy) {
    int yy = y + dy;
    if (yy < 0 || yy > 127) continue;
#pragma unroll
    for (int dx = -1; dx <= 1; ++dx) {
      int xc = xx + dx;
      if (xc < 0 || xc > 127) continue;
      acc = fmaf(w[(dy + 1) * 3 + dx + 1], base[yy * 128 + xc], acc);
    }
  }
  qkv[gid] = acc;
}

// ---------------- 3a: per-channel mean of q ----------------
__global__ __launch_bounds__(256) void k_mean(
    const float* __restrict__ qkv, float* __restrict__ mean) {
  int bc = blockIdx.x;              // b*64 + c
  int b = bc >> 6, c = bc & 63;
  const float* src = qkv + ((size_t)b * 192 + c) * HWP;
  float s = 0.f;
  for (int i = threadIdx.x; i < HWP; i += 256) s += src[i];
  __shared__ float red[4];
  for (int off = 32; off > 0; off >>= 1) s += __shfl_down(s, off);
  int t = threadIdx.x;
  if ((t & 63) == 0) red[t >> 6] = s;
  __syncthreads();
  if (t == 0) mean[bc] = (red[0] + red[1] + red[2] + red[3]) * (1.f / 16384.f);
}

// ---------------- 3b: centered cov partials (chunks of 128) ----------------
__global__ __launch_bounds__(256) void k_covpart(
    const float* __restrict__ qkv, const float* __restrict__ mean,
    float* __restrict__ covp) {
  int blk = blockIdx.x;             // b*128 + chunk
  int b = blk >> 7, chunk = blk & 127;
  int e0 = chunk * 128;
  __shared__ float qc[64 * 129];    // +1 pad breaks stride conflicts
  int t = threadIdx.x;
  for (int i = 0; i < 32; ++i) {
    int f = i * 256 + t;
    int c = f >> 7, e = f & 127;
    qc[c * 129 + e] = qkv[((size_t)b * 192 + c) * HWP + e0 + e] - mean[b * 64 + c];
  }
  __syncthreads();
  int d = t & 63;
  int crow = t >> 6;                // wave-uniform
  float acc[16];
#pragma unroll
  for (int i = 0; i < 16; ++i) acc[i] = 0.f;
  for (int e = 0; e < 128; ++e) {
    float qd = qc[d * 129 + e];
#pragma unroll
    for (int i = 0; i < 16; ++i) {
      int c = crow + 4 * i;
      acc[i] = fmaf(qc[c * 129 + e], qd, acc[i]);
    }
  }
  float* dst = covp + (size_t)blk * 4096;
#pragma unroll
  for (int i = 0; i < 16; ++i) {
    int c = crow + 4 * i;
    dst[c * 64 + d] = acc[i];       // == dst[i*256 + t], coalesced
  }
}

// ---------------- 3b2: reduce cov partials over 128 chunks ----------------
__global__ __launch_bounds__(256) void k_covred(
    const float* __restrict__ covp, float* __restrict__ covs) {
  int blk = blockIdx.x;             // b*16 + j
  int b = blk >> 4;
  int pp = (blk & 15) * 256 + threadIdx.x;
  const float* src = covp + (size_t)b * 524288 + pp;
  float s = 0.f;
  for (int ch = 0; ch < 128; ++ch) s += src[ch * 4096];   // chunk order preserved
  covs[b * 4096 + pp] = s;
}

// ---------------- 3c: correlation-mean sim, stable rank ----------------
__global__ __launch_bounds__(256) void k_simsort(
    const float* __restrict__ covs_g, int* __restrict__ idx, int* __restrict__ inv) {
  int b = blockIdx.x;               // 4 blocks
  __shared__ float covs[4096];
  __shared__ float stds[64];
  __shared__ float sims[64];
  int t = threadIdx.x;
  for (int i = 0; i < 16; ++i) covs[i * 256 + t] = covs_g[b * 4096 + i * 256 + t];
  __syncthreads();
  if (t < 64) stds[t] = sqrtf(covs[t * 64 + t] + 1e-8f);
  __syncthreads();
  if (t < 64) {
    float s = 0.f;
    float sc = stds[t];
    for (int d2 = 0; d2 < 64; ++d2) {
      float denom = fmaxf(sc * stds[d2], 1e-8f);
      s += covs[d2 * 64 + t] / denom;   // symmetric matrix: bitwise equal to [t][d2]
    }
    sims[t] = s * (1.f / 64.f);
  }
  __syncthreads();
  if (t < 64) {
    float sv = sims[t];
    int r = 0;
    for (int d2 = 0; d2 < 64; ++d2) {
      float o = sims[d2];
      if (o > sv || (o == sv && d2 < t)) r++;
    }
    idx[b * 64 + r] = t;
    inv[b * 64 + t] = r;
  }
}

// ---------------- 6: stage K-hat (rel-added, l2-normalized) + packed V ----
// khat: [tile=bi][key 0..99][16ch]  (64B rows, wave-uniform in k_attn)
// vpk : [b*4+head][pos 0..16383][16ch] (no halo duplication; each pooled
//       position is interior to exactly one tile -> that tile writes it)
__global__ __launch_bounds__(64) void k_stage(
    const float* __restrict__ qkv, const int* __restrict__ idx,
    const float* __restrict__ rel_h, const float* __restrict__ rel_w,
    float* __restrict__ khat, float* __restrict__ vpk) {
  int bi = blockIdx.x;
  int head = bi & 3;
  int wj = (bi >> 2) & 15;
  int hi = (bi >> 6) & 15;
  int b = bi >> 10;
  int t = threadIdx.x;
  const size_t bb = (size_t)b * 192 * HWP;
  int chg[16];
#pragma unroll
  for (int ch = 0; ch < 16; ++ch) chg[ch] = idx[b * 64 + head * 16 + ch];
  // K rows: 100 halo positions
  for (int i = 0; i < 2; ++i) {
    int pos = i * 64 + t;
    if (pos < 100) {
      int py = pos / 10, px = pos - py * 10;
      int ky = hi * 8 + py - 1, kx = wj * 8 + px - 1;
      bool ok = (ky >= 0) && (ky < 128) && (kx >= 0) && (kx < 128);
      int sp = ky * 128 + kx;
      float kv[16];
      float s = 0.f;
#pragma unroll
      for (int ch = 0; ch < 16; ++ch) {
        float k = ok ? qkv[bb + (size_t)(64 + chg[ch]) * HWP + sp] : 0.f;
        k += (ch < 8) ? rel_h[(head * 10 + py) * 8 + ch]
                      : rel_w[(head * 10 + px) * 8 + (ch - 8)];
        kv[ch] = k;
        s += k * k;
      }
      float rn = 1.f / fmaxf(sqrtf(s), 1e-12f);   // ref: l2norm(k+rel) before dot
      float* kd = khat + ((size_t)bi * 100 + pos) * 16;
#pragma unroll
      for (int ch = 0; ch < 16; ++ch) kd[ch] = kv[ch] * rn;
    }
  }
  // V rows: this tile's 64 interior positions, gathered channel-packed
  int qy = hi * 8 + (t >> 3), qx = wj * 8 + (t & 7);
  int spq = qy * 128 + qx;
  float* vd = vpk + ((size_t)(b * 4 + head) * 16384 + spq) * 16;
#pragma unroll
  for (int ch = 0; ch < 16; ++ch)
    vd[ch] = qkv[bb + (size_t)(128 + chg[ch]) * HWP + spq];
}

// ---------------- 7: halo block attention + gate ----------------
// No LDS, no barriers. K/V rows are wave-uniform 64B lines -> scalar loads
// (s_load_dwordx16); SGPR operands feed v_fmac directly. Output is scattered
// IN PLACE into the dead V planes of qkv (read by k_post as attn).
__global__ __launch_bounds__(64) void k_attn(
    const float* __restrict__ qkv, const int* __restrict__ idx,
    const float* __restrict__ khat, const float* __restrict__ vpk,
    const float* __restrict__ gate_w, const float* __restrict__ gate_b,
    const float* __restrict__ temp, float* __restrict__ attn_out) {
  int bi = blockIdx.x;
  int head = bi & 3;
  int wj = (bi >> 2) & 15;
  int hi = (bi >> 6) & 15;
  int b = bi >> 10;
  int t = threadIdx.x;
  const size_t bb = (size_t)b * 192 * HWP;
  int chg[16];
#pragma unroll
  for (int ch = 0; ch < 16; ++ch) chg[ch] = idx[b * 64 + head * 16 + ch];
  int qy = hi * 8 + (t >> 3), qx = wj * 8 + (t & 7);
  float q[16];
  float qs = 0.f;
#pragma unroll
  for (int ch = 0; ch < 16; ++ch) {
    q[ch] = qkv[bb + (size_t)chg[ch] * HWP + qy * 128 + qx];
    qs += q[ch] * q[ch];
  }
  float T = expf(temp[head]);
  float qnT = T / fmaxf(sqrtf(qs), 1e-12f);
  const float* kb = khat + (size_t)bi * 1600;
  const float* vb = vpk + (size_t)(b * 4 + head) * (16384 * 16);
  float out[16];
#pragma unroll
  for (int ch = 0; ch < 16; ++ch) out[ch] = 0.f;
  float wsum = 0.f;
  for (int py = 0; py < 10; ++py) {
    int ky = hi * 8 + py - 1;
    bool oky = (ky >= 0) && (ky < 128);
    const float* kprow = kb + py * 160;
    int spy = ky * 128;
    for (int px = 0; px < 10; ++px) {
      int kx = wj * 8 + px - 1;
      bool ok = oky && (kx >= 0) && (kx < 128);
      int sp = ok ? (spy + kx) : 0;               // clamp: OOB reads row 0, masked below
      const float* kp = kprow + px * 16;          // uniform -> s_load_dwordx16
      const float* vp = vb + (size_t)sp * 16;     // uniform -> s_load_dwordx16
      float dacc = 0.f;
#pragma unroll
      for (int ch = 0; ch < 16; ++ch) dacc = fmaf(q[ch], kp[ch], dacc);
      float e = expf(fmaf(dacc, qnT, -T));        // exp(d - T): exact softmax shift
      wsum += e;                                  // OOB keys DO count in denominator
      float ev = ok ? e : 0.f;                    // ...but contribute V=0
#pragma unroll
      for (int ch = 0; ch < 16; ++ch) out[ch] = fmaf(ev, vp[ch], out[ch]);
    }
  }
  float winv = 1.f / wsum;
#pragma unroll
  for (int o = 0; o < 16; ++o) {
    float gsv = gate_b[head * 16 + o];
#pragma unroll
    for (int c = 0; c < 16; ++c)
      gsv = fmaf(gate_w[head * 256 + o * 16 + c], q[c], gsv);
    float sig = 1.f / (1.f + expf(-gsv));
    attn_out[bb + (size_t)(128 + chg[o]) * HWP + qy * 128 + qx] = out[o] * winv * sig;
  }
}

// ---------------- 8: mixed -> gating -> down -> up -> (+attn) -> proj ----
// attn lives in the qkv V planes: channel c of batch b at (b*192+128+c)*HWP.
// 256 threads = 4 waves per block, 64 pixels per block (lane = pixel).
// Output channels are SPLIT ACROSS WAVES (16/wave; 8/wave for down): raises
// waves/CU from 4 to 16 (round-1 counters: Occupancy 10.8%, VALUBusy 16.6%
// -> launch-width latency bound at 1 wave/SIMD). Per-channel accumulator
// chain order (d ascending) is unchanged -> bitwise-identical results.
__global__ __launch_bounds__(256) void k_post(
    const float* __restrict__ attn, const float* __restrict__ qkv,
    const float* __restrict__ gT, const float* __restrict__ gating_b,
    const float* __restrict__ dT, const float* __restrict__ down_b,
    const float* __restrict__ uT, const float* __restrict__ up_b,
    const float* __restrict__ pT, float* __restrict__ out3) {
  __shared__ float xs[64 * 64];     // [c][pix]
  int t = threadIdx.x;
  int lane = t & 63;                // pixel within block
  int w = t >> 6;                   // wave 0..3 (uniform)
  int p = blockIdx.x * 64 + lane;   // global pooled pixel id
  int b = p >> 14;
  int pix = p & 16383;
  const float* ap = attn + ((size_t)b * 192 + 128) * HWP + pix;
  const float* qp = qkv + (size_t)b * 192 * HWP + pix;
  float* op = out3 + (size_t)b * 64 * HWP + pix;
  int ob16 = __builtin_amdgcn_readfirstlane(w * 16);
  int ob8  = __builtin_amdgcn_readfirstlane(w * 8);
  // mixed = attn_out + (q + k): each wave loads its 16 channels (concurrent)
#pragma unroll
  for (int i = 0; i < 16; ++i) {
    int c = ob16 + i;
    xs[c * 64 + lane] = ap[(size_t)c * HWP] + qp[(size_t)c * HWP] + qp[(size_t)(64 + c) * HWP];
  }
  __syncthreads();
  // ---- gating conv + exact gelu, * mixed ----
  {
    float acc[16];
#pragma unroll
    for (int o = 0; o < 16; ++o) acc[o] = gating_b[ob16 + o];
    for (int d = 0; d < 64; ++d) {
      float xv = xs[d * 64 + lane];
      const float* wd = gT + d * 64 + ob16;   // wave-uniform -> s_load
#pragma unroll
      for (int o = 0; o < 16; ++o) acc[o] = fmaf(wd[o], xv, acc[o]);
    }
    __syncthreads();                 // all reads done before any overwrite
#pragma unroll
    for (int o = 0; o < 16; ++o) {
      float a = acc[o];
      float ge = 0.5f * a * (1.f + erff(a * 0.70710678118654752f));
      xs[(ob16 + o) * 64 + lane] = ge * xs[(ob16 + o) * 64 + lane];
    }
    __syncthreads();
  }
  // ---- down 64->32 (8 outputs/wave) ----
  {
    float acc[8];
#pragma unroll
    for (int o = 0; o < 8; ++o) acc[o] = down_b[ob8 + o];
    for (int d = 0; d < 64; ++d) {
      float xv = xs[d * 64 + lane];
      const float* wd = dT + d * 32 + ob8;
#pragma unroll
      for (int o = 0; o < 8; ++o) acc[o] = fmaf(wd[o], xv, acc[o]);
    }
    __syncthreads();
#pragma unroll
    for (int o = 0; o < 8; ++o) xs[(ob8 + o) * 64 + lane] = acc[o];
    __syncthreads();
  }
  // ---- up 32->64, + attn residual ----
  {
    float acc[16];
#pragma unroll
    for (int o = 0; o < 16; ++o) acc[o] = up_b[ob16 + o];
    for (int d = 0; d < 32; ++d) {
      float xv = xs[d * 64 + lane];
      const float* wd = uT + d * 64 + ob16;
#pragma unroll
      for (int o = 0; o < 16; ++o) acc[o] = fmaf(wd[o], xv, acc[o]);
    }
    __syncthreads();
#pragma unroll
    for (int o = 0; o < 16; ++o)
      xs[(ob16 + o) * 64 + lane] = acc[o] + ap[(size_t)(ob16 + o) * HWP];
    __syncthreads();
  }
  // ---- proj (no bias) ----
  {
    float acc[16];
#pragma unroll
    for (int o = 0; o < 16; ++o) acc[o] = 0.f;
    for (int d = 0; d < 64; ++d) {
      float xv = xs[d * 64 + lane];
      const float* wd = pT + d * 64 + ob16;
#pragma unroll
      for (int o = 0; o < 16; ++o) acc[o] = fmaf(wd[o], xv, acc[o]);
    }
#pragma unroll
    for (int o = 0; o < 16; ++o) op[(size_t)(ob16 + o) * HWP] = acc[o];
  }
}

// ---------------- 9: dw3x3 reflect + bias + bilinear x2 (align-corners) ----
__global__ __launch_bounds__(256) void k_final(
    const float* __restrict__ out3, const float* __restrict__ lp_w,
    const float* __restrict__ lp_b, float* __restrict__ out) {
  int bi = blockIdx.x;                 // (b*64+ch)*8 + rt
  int rt = bi & 7;
  int bc = bi >> 3;
  int ch = bc & 63;
  int r0 = rt * 16;
  __shared__ float tin[20 * 128];      // input rows r0-2 .. r0+17 (reflected)
  __shared__ float tdw[18 * 128];      // dw rows r0-1 .. r0+16
  int t = threadIdx.x;
  const float* src = out3 + (size_t)bc * HWP;
  for (int i = 0; i < 10; ++i) {
    int f = i * 256 + t;               // 2560 exactly
    int r = f >> 7, xx = f & 127;
    int ry = r0 - 2 + r;
    ry = ry < 0 ? -ry : (ry > 127 ? 254 - ry : ry);
    tin[f] = src[ry * 128 + xx];
  }
  __syncthreads();
  float w0 = lp_w[ch * 9 + 0], w1 = lp_w[ch * 9 + 1], w2 = lp_w[ch * 9 + 2];
  float w3 = lp_w[ch * 9 + 3], w4 = lp_w[ch * 9 + 4], w5 = lp_w[ch * 9 + 5];
  float w6 = lp_w[ch * 9 + 6], w7 = lp_w[ch * 9 + 7], w8 = lp_w[ch * 9 + 8];
  float bias = lp_b[ch];
  for (int i = 0; i < 9; ++i) {
    int f = i * 256 + t;               // 2304 exactly
    int r = f >> 7, xx = f & 127;
    int xm = (xx == 0) ? 1 : xx - 1;
    int xp = (xx == 127) ? 126 : xx + 1;
    const float* r0p = tin + r * 128;
    const float* r1p = r0p + 128;
    const float* r2p = r1p + 128;
    float acc = bias;
    acc = fmaf(w0, r0p[xm], acc); acc = fmaf(w1, r0p[xx], acc); acc = fmaf(w2, r0p[xp], acc);
    acc = fmaf(w3, r1p[xm], acc); acc = fmaf(w4, r1p[xx], acc); acc = fmaf(w5, r1p[xp], acc);
    acc = fmaf(w6, r2p[xm], acc); acc = fmaf(w7, r2p[xx], acc); acc = fmaf(w8, r2p[xp], acc);
    tdw[f] = acc;
  }
  __syncthreads();
  const float s = (float)(127.0 / 255.0);
  float* dst = out + (size_t)bc * 65536;
  for (int i = 0; i < 32; ++i) {
    int f = i * 256 + t;               // 8192 exactly: rows 2r0..2r0+31, cols 0..255
    int vr = f >> 8, vx = f & 255;
    int v = 2 * r0 + vr;
    float cy = (float)v * s;
    int ly = (int)floorf(cy); if (ly > 126) ly = 126;
    float wy = cy - (float)ly;
    float cx = (float)vx * s;
    int lx = (int)floorf(cx); if (lx > 126) lx = 126;
    float wx = cx - (float)lx;
    int lr = ly - r0 + 1;              // tdw row index
    float a  = tdw[lr * 128 + lx];
    float bq = tdw[lr * 128 + lx + 1];
    float c2 = tdw[(lr + 1) * 128 + lx];
    float d2 = tdw[(lr + 1) * 128 + lx + 1];
    float t0 = a  * (1.f - wy) + c2 * wy;   // y-lerp first (matches ref order)
    float t1 = bq * (1.f - wy) + d2 * wy;
    dst[v * 256 + vx] = t0 * (1.f - wx) + t1 * wx;
  }
}

extern "C" void kernel_launch(void* const* d_in, const int* in_sizes, int n_in,
                              void* d_out, int out_size, void* d_ws, size_t ws_size,
                              hipStream_t stream) {
  (void)in_sizes; (void)n_in; (void)out_size; (void)ws_size;
  const float* x        = (const float*)d_in[0];
  const float* qkv_w    = (const float*)d_in[1];
  const float* lce_w    = (const float*)d_in[2];
  const float* gate_w   = (const float*)d_in[3];
  const float* gate_b   = (const float*)d_in[4];
  const float* temp     = (const float*)d_in[5];
  const float* rel_h    = (const float*)d_in[6];
  const float* rel_w    = (const float*)d_in[7];
  const float* down_w   = (const float*)d_in[8];
  const float* down_b   = (const float*)d_in[9];
  const float* up_w     = (const float*)d_in[10];
  const float* up_b     = (const float*)d_in[11];
  const float* gating_w = (const float*)d_in[12];
  const float* gating_b = (const float*)d_in[13];
  const float* proj_w   = (const float*)d_in[14];
  const float* lp_w     = (const float*)d_in[15];
  const float* lp_b     = (const float*)d_in[16];
  float* fws = (float*)d_ws;
  float* outp = (float*)d_out;

  float* pre  = fws + PRE_OFF;
  float* qkv  = fws + QKV_OFF;
  float* khat = fws + KHAT_OFF;
  float* vpk  = fws + VPK_OFF;
  float* out3 = fws + OUT3_OFF;
  float* covp = fws + COVP_OFF;
  float* mean = fws + MEAN_OFF;
  int* idx = (int*)(fws + IDX_OFF);
  int* inv = (int*)(fws + INV_OFF);
  float* covs = fws + COVS_OFF;
  float* wT   = fws + WT_OFF;
  float* gT   = fws + GT2_OFF;
  float* dT   = fws + DT2_OFF;
  float* uT   = fws + UT2_OFF;
  float* pT   = fws + PT2_OFF;

  k_prep_wt<<<48, 256, 0, stream>>>(qkv_w, wT);
  k_pool_conv<<<1024, 256, 0, stream>>>(x, wT, pre);
  k_dw3x3_zero<<<49152, 256, 0, stream>>>(pre, lce_w, qkv);
  k_prep2<<<16, 256, 0, stream>>>(gating_w, down_w, up_w, proj_w, gT, dT, uT, pT);
  k_mean<<<256, 256, 0, stream>>>(qkv, mean);
  k_covpart<<<512, 256, 0, stream>>>(qkv, mean, covp);
  k_covred<<<64, 256, 0, stream>>>(covp, covs);
  k_simsort<<<4, 256, 0, stream>>>(covs, idx, inv);
  k_stage<<<4096, 64, 0, stream>>>(qkv, idx, rel_h, rel_w, khat, vpk);
  k_attn<<<4096, 64, 0, stream>>>(qkv, idx, khat, vpk, gate_w, gate_b, temp, qkv);
  k_post<<<1024, 256, 0, stream>>>(qkv, qkv, gT, gating_b, dT, down_b,
                                   uT, up_b, pT, out3);
  k_final<<<2048, 256, 0, stream>>>(out3, lp_w, lp_b, outp);
  (void)inv;
}

// Round 3
// 440.992 us; speedup vs baseline: 1.0909x; 1.0065x over previous
//
#include <hip/hip_runtime.h>
#include <math.h>

#define HWP 16384   // 128*128 pooled plane

// ---------------- workspace layout (float offsets) ----------------
// Lifetimes (same-stream serialization):
//   pre   [0, 12,582,912)          pool_conv -> dw3x3
//   cov   [0, ~2.12M)              mean -> simsort      (inside dead pre)
//   khat  [0, 6,553,600)           stage -> attn        (inside dead pre)
//   vpk   [6,553,600, 10,747,904)  stage -> attn        (inside dead pre)
//   out3  [0, 4,194,304)           post -> final        (staging dead)
//   tail  [12,570,112, 12,582,912) idx/inv + MLP weights, written only
//                                  after dw3x3, live through post
//   qkv   [12,582,912, 25,165,824) dw3x3 -> post; its V planes are dead
//                                  after k_stage and are overwritten IN
//                                  PLACE by k_attn's output (read by post).
static const size_t PRE_OFF  = 0;          // 12,582,912
static const size_t QKV_OFF  = 12582912;
// wT lives at the START of the QKV region: written by k_prep_wt, read only by
// k_pool_conv (which writes PRE only), then overwritten by k_dw3x3_zero.
static const size_t WT_OFF   = QKV_OFF;    // 12,288 floats
static const size_t COVP_OFF = 0;          // 2,097,152
static const size_t MEAN_OFF = 2097152;    // 256
static const size_t COVS_OFF = 2097408;    // 16,384 -> ends 2,113,792
static const size_t KHAT_OFF = 0;          // 6,553,600 (4096 tiles *100*16)
static const size_t VPK_OFF  = 6553600;    // 4,194,304 -> ends 10,747,904
static const size_t OUT3_OFF = 0;          // 4,194,304
static const size_t IDX_OFF  = 12570112;   // 256 ints
static const size_t INV_OFF  = 12570368;   // 256 ints
static const size_t GT2_OFF  = 12570624;   // 4096
static const size_t DT2_OFF  = 12574720;   // 2048
static const size_t UT2_OFF  = 12576768;   // 2048
static const size_t PT2_OFF  = 12578816;   // 4096 -> ends 12,582,912 exactly

// ---------------- 0: transpose qkv_w -> wT[c*192+o] ----------------
__global__ __launch_bounds__(256) void k_prep_wt(
    const float* __restrict__ qkv_w, float* __restrict__ wT) {
  int i = blockIdx.x * 256 + threadIdx.x;   // 12288
  int o = i >> 6, c = i & 63;
  wT[c * 192 + o] = qkv_w[i];
}

// ---------------- 0b: transpose MLP weights to d-major ----------------
__global__ __launch_bounds__(256) void k_prep2(
    const float* __restrict__ gating_w, const float* __restrict__ down_w,
    const float* __restrict__ up_w, const float* __restrict__ proj_w,
    float* __restrict__ gT, float* __restrict__ dT,
    float* __restrict__ uT, float* __restrict__ pT) {
  int t = blockIdx.x * 256 + threadIdx.x;
  if (t < 4096) {
    int o = t >> 6, d = t & 63;
    gT[d * 64 + o] = gating_w[t];
    pT[d * 64 + o] = proj_w[t];
  }
  if (t < 2048) {
    int o = t >> 6, d = t & 63;      // down_w (32,64)
    dT[d * 32 + o] = down_w[t];
    int o2 = t >> 5, d2 = t & 31;    // up_w (64,32)
    uT[d2 * 64 + o2] = up_w[t];
  }
}

// ---------------- 1: maxpool2 + conv1x1 (x -> qkv_pre) ----------------
__global__ __launch_bounds__(256) void k_pool_conv(
    const float* __restrict__ x, const float* __restrict__ wT,
    float* __restrict__ pre) {
  int b = blockIdx.x >> 8;          // 256 tiles / batch
  int pix0 = (blockIdx.x & 255) * 64;
  __shared__ float xt[64 * 64];     // [c][p]
  int t = threadIdx.x;
  for (int i = 0; i < 16; ++i) {
    int f = i * 256 + t;
    int c = f >> 6, p = f & 63;
    int pix = pix0 + p;
    int y = pix >> 7, xx = pix & 127;
    const float* src = x + ((size_t)(b * 64 + c) * 65536) + (2 * y) * 256 + 2 * xx;
    float2 v01 = *(const float2*)src;
    float2 v23 = *(const float2*)(src + 256);
    xt[c * 64 + p] = fmaxf(fmaxf(v01.x, v01.y), fmaxf(v23.x, v23.y));
  }
  __syncthreads();
  int p = t & 63;
  int obase = __builtin_amdgcn_readfirstlane((t >> 6) * 48);  // wave-uniform
  const float* wbase = wT + obase;
  float acc[48];
#pragma unroll
  for (int j = 0; j < 48; ++j) acc[j] = 0.f;
  for (int c = 0; c < 64; ++c) {
    float xv = xt[c * 64 + p];
    const float* wc = wbase + c * 192;    // uniform -> s_load_dwordx16 x3
#pragma unroll
    for (int j = 0; j < 48; ++j) acc[j] = fmaf(wc[j], xv, acc[j]);
  }
  float* dst = pre + ((size_t)b * 192 + obase) * HWP + pix0 + p;
#pragma unroll
  for (int j = 0; j < 48; ++j) dst[(size_t)j * HWP] = acc[j];
}

// ---------------- 2: depthwise 3x3, zero pad (pre -> qkv) ----------------
__global__ __launch_bounds__(256) void k_dw3x3_zero(
    const float* __restrict__ pre, const float* __restrict__ lce_w,
    float* __restrict__ qkv) {
  int gid = blockIdx.x * 256 + threadIdx.x;   // 4*192*16384 total
  int pix = gid & (HWP - 1);
  int bc = gid >> 14;
  int ch = bc % 192;
  int y = pix >> 7, xx = pix & 127;
  const float* w = lce_w + ch * 9;
  const float* base = pre + (size_t)bc * HWP;
  float acc = 0.f;
#pragma unroll
  for (int dy = -1; dy <= 1; ++dy) {
    int yy = y + dy;
    if (yy < 0 || yy > 127) continue;
#pragma unroll
    for (int dx = -1; dx <= 1; ++dx) {
      int xc = xx + dx;
      if (xc < 0 || xc > 127) continue;
      acc = fmaf(w[(dy + 1) * 3 + dx + 1], base[yy * 128 + xc], acc);
    }
  }
  qkv[gid] = acc;
}

// ---------------- 3a: per-channel mean of q ----------------
__global__ __launch_bounds__(256) void k_mean(
    const float* __restrict__ qkv, float* __restrict__ mean) {
  int bc = blockIdx.x;              // b*64 + c
  int b = bc >> 6, c = bc & 63;
  const float* src = qkv + ((size_t)b * 192 + c) * HWP;
  float s = 0.f;
  for (int i = threadIdx.x; i < HWP; i += 256) s += src[i];
  __shared__ float red[4];
  for (int off = 32; off > 0; off >>= 1) s += __shfl_down(s, off);
  int t = threadIdx.x;
  if ((t & 63) == 0) red[t >> 6] = s;
  __syncthreads();
  if (t == 0) mean[bc] = (red[0] + red[1] + red[2] + red[3]) * (1.f / 16384.f);
}

// ---------------- 3b: centered cov partials (chunks of 128) ----------------
__global__ __launch_bounds__(256) void k_covpart(
    const float* __restrict__ qkv, const float* __restrict__ mean,
    float* __restrict__ covp) {
  int blk = blockIdx.x;             // b*128 + chunk
  int b = blk >> 7, chunk = blk & 127;
  int e0 = chunk * 128;
  __shared__ float qc[64 * 129];    // +1 pad breaks stride conflicts
  int t = threadIdx.x;
  for (int i = 0; i < 32; ++i) {
    int f = i * 256 + t;
    int c = f >> 7, e = f & 127;
    qc[c * 129 + e] = qkv[((size_t)b * 192 + c) * HWP + e0 + e] - mean[b * 64 + c];
  }
  __syncthreads();
  int d = t & 63;
  int crow = t >> 6;                // wave-uniform
  float acc[16];
#pragma unroll
  for (int i = 0; i < 16; ++i) acc[i] = 0.f;
  for (int e = 0; e < 128; ++e) {
    float qd = qc[d * 129 + e];
#pragma unroll
    for (int i = 0; i < 16; ++i) {
      int c = crow + 4 * i;
      acc[i] = fmaf(qc[c * 129 + e], qd, acc[i]);
    }
  }
  float* dst = covp + (size_t)blk * 4096;
#pragma unroll
  for (int i = 0; i < 16; ++i) {
    int c = crow + 4 * i;
    dst[c * 64 + d] = acc[i];       // == dst[i*256 + t], coalesced
  }
}

// ---------------- 3b2: reduce cov partials over 128 chunks ----------------
__global__ __launch_bounds__(256) void k_covred(
    const float* __restrict__ covp, float* __restrict__ covs) {
  int blk = blockIdx.x;             // b*16 + j
  int b = blk >> 4;
  int pp = (blk & 15) * 256 + threadIdx.x;
  const float* src = covp + (size_t)b * 524288 + pp;
  float s = 0.f;
  for (int ch = 0; ch < 128; ++ch) s += src[ch * 4096];   // chunk order preserved
  covs[b * 4096 + pp] = s;
}

// ---------------- 3c: correlation-mean sim, stable rank ----------------
__global__ __launch_bounds__(256) void k_simsort(
    const float* __restrict__ covs_g, int* __restrict__ idx, int* __restrict__ inv) {
  int b = blockIdx.x;               // 4 blocks
  __shared__ float covs[4096];
  __shared__ float stds[64];
  __shared__ float sims[64];
  int t = threadIdx.x;
  for (int i = 0; i < 16; ++i) covs[i * 256 + t] = covs_g[b * 4096 + i * 256 + t];
  __syncthreads();
  if (t < 64) stds[t] = sqrtf(covs[t * 64 + t] + 1e-8f);
  __syncthreads();
  if (t < 64) {
    float s = 0.f;
    float sc = stds[t];
    for (int d2 = 0; d2 < 64; ++d2) {
      float denom = fmaxf(sc * stds[d2], 1e-8f);
      s += covs[d2 * 64 + t] / denom;   // symmetric matrix: bitwise equal to [t][d2]
    }
    sims[t] = s * (1.f / 64.f);
  }
  __syncthreads();
  if (t < 64) {
    float sv = sims[t];
    int r = 0;
    for (int d2 = 0; d2 < 64; ++d2) {
      float o = sims[d2];
      if (o > sv || (o == sv && d2 < t)) r++;
    }
    idx[b * 64 + r] = t;
    inv[b * 64 + t] = r;
  }
}

// ---------------- 6: stage K-hat (rel-added, l2-normalized) + packed V ----
// khat: [tile=bi][key 0..99][16ch]  (64B rows, wave-uniform in k_attn)
// vpk : [b*4+head][pos 0..16383][16ch] (no halo duplication; each pooled
//       position is interior to exactly one tile -> that tile writes it)
__global__ __launch_bounds__(64) void k_stage(
    const float* __restrict__ qkv, const int* __restrict__ idx,
    const float* __restrict__ rel_h, const float* __restrict__ rel_w,
    float* __restrict__ khat, float* __restrict__ vpk) {
  int bi = blockIdx.x;
  int head = bi & 3;
  int wj = (bi >> 2) & 15;
  int hi = (bi >> 6) & 15;
  int b = bi >> 10;
  int t = threadIdx.x;
  const size_t bb = (size_t)b * 192 * HWP;
  int chg[16];
#pragma unroll
  for (int ch = 0; ch < 16; ++ch) chg[ch] = idx[b * 64 + head * 16 + ch];
  // K rows: 100 halo positions
  for (int i = 0; i < 2; ++i) {
    int pos = i * 64 + t;
    if (pos < 100) {
      int py = pos / 10, px = pos - py * 10;
      int ky = hi * 8 + py - 1, kx = wj * 8 + px - 1;
      bool ok = (ky >= 0) && (ky < 128) && (kx >= 0) && (kx < 128);
      int sp = ky * 128 + kx;
      float kv[16];
      float s = 0.f;
#pragma unroll
      for (int ch = 0; ch < 16; ++ch) {
        float k = ok ? qkv[bb + (size_t)(64 + chg[ch]) * HWP + sp] : 0.f;
        k += (ch < 8) ? rel_h[(head * 10 + py) * 8 + ch]
                      : rel_w[(head * 10 + px) * 8 + (ch - 8)];
        kv[ch] = k;
        s += k * k;
      }
      float rn = 1.f / fmaxf(sqrtf(s), 1e-12f);   // ref: l2norm(k+rel) before dot
      float* kd = khat + ((size_t)bi * 100 + pos) * 16;
#pragma unroll
      for (int ch = 0; ch < 16; ++ch) kd[ch] = kv[ch] * rn;
    }
  }
  // V rows: this tile's 64 interior positions, gathered channel-packed
  int qy = hi * 8 + (t >> 3), qx = wj * 8 + (t & 7);
  int spq = qy * 128 + qx;
  float* vd = vpk + ((size_t)(b * 4 + head) * 16384 + spq) * 16;
#pragma unroll
  for (int ch = 0; ch < 16; ++ch)
    vd[ch] = qkv[bb + (size_t)(128 + chg[ch]) * HWP + spq];
}

// ---------------- 7: halo block attention + gate ----------------
// No LDS, no barriers. K/V rows are wave-uniform 64B lines -> scalar loads
// (s_load_dwordx16); SGPR operands feed v_fmac directly. Output is scattered
// IN PLACE into the dead V planes of qkv (read by k_post as attn).
// Round-3: expf -> __expf (native v_exp_f32; arg range is [-2T,0], no range
// reduction needed — libm expf was ~25 VALU ops/key = half the loop's VALU
// work). Dot chain split 4-way to shorten the per-key dependency chain.
__global__ __launch_bounds__(64) void k_attn(
    const float* __restrict__ qkv, const int* __restrict__ idx,
    const float* __restrict__ khat, const float* __restrict__ vpk,
    const float* __restrict__ gate_w, const float* __restrict__ gate_b,
    const float* __restrict__ temp, float* __restrict__ attn_out) {
  int bi = blockIdx.x;
  int head = bi & 3;
  int wj = (bi >> 2) & 15;
  int hi = (bi >> 6) & 15;
  int b = bi >> 10;
  int t = threadIdx.x;
  const size_t bb = (size_t)b * 192 * HWP;
  int chg[16];
#pragma unroll
  for (int ch = 0; ch < 16; ++ch) chg[ch] = idx[b * 64 + head * 16 + ch];
  int qy = hi * 8 + (t >> 3), qx = wj * 8 + (t & 7);
  float q[16];
  float qs = 0.f;
#pragma unroll
  for (int ch = 0; ch < 16; ++ch) {
    q[ch] = qkv[bb + (size_t)chg[ch] * HWP + qy * 128 + qx];
    qs += q[ch] * q[ch];
  }
  float T = expf(temp[head]);
  float qnT = T / fmaxf(sqrtf(qs), 1e-12f);
  const float* kb = khat + (size_t)bi * 1600;
  const float* vb = vpk + (size_t)(b * 4 + head) * (16384 * 16);
  float out[16];
#pragma unroll
  for (int ch = 0; ch < 16; ++ch) out[ch] = 0.f;
  float wsum = 0.f;
  for (int py = 0; py < 10; ++py) {
    int ky = hi * 8 + py - 1;
    bool oky = (ky >= 0) && (ky < 128);
    const float* kprow = kb + py * 160;
    int spy = ky * 128;
    for (int px = 0; px < 10; ++px) {
      int kx = wj * 8 + px - 1;
      bool ok = oky && (kx >= 0) && (kx < 128);
      int sp = ok ? (spy + kx) : 0;               // clamp: OOB reads row 0, masked below
      const float* kp = kprow + px * 16;          // uniform -> s_load_dwordx16
      const float* vp = vb + (size_t)sp * 16;     // uniform -> s_load_dwordx16
      float d0 = 0.f, d1 = 0.f, d2 = 0.f, d3 = 0.f;
#pragma unroll
      for (int ch = 0; ch < 4; ++ch) {
        d0 = fmaf(q[ch], kp[ch], d0);
        d1 = fmaf(q[ch + 4], kp[ch + 4], d1);
        d2 = fmaf(q[ch + 8], kp[ch + 8], d2);
        d3 = fmaf(q[ch + 12], kp[ch + 12], d3);
      }
      float dacc = (d0 + d1) + (d2 + d3);
      float e = __expf(fmaf(dacc, qnT, -T));      // exp(d - T): exact softmax shift
      wsum += e;                                  // OOB keys DO count in denominator
      float ev = ok ? e : 0.f;                    // ...but contribute V=0
#pragma unroll
      for (int ch = 0; ch < 16; ++ch) out[ch] = fmaf(ev, vp[ch], out[ch]);
    }
  }
  float winv = 1.f / wsum;
#pragma unroll
  for (int o = 0; o < 16; ++o) {
    float gsv = gate_b[head * 16 + o];
#pragma unroll
    for (int c = 0; c < 16; ++c)
      gsv = fmaf(gate_w[head * 256 + o * 16 + c], q[c], gsv);
    float sig = 1.f / (1.f + __expf(-gsv));
    attn_out[bb + (size_t)(128 + chg[o]) * HWP + qy * 128 + qx] = out[o] * winv * sig;
  }
}

// ---------------- 8: mixed -> gating -> down -> up -> (+attn) -> proj ----
// attn lives in the qkv V planes: channel c of batch b at (b*192+128+c)*HWP.
// 256 threads = 4 waves per block, 64 pixels per block (lane = pixel).
// Output channels are SPLIT ACROSS WAVES (16/wave; 8/wave for down): raises
// waves/CU from 4 to 16. Per-channel accumulator chain order (d ascending)
// is unchanged -> bitwise-identical results.
__global__ __launch_bounds__(256) void k_post(
    const float* __restrict__ attn, const float* __restrict__ qkv,
    const float* __restrict__ gT, const float* __restrict__ gating_b,
    const float* __restrict__ dT, const float* __restrict__ down_b,
    const float* __restrict__ uT, const float* __restrict__ up_b,
    const float* __restrict__ pT, float* __restrict__ out3) {
  __shared__ float xs[64 * 64];     // [c][pix]
  int t = threadIdx.x;
  int lane = t & 63;                // pixel within block
  int w = t >> 6;                   // wave 0..3 (uniform)
  int p = blockIdx.x * 64 + lane;   // global pooled pixel id
  int b = p >> 14;
  int pix = p & 16383;
  const float* ap = attn + ((size_t)b * 192 + 128) * HWP + pix;
  const float* qp = qkv + (size_t)b * 192 * HWP + pix;
  float* op = out3 + (size_t)b * 64 * HWP + pix;
  int ob16 = __builtin_amdgcn_readfirstlane(w * 16);
  int ob8  = __builtin_amdgcn_readfirstlane(w * 8);
  // mixed = attn_out + (q + k): each wave loads its 16 channels (concurrent)
#pragma unroll
  for (int i = 0; i < 16; ++i) {
    int c = ob16 + i;
    xs[c * 64 + lane] = ap[(size_t)c * HWP] + qp[(size_t)c * HWP] + qp[(size_t)(64 + c) * HWP];
  }
  __syncthreads();
  // ---- gating conv + exact gelu, * mixed ----
  {
    float acc[16];
#pragma unroll
    for (int o = 0; o < 16; ++o) acc[o] = gating_b[ob16 + o];
    for (int d = 0; d < 64; ++d) {
      float xv = xs[d * 64 + lane];
      const float* wd = gT + d * 64 + ob16;   // wave-uniform -> s_load
#pragma unroll
      for (int o = 0; o < 16; ++o) acc[o] = fmaf(wd[o], xv, acc[o]);
    }
    __syncthreads();                 // all reads done before any overwrite
#pragma unroll
    for (int o = 0; o < 16; ++o) {
      float a = acc[o];
      float ge = 0.5f * a * (1.f + erff(a * 0.70710678118654752f));
      xs[(ob16 + o) * 64 + lane] = ge * xs[(ob16 + o) * 64 + lane];
    }
    __syncthreads();
  }
  // ---- down 64->32 (8 outputs/wave) ----
  {
    float acc[8];
#pragma unroll
    for (int o = 0; o < 8; ++o) acc[o] = down_b[ob8 + o];
    for (int d = 0; d < 64; ++d) {
      float xv = xs[d * 64 + lane];
      const float* wd = dT + d * 32 + ob8;
#pragma unroll
      for (int o = 0; o < 8; ++o) acc[o] = fmaf(wd[o], xv, acc[o]);
    }
    __syncthreads();
#pragma unroll
    for (int o = 0; o < 8; ++o) xs[(ob8 + o) * 64 + lane] = acc[o];
    __syncthreads();
  }
  // ---- up 32->64, + attn residual ----
  {
    float acc[16];
#pragma unroll
    for (int o = 0; o < 16; ++o) acc[o] = up_b[ob16 + o];
    for (int d = 0; d < 32; ++d) {
      float xv = xs[d * 64 + lane];
      const float* wd = uT + d * 64 + ob16;
#pragma unroll
      for (int o = 0; o < 16; ++o) acc[o] = fmaf(wd[o], xv, acc[o]);
    }
    __syncthreads();
#pragma unroll
    for (int o = 0; o < 16; ++o)
      xs[(ob16 + o) * 64 + lane] = acc[o] + ap[(size_t)(ob16 + o) * HWP];
    __syncthreads();
  }
  // ---- proj (no bias) ----
  {
    float acc[16];
#pragma unroll
    for (int o = 0; o < 16; ++o) acc[o] = 0.f;
    for (int d = 0; d < 64; ++d) {
      float xv = xs[d * 64 + lane];
      const float* wd = pT + d * 64 + ob16;
#pragma unroll
      for (int o = 0; o < 16; ++o) acc[o] = fmaf(wd[o], xv, acc[o]);
    }
#pragma unroll
    for (int o = 0; o < 16; ++o) op[(size_t)(ob16 + o) * HWP] = acc[o];
  }
}

// ---------------- 9: dw3x3 reflect + bias + bilinear x2 (align-corners) ----
__global__ __launch_bounds__(256) void k_final(
    const float* __restrict__ out3, const float* __restrict__ lp_w,
    const float* __restrict__ lp_b, float* __restrict__ out) {
  int bi = blockIdx.x;                 // (b*64+ch)*8 + rt
  int rt = bi & 7;
  int bc = bi >> 3;
  int ch = bc & 63;
  int r0 = rt * 16;
  __shared__ float tin[20 * 128];      // input rows r0-2 .. r0+17 (reflected)
  __shared__ float tdw[18 * 128];      // dw rows r0-1 .. r0+16
  int t = threadIdx.x;
  const float* src = out3 + (size_t)bc * HWP;
  for (int i = 0; i < 10; ++i) {
    int f = i * 256 + t;               // 2560 exactly
    int r = f >> 7, xx = f & 127;
    int ry = r0 - 2 + r;
    ry = ry < 0 ? -ry : (ry > 127 ? 254 - ry : ry);
    tin[f] = src[ry * 128 + xx];
  }
  __syncthreads();
  float w0 = lp_w[ch * 9 + 0], w1 = lp_w[ch * 9 + 1], w2 = lp_w[ch * 9 + 2];
  float w3 = lp_w[ch * 9 + 3], w4 = lp_w[ch * 9 + 4], w5 = lp_w[ch * 9 + 5];
  float w6 = lp_w[ch * 9 + 6], w7 = lp_w[ch * 9 + 7], w8 = lp_w[ch * 9 + 8];
  float bias = lp_b[ch];
  for (int i = 0; i < 9; ++i) {
    int f = i * 256 + t;               // 2304 exactly
    int r = f >> 7, xx = f & 127;
    int xm = (xx == 0) ? 1 : xx - 1;
    int xp = (xx == 127) ? 126 : xx + 1;
    const float* r0p = tin + r * 128;
    const float* r1p = r0p + 128;
    const float* r2p = r1p + 128;
    float acc = bias;
    acc = fmaf(w0, r0p[xm], acc); acc = fmaf(w1, r0p[xx], acc); acc = fmaf(w2, r0p[xp], acc);
    acc = fmaf(w3, r1p[xm], acc); acc = fmaf(w4, r1p[xx], acc); acc = fmaf(w5, r1p[xp], acc);
    acc = fmaf(w6, r2p[xm], acc); acc = fmaf(w7, r2p[xx], acc); acc = fmaf(w8, r2p[xp], acc);
    tdw[f] = acc;
  }
  __syncthreads();
  const float s = (float)(127.0 / 255.0);
  float* dst = out + (size_t)bc * 65536;
  for (int i = 0; i < 32; ++i) {
    int f = i * 256 + t;               // 8192 exactly: rows 2r0..2r0+31, cols 0..255
    int vr = f >> 8, vx = f & 255;
    int v = 2 * r0 + vr;
    float cy = (float)v * s;
    int ly = (int)floorf(cy); if (ly > 126) ly = 126;
    float wy = cy - (float)ly;
    float cx = (float)vx * s;
    int lx = (int)floorf(cx); if (lx > 126) lx = 126;
    float wx = cx - (float)lx;
    int lr = ly - r0 + 1;              // tdw row index
    float a  = tdw[lr * 128 + lx];
    float bq = tdw[lr * 128 + lx + 1];
    float c2 = tdw[(lr + 1) * 128 + lx];
    float d2 = tdw[(lr + 1) * 128 + lx + 1];
    float t0 = a  * (1.f - wy) + c2 * wy;   // y-lerp first (matches ref order)
    float t1 = bq * (1.f - wy) + d2 * wy;
    dst[v * 256 + vx] = t0 * (1.f - wx) + t1 * wx;
  }
}

extern "C" void kernel_launch(void* const* d_in, const int* in_sizes, int n_in,
                              void* d_out, int out_size, void* d_ws, size_t ws_size,
                              hipStream_t stream) {
  (void)in_sizes; (void)n_in; (void)out_size; (void)ws_size;
  const float* x        = (const float*)d_in[0];
  const float* qkv_w    = (const float*)d_in[1];
  const float* lce_w    = (const float*)d_in[2];
  const float* gate_w   = (const float*)d_in[3];
  const float* gate_b   = (const float*)d_in[4];
  const float* temp     = (const float*)d_in[5];
  const float* rel_h    = (const float*)d_in[6];
  const float* rel_w    = (const float*)d_in[7];
  const float* down_w   = (const float*)d_in[8];
  const float* down_b   = (const float*)d_in[9];
  const float* up_w     = (const float*)d_in[10];
  const float* up_b     = (const float*)d_in[11];
  const float* gating_w = (const float*)d_in[12];
  const float* gating_b = (const float*)d_in[13];
  const float* proj_w   = (const float*)d_in[14];
  const float* lp_w     = (const float*)d_in[15];
  const float* lp_b     = (const float*)d_in[16];
  float* fws = (float*)d_ws;
  float* outp = (float*)d_out;

  float* pre  = fws + PRE_OFF;
  float* qkv  = fws + QKV_OFF;
  float* khat = fws + KHAT_OFF;
  float* vpk  = fws + VPK_OFF;
  float* out3 = fws + OUT3_OFF;
  float* covp = fws + COVP_OFF;
  float* mean = fws + MEAN_OFF;
  int* idx = (int*)(fws + IDX_OFF);
  int* inv = (int*)(fws + INV_OFF);
  float* covs = fws + COVS_OFF;
  float* wT   = fws + WT_OFF;
  float* gT   = fws + GT2_OFF;
  float* dT   = fws + DT2_OFF;
  float* uT   = fws + UT2_OFF;
  float* pT   = fws + PT2_OFF;

  k_prep_wt<<<48, 256, 0, stream>>>(qkv_w, wT);
  k_pool_conv<<<1024, 256, 0, stream>>>(x, wT, pre);
  k_dw3x3_zero<<<49152, 256, 0, stream>>>(pre, lce_w, qkv);
  k_prep2<<<16, 256, 0, stream>>>(gating_w, down_w, up_w, proj_w, gT, dT, uT, pT);
  k_mean<<<256, 256, 0, stream>>>(qkv, mean);
  k_covpart<<<512, 256, 0, stream>>>(qkv, mean, covp);
  k_covred<<<64, 256, 0, stream>>>(covp, covs);
  k_simsort<<<4, 256, 0, stream>>>(covs, idx, inv);
  k_stage<<<4096, 64, 0, stream>>>(qkv, idx, rel_h, rel_w, khat, vpk);
  k_attn<<<4096, 64, 0, stream>>>(qkv, idx, khat, vpk, gate_w, gate_b, temp, qkv);
  k_post<<<1024, 256, 0, stream>>>(qkv, qkv, gT, gating_b, dT, down_b,
                                   uT, up_b, pT, out3);
  k_final<<<2048, 256, 0, stream>>>(out3, lp_w, lp_b, outp);
  (void)inv;
}

// Round 4
// 437.017 us; speedup vs baseline: 1.1008x; 1.0091x over previous
//
#include <hip/hip_runtime.h>
#include <math.h>

#define HWP 16384   // 128*128 pooled plane

// ---------------- workspace layout (float offsets) ----------------
// Lifetimes (same-stream serialization):
//   pre   [0, 12,582,912)          pool_conv -> dw3x3
//   cov   [0, ~2.12M)              mean -> simsort      (inside dead pre)
//   khat  [0, 6,553,600)           stage -> attn        (inside dead pre)
//   vpk   [6,553,600, 10,747,904)  stage -> attn        (inside dead pre)
//   out3  [0, 4,194,304)           post -> final        (staging dead)
//   tail  [12,570,112, 12,582,912) idx/inv + MLP weights, written only
//                                  after dw3x3, live through post
//   qkv   [12,582,912, 25,165,824) dw3x3 -> post; its V planes are dead
//                                  after k_stage and are overwritten IN
//                                  PLACE by k_attn's output (read by post).
static const size_t PRE_OFF  = 0;          // 12,582,912
static const size_t QKV_OFF  = 12582912;
// wT lives at the START of the QKV region: written by k_prep_wt, read only by
// k_pool_conv (which writes PRE only), then overwritten by k_dw3x3_zero.
static const size_t WT_OFF   = QKV_OFF;    // 12,288 floats
static const size_t COVP_OFF = 0;          // 2,097,152
static const size_t MEAN_OFF = 2097152;    // 256
static const size_t COVS_OFF = 2097408;    // 16,384 -> ends 2,113,792
static const size_t KHAT_OFF = 0;          // 6,553,600 (4096 tiles *100*16)
static const size_t VPK_OFF  = 6553600;    // 4,194,304 -> ends 10,747,904
static const size_t OUT3_OFF = 0;          // 4,194,304
static const size_t IDX_OFF  = 12570112;   // 256 ints
static const size_t INV_OFF  = 12570368;   // 256 ints
static const size_t GT2_OFF  = 12570624;   // 4096
static const size_t DT2_OFF  = 12574720;   // 2048
static const size_t UT2_OFF  = 12576768;   // 2048
static const size_t PT2_OFF  = 12578816;   // 4096 -> ends 12,582,912 exactly

// ---------------- 0: transpose qkv_w -> wT[c*192+o] ----------------
__global__ __launch_bounds__(256) void k_prep_wt(
    const float* __restrict__ qkv_w, float* __restrict__ wT) {
  int i = blockIdx.x * 256 + threadIdx.x;   // 12288
  int o = i >> 6, c = i & 63;
  wT[c * 192 + o] = qkv_w[i];
}

// ---------------- 0b: transpose MLP weights to d-major ----------------
__global__ __launch_bounds__(256) void k_prep2(
    const float* __restrict__ gating_w, const float* __restrict__ down_w,
    const float* __restrict__ up_w, const float* __restrict__ proj_w,
    float* __restrict__ gT, float* __restrict__ dT,
    float* __restrict__ uT, float* __restrict__ pT) {
  int t = blockIdx.x * 256 + threadIdx.x;
  if (t < 4096) {
    int o = t >> 6, d = t & 63;
    gT[d * 64 + o] = gating_w[t];
    pT[d * 64 + o] = proj_w[t];
  }
  if (t < 2048) {
    int o = t >> 6, d = t & 63;      // down_w (32,64)
    dT[d * 32 + o] = down_w[t];
    int o2 = t >> 5, d2 = t & 31;    // up_w (64,32)
    uT[d2 * 64 + o2] = up_w[t];
  }
}

// ---------------- 1: maxpool2 + conv1x1 (x -> qkv_pre) ----------------
__global__ __launch_bounds__(256) void k_pool_conv(
    const float* __restrict__ x, const float* __restrict__ wT,
    float* __restrict__ pre) {
  int b = blockIdx.x >> 8;          // 256 tiles / batch
  int pix0 = (blockIdx.x & 255) * 64;
  __shared__ float xt[64 * 64];     // [c][p]
  int t = threadIdx.x;
  for (int i = 0; i < 16; ++i) {
    int f = i * 256 + t;
    int c = f >> 6, p = f & 63;
    int pix = pix0 + p;
    int y = pix >> 7, xx = pix & 127;
    const float* src = x + ((size_t)(b * 64 + c) * 65536) + (2 * y) * 256 + 2 * xx;
    float2 v01 = *(const float2*)src;
    float2 v23 = *(const float2*)(src + 256);
    xt[c * 64 + p] = fmaxf(fmaxf(v01.x, v01.y), fmaxf(v23.x, v23.y));
  }
  __syncthreads();
  int p = t & 63;
  int obase = __builtin_amdgcn_readfirstlane((t >> 6) * 48);  // wave-uniform
  const float* wbase = wT + obase;
  float acc[48];
#pragma unroll
  for (int j = 0; j < 48; ++j) acc[j] = 0.f;
  for (int c = 0; c < 64; ++c) {
    float xv = xt[c * 64 + p];
    const float* wc = wbase + c * 192;    // uniform -> s_load_dwordx16 x3
#pragma unroll
    for (int j = 0; j < 48; ++j) acc[j] = fmaf(wc[j], xv, acc[j]);
  }
  float* dst = pre + ((size_t)b * 192 + obase) * HWP + pix0 + p;
#pragma unroll
  for (int j = 0; j < 48; ++j) dst[(size_t)j * HWP] = acc[j];
}

// ---------------- 2: depthwise 3x3, zero pad (pre -> qkv) ----------------
__global__ __launch_bounds__(256) void k_dw3x3_zero(
    const float* __restrict__ pre, const float* __restrict__ lce_w,
    float* __restrict__ qkv) {
  int gid = blockIdx.x * 256 + threadIdx.x;   // 4*192*16384 total
  int pix = gid & (HWP - 1);
  int bc = gid >> 14;
  int ch = bc % 192;
  int y = pix >> 7, xx = pix & 127;
  const float* w = lce_w + ch * 9;
  const float* base = pre + (size_t)bc * HWP;
  float acc = 0.f;
#pragma unroll
  for (int dy = -1; dy <= 1; ++dy) {
    int yy = y + dy;
    if (yy < 0 || yy > 127) continue;
#pragma unroll
    for (int dx = -1; dx <= 1; ++dx) {
      int xc = xx + dx;
      if (xc < 0 || xc > 127) continue;
      acc = fmaf(w[(dy + 1) * 3 + dx + 1], base[yy * 128 + xc], acc);
    }
  }
  qkv[gid] = acc;
}

// ---------------- 3a: per-channel mean of q ----------------
__global__ __launch_bounds__(256) void k_mean(
    const float* __restrict__ qkv, float* __restrict__ mean) {
  int bc = blockIdx.x;              // b*64 + c
  int b = bc >> 6, c = bc & 63;
  const float* src = qkv + ((size_t)b * 192 + c) * HWP;
  float s = 0.f;
  for (int i = threadIdx.x; i < HWP; i += 256) s += src[i];
  __shared__ float red[4];
  for (int off = 32; off > 0; off >>= 1) s += __shfl_down(s, off);
  int t = threadIdx.x;
  if ((t & 63) == 0) red[t >> 6] = s;
  __syncthreads();
  if (t == 0) mean[bc] = (red[0] + red[1] + red[2] + red[3]) * (1.f / 16384.f);
}

// ---------------- 3b: centered cov partials (chunks of 128) ----------------
__global__ __launch_bounds__(256) void k_covpart(
    const float* __restrict__ qkv, const float* __restrict__ mean,
    float* __restrict__ covp) {
  int blk = blockIdx.x;             // b*128 + chunk
  int b = blk >> 7, chunk = blk & 127;
  int e0 = chunk * 128;
  __shared__ float qc[64 * 129];    // +1 pad breaks stride conflicts
  int t = threadIdx.x;
  for (int i = 0; i < 32; ++i) {
    int f = i * 256 + t;
    int c = f >> 7, e = f & 127;
    qc[c * 129 + e] = qkv[((size_t)b * 192 + c) * HWP + e0 + e] - mean[b * 64 + c];
  }
  __syncthreads();
  int d = t & 63;
  int crow = t >> 6;                // wave-uniform
  float acc[16];
#pragma unroll
  for (int i = 0; i < 16; ++i) acc[i] = 0.f;
  for (int e = 0; e < 128; ++e) {
    float qd = qc[d * 129 + e];
#pragma unroll
    for (int i = 0; i < 16; ++i) {
      int c = crow + 4 * i;
      acc[i] = fmaf(qc[c * 129 + e], qd, acc[i]);
    }
  }
  float* dst = covp + (size_t)blk * 4096;
#pragma unroll
  for (int i = 0; i < 16; ++i) {
    int c = crow + 4 * i;
    dst[c * 64 + d] = acc[i];       // == dst[i*256 + t], coalesced
  }
}

// ---------------- 3b2: reduce cov partials over 128 chunks ----------------
__global__ __launch_bounds__(256) void k_covred(
    const float* __restrict__ covp, float* __restrict__ covs) {
  int blk = blockIdx.x;             // b*16 + j
  int b = blk >> 4;
  int pp = (blk & 15) * 256 + threadIdx.x;
  const float* src = covp + (size_t)b * 524288 + pp;
  float s = 0.f;
  for (int ch = 0; ch < 128; ++ch) s += src[ch * 4096];   // chunk order preserved
  covs[b * 4096 + pp] = s;
}

// ---------------- 3c: correlation-mean sim, stable rank ----------------
__global__ __launch_bounds__(256) void k_simsort(
    const float* __restrict__ covs_g, int* __restrict__ idx, int* __restrict__ inv) {
  int b = blockIdx.x;               // 4 blocks
  __shared__ float covs[4096];
  __shared__ float stds[64];
  __shared__ float sims[64];
  int t = threadIdx.x;
  for (int i = 0; i < 16; ++i) covs[i * 256 + t] = covs_g[b * 4096 + i * 256 + t];
  __syncthreads();
  if (t < 64) stds[t] = sqrtf(covs[t * 64 + t] + 1e-8f);
  __syncthreads();
  if (t < 64) {
    float s = 0.f;
    float sc = stds[t];
    for (int d2 = 0; d2 < 64; ++d2) {
      float denom = fmaxf(sc * stds[d2], 1e-8f);
      s += covs[d2 * 64 + t] / denom;   // symmetric matrix: bitwise equal to [t][d2]
    }
    sims[t] = s * (1.f / 64.f);
  }
  __syncthreads();
  if (t < 64) {
    float sv = sims[t];
    int r = 0;
    for (int d2 = 0; d2 < 64; ++d2) {
      float o = sims[d2];
      if (o > sv || (o == sv && d2 < t)) r++;
    }
    idx[b * 64 + r] = t;
    inv[b * 64 + t] = r;
  }
}

// ---------------- 6: stage K-hat (rel-added, l2-normalized) + packed V ----
// khat: [tile=bi][key 0..99][16ch]  (64B rows, wave-uniform in k_attn)
// vpk : [b*4+head][pos 0..16383][16ch] (no halo duplication; each pooled
//       position is interior to exactly one tile -> that tile writes it)
__global__ __launch_bounds__(64) void k_stage(
    const float* __restrict__ qkv, const int* __restrict__ idx,
    const float* __restrict__ rel_h, const float* __restrict__ rel_w,
    float* __restrict__ khat, float* __restrict__ vpk) {
  int bi = blockIdx.x;
  int head = bi & 3;
  int wj = (bi >> 2) & 15;
  int hi = (bi >> 6) & 15;
  int b = bi >> 10;
  int t = threadIdx.x;
  const size_t bb = (size_t)b * 192 * HWP;
  int chg[16];
#pragma unroll
  for (int ch = 0; ch < 16; ++ch) chg[ch] = idx[b * 64 + head * 16 + ch];
  // K rows: 100 halo positions
  for (int i = 0; i < 2; ++i) {
    int pos = i * 64 + t;
    if (pos < 100) {
      int py = pos / 10, px = pos - py * 10;
      int ky = hi * 8 + py - 1, kx = wj * 8 + px - 1;
      bool ok = (ky >= 0) && (ky < 128) && (kx >= 0) && (kx < 128);
      int sp = ky * 128 + kx;
      float kv[16];
      float s = 0.f;
#pragma unroll
      for (int ch = 0; ch < 16; ++ch) {
        float k = ok ? qkv[bb + (size_t)(64 + chg[ch]) * HWP + sp] : 0.f;
        k += (ch < 8) ? rel_h[(head * 10 + py) * 8 + ch]
                      : rel_w[(head * 10 + px) * 8 + (ch - 8)];
        kv[ch] = k;
        s += k * k;
      }
      float rn = 1.f / fmaxf(sqrtf(s), 1e-12f);   // ref: l2norm(k+rel) before dot
      float* kd = khat + ((size_t)bi * 100 + pos) * 16;
#pragma unroll
      for (int ch = 0; ch < 16; ++ch) kd[ch] = kv[ch] * rn;
    }
  }
  // V rows: this tile's 64 interior positions, gathered channel-packed
  int qy = hi * 8 + (t >> 3), qx = wj * 8 + (t & 7);
  int spq = qy * 128 + qx;
  float* vd = vpk + ((size_t)(b * 4 + head) * 16384 + spq) * 16;
#pragma unroll
  for (int ch = 0; ch < 16; ++ch)
    vd[ch] = qkv[bb + (size_t)(128 + chg[ch]) * HWP + spq];
}

// ---------------- 7: halo block attention + gate ----------------
// 2 waves per tile: wave 0 -> keys py 0..4, wave 1 -> keys py 5..9 (50 keys
// each). Round-3 post-mortem: removing libm expf EXPOSED scalar-load latency
// (VALUBusy fell to 25%, dur rose) — the 100-key loop is a serial chain of
// dependent s_load_dwordx16 pairs, and the grid only filled 16 of 32
// waves/CU. Halving the chain and doubling waves/CU (8192 waves = 32/CU)
// attacks the latency bound directly. Partials combine in LDS (one barrier);
// each wave then finishes 8 of the 16 output channels. Softmax split is a
// pure reassociation (same shift T for both halves).
__global__ __launch_bounds__(128) void k_attn(
    const float* __restrict__ qkv, const int* __restrict__ idx,
    const float* __restrict__ khat, const float* __restrict__ vpk,
    const float* __restrict__ gate_w, const float* __restrict__ gate_b,
    const float* __restrict__ temp, float* __restrict__ attn_out) {
  int bi = blockIdx.x;
  int head = bi & 3;
  int wj = (bi >> 2) & 15;
  int hi = (bi >> 6) & 15;
  int b = bi >> 10;
  int t = threadIdx.x & 63;                       // lane = query
  int w = __builtin_amdgcn_readfirstlane(threadIdx.x >> 6);  // wave 0/1
  __shared__ float po[2][16][64];                 // partial out
  __shared__ float pw[2][64];                     // partial wsum
  const size_t bb = (size_t)b * 192 * HWP;
  int chg[16];
#pragma unroll
  for (int ch = 0; ch < 16; ++ch) chg[ch] = idx[b * 64 + head * 16 + ch];
  int qy = hi * 8 + (t >> 3), qx = wj * 8 + (t & 7);
  float q[16];
  float qs = 0.f;
#pragma unroll
  for (int ch = 0; ch < 16; ++ch) {
    q[ch] = qkv[bb + (size_t)chg[ch] * HWP + qy * 128 + qx];
    qs += q[ch] * q[ch];
  }
  float T = expf(temp[head]);
  float qnT = T / fmaxf(sqrtf(qs), 1e-12f);
  const float* kb = khat + (size_t)bi * 1600;
  const float* vb = vpk + (size_t)(b * 4 + head) * (16384 * 16);
  float out[16];
#pragma unroll
  for (int ch = 0; ch < 16; ++ch) out[ch] = 0.f;
  float wsum = 0.f;
  for (int pyl = 0; pyl < 5; ++pyl) {
    int py = w * 5 + pyl;
    int ky = hi * 8 + py - 1;
    bool oky = (ky >= 0) && (ky < 128);
    const float* kprow = kb + py * 160;
    int spy = ky * 128;
    for (int px = 0; px < 10; ++px) {
      int kx = wj * 8 + px - 1;
      bool ok = oky && (kx >= 0) && (kx < 128);
      int sp = ok ? (spy + kx) : 0;               // clamp: OOB reads row 0, masked below
      const float* kp = kprow + px * 16;          // uniform -> s_load_dwordx16
      const float* vp = vb + (size_t)sp * 16;     // uniform -> s_load_dwordx16
      float d0 = 0.f, d1 = 0.f, d2 = 0.f, d3 = 0.f;
#pragma unroll
      for (int ch = 0; ch < 4; ++ch) {
        d0 = fmaf(q[ch], kp[ch], d0);
        d1 = fmaf(q[ch + 4], kp[ch + 4], d1);
        d2 = fmaf(q[ch + 8], kp[ch + 8], d2);
        d3 = fmaf(q[ch + 12], kp[ch + 12], d3);
      }
      float dacc = (d0 + d1) + (d2 + d3);
      float e = __expf(fmaf(dacc, qnT, -T));      // exp(d - T): exact softmax shift
      wsum += e;                                  // OOB keys DO count in denominator
      float ev = ok ? e : 0.f;                    // ...but contribute V=0
#pragma unroll
      for (int ch = 0; ch < 16; ++ch) out[ch] = fmaf(ev, vp[ch], out[ch]);
    }
  }
  pw[w][t] = wsum;
#pragma unroll
  for (int ch = 0; ch < 16; ++ch) po[w][ch][t] = out[ch];
  __syncthreads();
  float winv = 1.f / (pw[0][t] + pw[1][t]);
  int ob = w * 8;                                 // this wave's 8 outputs
#pragma unroll
  for (int i = 0; i < 8; ++i) {
    int o = ob + i;
    float oc = po[0][o][t] + po[1][o][t];
    float gsv = gate_b[head * 16 + o];
#pragma unroll
    for (int c = 0; c < 16; ++c)
      gsv = fmaf(gate_w[head * 256 + o * 16 + c], q[c], gsv);
    float sig = 1.f / (1.f + __expf(-gsv));
    attn_out[bb + (size_t)(128 + chg[o]) * HWP + qy * 128 + qx] = oc * winv * sig;
  }
}

// ---------------- 8: mixed -> gating -> down -> up -> (+attn) -> proj ----
// attn lives in the qkv V planes: channel c of batch b at (b*192+128+c)*HWP.
// 256 threads = 4 waves per block, 64 pixels per block (lane = pixel).
// Output channels are SPLIT ACROSS WAVES (16/wave; 8/wave for down): raises
// waves/CU from 4 to 16. Per-channel accumulator chain order (d ascending)
// is unchanged -> bitwise-identical results.
__global__ __launch_bounds__(256) void k_post(
    const float* __restrict__ attn, const float* __restrict__ qkv,
    const float* __restrict__ gT, const float* __restrict__ gating_b,
    const float* __restrict__ dT, const float* __restrict__ down_b,
    const float* __restrict__ uT, const float* __restrict__ up_b,
    const float* __restrict__ pT, float* __restrict__ out3) {
  __shared__ float xs[64 * 64];     // [c][pix]
  int t = threadIdx.x;
  int lane = t & 63;                // pixel within block
  int w = t >> 6;                   // wave 0..3 (uniform)
  int p = blockIdx.x * 64 + lane;   // global pooled pixel id
  int b = p >> 14;
  int pix = p & 16383;
  const float* ap = attn + ((size_t)b * 192 + 128) * HWP + pix;
  const float* qp = qkv + (size_t)b * 192 * HWP + pix;
  float* op = out3 + (size_t)b * 64 * HWP + pix;
  int ob16 = __builtin_amdgcn_readfirstlane(w * 16);
  int ob8  = __builtin_amdgcn_readfirstlane(w * 8);
  // mixed = attn_out + (q + k): each wave loads its 16 channels (concurrent)
#pragma unroll
  for (int i = 0; i < 16; ++i) {
    int c = ob16 + i;
    xs[c * 64 + lane] = ap[(size_t)c * HWP] + qp[(size_t)c * HWP] + qp[(size_t)(64 + c) * HWP];
  }
  __syncthreads();
  // ---- gating conv + exact gelu, * mixed ----
  {
    float acc[16];
#pragma unroll
    for (int o = 0; o < 16; ++o) acc[o] = gating_b[ob16 + o];
    for (int d = 0; d < 64; ++d) {
      float xv = xs[d * 64 + lane];
      const float* wd = gT + d * 64 + ob16;   // wave-uniform -> s_load
#pragma unroll
      for (int o = 0; o < 16; ++o) acc[o] = fmaf(wd[o], xv, acc[o]);
    }
    __syncthreads();                 // all reads done before any overwrite
#pragma unroll
    for (int o = 0; o < 16; ++o) {
      float a = acc[o];
      float ge = 0.5f * a * (1.f + erff(a * 0.70710678118654752f));
      xs[(ob16 + o) * 64 + lane] = ge * xs[(ob16 + o) * 64 + lane];
    }
    __syncthreads();
  }
  // ---- down 64->32 (8 outputs/wave) ----
  {
    float acc[8];
#pragma unroll
    for (int o = 0; o < 8; ++o) acc[o] = down_b[ob8 + o];
    for (int d = 0; d < 64; ++d) {
      float xv = xs[d * 64 + lane];
      const float* wd = dT + d * 32 + ob8;
#pragma unroll
      for (int o = 0; o < 8; ++o) acc[o] = fmaf(wd[o], xv, acc[o]);
    }
    __syncthreads();
#pragma unroll
    for (int o = 0; o < 8; ++o) xs[(ob8 + o) * 64 + lane] = acc[o];
    __syncthreads();
  }
  // ---- up 32->64, + attn residual ----
  {
    float acc[16];
#pragma unroll
    for (int o = 0; o < 16; ++o) acc[o] = up_b[ob16 + o];
    for (int d = 0; d < 32; ++d) {
      float xv = xs[d * 64 + lane];
      const float* wd = uT + d * 64 + ob16;
#pragma unroll
      for (int o = 0; o < 16; ++o) acc[o] = fmaf(wd[o], xv, acc[o]);
    }
    __syncthreads();
#pragma unroll
    for (int o = 0; o < 16; ++o)
      xs[(ob16 + o) * 64 + lane] = acc[o] + ap[(size_t)(ob16 + o) * HWP];
    __syncthreads();
  }
  // ---- proj (no bias) ----
  {
    float acc[16];
#pragma unroll
    for (int o = 0; o < 16; ++o) acc[o] = 0.f;
    for (int d = 0; d < 64; ++d) {
      float xv = xs[d * 64 + lane];
      const float* wd = pT + d * 64 + ob16;
#pragma unroll
      for (int o = 0; o < 16; ++o) acc[o] = fmaf(wd[o], xv, acc[o]);
    }
#pragma unroll
    for (int o = 0; o < 16; ++o) op[(size_t)(ob16 + o) * HWP] = acc[o];
  }
}

// ---------------- 9: dw3x3 reflect + bias + bilinear x2 (align-corners) ----
__global__ __launch_bounds__(256) void k_final(
    const float* __restrict__ out3, const float* __restrict__ lp_w,
    const float* __restrict__ lp_b, float* __restrict__ out) {
  int bi = blockIdx.x;                 // (b*64+ch)*8 + rt
  int rt = bi & 7;
  int bc = bi >> 3;
  int ch = bc & 63;
  int r0 = rt * 16;
  __shared__ float tin[20 * 128];      // input rows r0-2 .. r0+17 (reflected)
  __shared__ float tdw[18 * 128];      // dw rows r0-1 .. r0+16
  int t = threadIdx.x;
  const float* src = out3 + (size_t)bc * HWP;
  for (int i = 0; i < 10; ++i) {
    int f = i * 256 + t;               // 2560 exactly
    int r = f >> 7, xx = f & 127;
    int ry = r0 - 2 + r;
    ry = ry < 0 ? -ry : (ry > 127 ? 254 - ry : ry);
    tin[f] = src[ry * 128 + xx];
  }
  __syncthreads();
  float w0 = lp_w[ch * 9 + 0], w1 = lp_w[ch * 9 + 1], w2 = lp_w[ch * 9 + 2];
  float w3 = lp_w[ch * 9 + 3], w4 = lp_w[ch * 9 + 4], w5 = lp_w[ch * 9 + 5];
  float w6 = lp_w[ch * 9 + 6], w7 = lp_w[ch * 9 + 7], w8 = lp_w[ch * 9 + 8];
  float bias = lp_b[ch];
  for (int i = 0; i < 9; ++i) {
    int f = i * 256 + t;               // 2304 exactly
    int r = f >> 7, xx = f & 127;
    int xm = (xx == 0) ? 1 : xx - 1;
    int xp = (xx == 127) ? 126 : xx + 1;
    const float* r0p = tin + r * 128;
    const float* r1p = r0p + 128;
    const float* r2p = r1p + 128;
    float acc = bias;
    acc = fmaf(w0, r0p[xm], acc); acc = fmaf(w1, r0p[xx], acc); acc = fmaf(w2, r0p[xp], acc);
    acc = fmaf(w3, r1p[xm], acc); acc = fmaf(w4, r1p[xx], acc); acc = fmaf(w5, r1p[xp], acc);
    acc = fmaf(w6, r2p[xm], acc); acc = fmaf(w7, r2p[xx], acc); acc = fmaf(w8, r2p[xp], acc);
    tdw[f] = acc;
  }
  __syncthreads();
  const float s = (float)(127.0 / 255.0);
  float* dst = out + (size_t)bc * 65536;
  for (int i = 0; i < 32; ++i) {
    int f = i * 256 + t;               // 8192 exactly: rows 2r0..2r0+31, cols 0..255
    int vr = f >> 8, vx = f & 255;
    int v = 2 * r0 + vr;
    float cy = (float)v * s;
    int ly = (int)floorf(cy); if (ly > 126) ly = 126;
    float wy = cy - (float)ly;
    float cx = (float)vx * s;
    int lx = (int)floorf(cx); if (lx > 126) lx = 126;
    float wx = cx - (float)lx;
    int lr = ly - r0 + 1;              // tdw row index
    float a  = tdw[lr * 128 + lx];
    float bq = tdw[lr * 128 + lx + 1];
    float c2 = tdw[(lr + 1) * 128 + lx];
    float d2 = tdw[(lr + 1) * 128 + lx + 1];
    float t0 = a  * (1.f - wy) + c2 * wy;   // y-lerp first (matches ref order)
    float t1 = bq * (1.f - wy) + d2 * wy;
    dst[v * 256 + vx] = t0 * (1.f - wx) + t1 * wx;
  }
}

extern "C" void kernel_launch(void* const* d_in, const int* in_sizes, int n_in,
                              void* d_out, int out_size, void* d_ws, size_t ws_size,
                              hipStream_t stream) {
  (void)in_sizes; (void)n_in; (void)out_size; (void)ws_size;
  const float* x        = (const float*)d_in[0];
  const float* qkv_w    = (const float*)d_in[1];
  const float* lce_w    = (const float*)d_in[2];
  const float* gate_w   = (const float*)d_in[3];
  const float* gate_b   = (const float*)d_in[4];
  const float* temp     = (const float*)d_in[5];
  const float* rel_h    = (const float*)d_in[6];
  const float* rel_w    = (const float*)d_in[7];
  const float* down_w   = (const float*)d_in[8];
  const float* down_b   = (const float*)d_in[9];
  const float* up_w     = (const float*)d_in[10];
  const float* up_b     = (const float*)d_in[11];
  const float* gating_w = (const float*)d_in[12];
  const float* gating_b = (const float*)d_in[13];
  const float* proj_w   = (const float*)d_in[14];
  const float* lp_w     = (const float*)d_in[15];
  const float* lp_b     = (const float*)d_in[16];
  float* fws = (float*)d_ws;
  float* outp = (float*)d_out;

  float* pre  = fws + PRE_OFF;
  float* qkv  = fws + QKV_OFF;
  float* khat = fws + KHAT_OFF;
  float* vpk  = fws + VPK_OFF;
  float* out3 = fws + OUT3_OFF;
  float* covp = fws + COVP_OFF;
  float* mean = fws + MEAN_OFF;
  int* idx = (int*)(fws + IDX_OFF);
  int* inv = (int*)(fws + INV_OFF);
  float* covs = fws + COVS_OFF;
  float* wT   = fws + WT_OFF;
  float* gT   = fws + GT2_OFF;
  float* dT   = fws + DT2_OFF;
  float* uT   = fws + UT2_OFF;
  float* pT   = fws + PT2_OFF;

  k_prep_wt<<<48, 256, 0, stream>>>(qkv_w, wT);
  k_pool_conv<<<1024, 256, 0, stream>>>(x, wT, pre);
  k_dw3x3_zero<<<49152, 256, 0, stream>>>(pre, lce_w, qkv);
  k_prep2<<<16, 256, 0, stream>>>(gating_w, down_w, up_w, proj_w, gT, dT, uT, pT);
  k_mean<<<256, 256, 0, stream>>>(qkv, mean);
  k_covpart<<<512, 256, 0, stream>>>(qkv, mean, covp);
  k_covred<<<64, 256, 0, stream>>>(covp, covs);
  k_simsort<<<4, 256, 0, stream>>>(covs, idx, inv);
  k_stage<<<4096, 64, 0, stream>>>(qkv, idx, rel_h, rel_w, khat, vpk);
  k_attn<<<4096, 128, 0, stream>>>(qkv, idx, khat, vpk, gate_w, gate_b, temp, qkv);
  k_post<<<1024, 256, 0, stream>>>(qkv, qkv, gT, gating_b, dT, down_b,
                                   uT, up_b, pT, out3);
  k_final<<<2048, 256, 0, stream>>>(out3, lp_w, lp_b, outp);
  (void)inv;
}

// Round 5
// 409.430 us; speedup vs baseline: 1.1750x; 1.0674x over previous
//
#include <hip/hip_runtime.h>
#include <math.h>

#define HWP 16384   // 128*128 pooled plane

// ---------------- workspace layout (float offsets) ----------------
// Lifetimes (same-stream serialization):
//   pre   [0, 12,582,912)          pool_conv -> dw3x3
//   cov   [0, ~2.12M)              mean -> simsort      (inside dead pre)
//   khat  [0, 6,553,600)           stage -> attn        (inside dead pre)
//   vpk   [6,553,600, 10,747,904)  stage -> attn        (inside dead pre)
//   out3  [0, 4,194,304)           post -> final        (staging dead)
//   tail  [12,570,112, 12,582,912) idx/inv + MLP weights, written only
//                                  after dw3x3, live through post
//   qkv   [12,582,912, 25,165,824) dw3x3 -> post; its V planes are dead
//                                  after k_stage and are overwritten IN
//                                  PLACE by k_attn's output (read by post).
static const size_t PRE_OFF  = 0;          // 12,582,912
static const size_t QKV_OFF  = 12582912;
// wT lives at the START of the QKV region: written by k_prep_wt, read only by
// k_pool_conv (which writes PRE only), then overwritten by k_dw3x3_zero.
static const size_t WT_OFF   = QKV_OFF;    // 12,288 floats
static const size_t COVP_OFF = 0;          // 2,097,152
static const size_t MEAN_OFF = 2097152;    // 256
static const size_t COVS_OFF = 2097408;    // 16,384 -> ends 2,113,792
static const size_t KHAT_OFF = 0;          // 6,553,600 (4096 tiles *100*16)
static const size_t VPK_OFF  = 6553600;    // 4,194,304 -> ends 10,747,904
static const size_t OUT3_OFF = 0;          // 4,194,304
static const size_t IDX_OFF  = 12570112;   // 256 ints
static const size_t INV_OFF  = 12570368;   // 256 ints
static const size_t GT2_OFF  = 12570624;   // 4096
static const size_t DT2_OFF  = 12574720;   // 2048
static const size_t UT2_OFF  = 12576768;   // 2048
static const size_t PT2_OFF  = 12578816;   // 4096 -> ends 12,582,912 exactly

// ---------------- 0: transpose qkv_w -> wT[c*192+o] ----------------
__global__ __launch_bounds__(256) void k_prep_wt(
    const float* __restrict__ qkv_w, float* __restrict__ wT) {
  int i = blockIdx.x * 256 + threadIdx.x;   // 12288
  int o = i >> 6, c = i & 63;
  wT[c * 192 + o] = qkv_w[i];
}

// ---------------- 0b: transpose MLP weights to d-major ----------------
__global__ __launch_bounds__(256) void k_prep2(
    const float* __restrict__ gating_w, const float* __restrict__ down_w,
    const float* __restrict__ up_w, const float* __restrict__ proj_w,
    float* __restrict__ gT, float* __restrict__ dT,
    float* __restrict__ uT, float* __restrict__ pT) {
  int t = blockIdx.x * 256 + threadIdx.x;
  if (t < 4096) {
    int o = t >> 6, d = t & 63;
    gT[d * 64 + o] = gating_w[t];
    pT[d * 64 + o] = proj_w[t];
  }
  if (t < 2048) {
    int o = t >> 6, d = t & 63;      // down_w (32,64)
    dT[d * 32 + o] = down_w[t];
    int o2 = t >> 5, d2 = t & 31;    // up_w (64,32)
    uT[d2 * 64 + o2] = up_w[t];
  }
}

// ---------------- 1: maxpool2 + conv1x1 (x -> qkv_pre) ----------------
__global__ __launch_bounds__(256) void k_pool_conv(
    const float* __restrict__ x, const float* __restrict__ wT,
    float* __restrict__ pre) {
  int b = blockIdx.x >> 8;          // 256 tiles / batch
  int pix0 = (blockIdx.x & 255) * 64;
  __shared__ float xt[64 * 64];     // [c][p]
  int t = threadIdx.x;
  for (int i = 0; i < 16; ++i) {
    int f = i * 256 + t;
    int c = f >> 6, p = f & 63;
    int pix = pix0 + p;
    int y = pix >> 7, xx = pix & 127;
    const float* src = x + ((size_t)(b * 64 + c) * 65536) + (2 * y) * 256 + 2 * xx;
    float2 v01 = *(const float2*)src;
    float2 v23 = *(const float2*)(src + 256);
    xt[c * 64 + p] = fmaxf(fmaxf(v01.x, v01.y), fmaxf(v23.x, v23.y));
  }
  __syncthreads();
  int p = t & 63;
  int obase = __builtin_amdgcn_readfirstlane((t >> 6) * 48);  // wave-uniform
  const float* wbase = wT + obase;
  float acc[48];
#pragma unroll
  for (int j = 0; j < 48; ++j) acc[j] = 0.f;
  for (int c = 0; c < 64; ++c) {
    float xv = xt[c * 64 + p];
    const float* wc = wbase + c * 192;    // uniform -> s_load_dwordx16 x3
#pragma unroll
    for (int j = 0; j < 48; ++j) acc[j] = fmaf(wc[j], xv, acc[j]);
  }
  float* dst = pre + ((size_t)b * 192 + obase) * HWP + pix0 + p;
#pragma unroll
  for (int j = 0; j < 48; ++j) dst[(size_t)j * HWP] = acc[j];
}

// ---------------- 2: depthwise 3x3, zero pad (pre -> qkv) ----------------
__global__ __launch_bounds__(256) void k_dw3x3_zero(
    const float* __restrict__ pre, const float* __restrict__ lce_w,
    float* __restrict__ qkv) {
  int gid = blockIdx.x * 256 + threadIdx.x;   // 4*192*16384 total
  int pix = gid & (HWP - 1);
  int bc = gid >> 14;
  int ch = bc % 192;
  int y = pix >> 7, xx = pix & 127;
  const float* w = lce_w + ch * 9;
  const float* base = pre + (size_t)bc * HWP;
  float acc = 0.f;
#pragma unroll
  for (int dy = -1; dy <= 1; ++dy) {
    int yy = y + dy;
    if (yy < 0 || yy > 127) continue;
#pragma unroll
    for (int dx = -1; dx <= 1; ++dx) {
      int xc = xx + dx;
      if (xc < 0 || xc > 127) continue;
      acc = fmaf(w[(dy + 1) * 3 + dx + 1], base[yy * 128 + xc], acc);
    }
  }
  qkv[gid] = acc;
}

// ---------------- 3a: per-channel mean of q ----------------
__global__ __launch_bounds__(256) void k_mean(
    const float* __restrict__ qkv, float* __restrict__ mean) {
  int bc = blockIdx.x;              // b*64 + c
  int b = bc >> 6, c = bc & 63;
  const float* src = qkv + ((size_t)b * 192 + c) * HWP;
  float s = 0.f;
  for (int i = threadIdx.x; i < HWP; i += 256) s += src[i];
  __shared__ float red[4];
  for (int off = 32; off > 0; off >>= 1) s += __shfl_down(s, off);
  int t = threadIdx.x;
  if ((t & 63) == 0) red[t >> 6] = s;
  __syncthreads();
  if (t == 0) mean[bc] = (red[0] + red[1] + red[2] + red[3]) * (1.f / 16384.f);
}

// ---------------- 3b: centered cov partials (chunks of 128) ----------------
__global__ __launch_bounds__(256) void k_covpart(
    const float* __restrict__ qkv, const float* __restrict__ mean,
    float* __restrict__ covp) {
  int blk = blockIdx.x;             // b*128 + chunk
  int b = blk >> 7, chunk = blk & 127;
  int e0 = chunk * 128;
  __shared__ float qc[64 * 129];    // +1 pad breaks stride conflicts
  int t = threadIdx.x;
  for (int i = 0; i < 32; ++i) {
    int f = i * 256 + t;
    int c = f >> 7, e = f & 127;
    qc[c * 129 + e] = qkv[((size_t)b * 192 + c) * HWP + e0 + e] - mean[b * 64 + c];
  }
  __syncthreads();
  int d = t & 63;
  int crow = t >> 6;                // wave-uniform
  float acc[16];
#pragma unroll
  for (int i = 0; i < 16; ++i) acc[i] = 0.f;
  for (int e = 0; e < 128; ++e) {
    float qd = qc[d * 129 + e];
#pragma unroll
    for (int i = 0; i < 16; ++i) {
      int c = crow + 4 * i;
      acc[i] = fmaf(qc[c * 129 + e], qd, acc[i]);
    }
  }
  float* dst = covp + (size_t)blk * 4096;
#pragma unroll
  for (int i = 0; i < 16; ++i) {
    int c = crow + 4 * i;
    dst[c * 64 + d] = acc[i];       // == dst[i*256 + t], coalesced
  }
}

// ---------------- 3b2: reduce cov partials over 128 chunks ----------------
__global__ __launch_bounds__(256) void k_covred(
    const float* __restrict__ covp, float* __restrict__ covs) {
  int blk = blockIdx.x;             // b*16 + j
  int b = blk >> 4;
  int pp = (blk & 15) * 256 + threadIdx.x;
  const float* src = covp + (size_t)b * 524288 + pp;
  float s = 0.f;
  for (int ch = 0; ch < 128; ++ch) s += src[ch * 4096];   // chunk order preserved
  covs[b * 4096 + pp] = s;
}

// ---------------- 3c: correlation-mean sim, stable rank ----------------
__global__ __launch_bounds__(256) void k_simsort(
    const float* __restrict__ covs_g, int* __restrict__ idx, int* __restrict__ inv) {
  int b = blockIdx.x;               // 4 blocks
  __shared__ float covs[4096];
  __shared__ float stds[64];
  __shared__ float sims[64];
  int t = threadIdx.x;
  for (int i = 0; i < 16; ++i) covs[i * 256 + t] = covs_g[b * 4096 + i * 256 + t];
  __syncthreads();
  if (t < 64) stds[t] = sqrtf(covs[t * 64 + t] + 1e-8f);
  __syncthreads();
  if (t < 64) {
    float s = 0.f;
    float sc = stds[t];
    for (int d2 = 0; d2 < 64; ++d2) {
      float denom = fmaxf(sc * stds[d2], 1e-8f);
      s += covs[d2 * 64 + t] / denom;   // symmetric matrix: bitwise equal to [t][d2]
    }
    sims[t] = s * (1.f / 64.f);
  }
  __syncthreads();
  if (t < 64) {
    float sv = sims[t];
    int r = 0;
    for (int d2 = 0; d2 < 64; ++d2) {
      float o = sims[d2];
      if (o > sv || (o == sv && d2 < t)) r++;
    }
    idx[b * 64 + r] = t;
    inv[b * 64 + t] = r;
  }
}

// ---------------- 6: stage K-hat (rel-added, l2-normalized) + packed V ----
// khat: [tile=bi][key 0..99][16ch]  (64B rows)
// vpk : [b*4+head][pos 0..16383][16ch] (no halo duplication; each pooled
//       position is interior to exactly one tile -> that tile writes it)
__global__ __launch_bounds__(64) void k_stage(
    const float* __restrict__ qkv, const int* __restrict__ idx,
    const float* __restrict__ rel_h, const float* __restrict__ rel_w,
    float* __restrict__ khat, float* __restrict__ vpk) {
  int bi = blockIdx.x;
  int head = bi & 3;
  int wj = (bi >> 2) & 15;
  int hi = (bi >> 6) & 15;
  int b = bi >> 10;
  int t = threadIdx.x;
  const size_t bb = (size_t)b * 192 * HWP;
  int chg[16];
#pragma unroll
  for (int ch = 0; ch < 16; ++ch) chg[ch] = idx[b * 64 + head * 16 + ch];
  // K rows: 100 halo positions
  for (int i = 0; i < 2; ++i) {
    int pos = i * 64 + t;
    if (pos < 100) {
      int py = pos / 10, px = pos - py * 10;
      int ky = hi * 8 + py - 1, kx = wj * 8 + px - 1;
      bool ok = (ky >= 0) && (ky < 128) && (kx >= 0) && (kx < 128);
      int sp = ky * 128 + kx;
      float kv[16];
      float s = 0.f;
#pragma unroll
      for (int ch = 0; ch < 16; ++ch) {
        float k = ok ? qkv[bb + (size_t)(64 + chg[ch]) * HWP + sp] : 0.f;
        k += (ch < 8) ? rel_h[(head * 10 + py) * 8 + ch]
                      : rel_w[(head * 10 + px) * 8 + (ch - 8)];
        kv[ch] = k;
        s += k * k;
      }
      float rn = 1.f / fmaxf(sqrtf(s), 1e-12f);   // ref: l2norm(k+rel) before dot
      float* kd = khat + ((size_t)bi * 100 + pos) * 16;
#pragma unroll
      for (int ch = 0; ch < 16; ++ch) kd[ch] = kv[ch] * rn;
    }
  }
  // V rows: this tile's 64 interior positions, gathered channel-packed
  int qy = hi * 8 + (t >> 3), qx = wj * 8 + (t & 7);
  int spq = qy * 128 + qx;
  float* vd = vpk + ((size_t)(b * 4 + head) * 16384 + spq) * 16;
#pragma unroll
  for (int ch = 0; ch < 16; ++ch)
    vd[ch] = qkv[bb + (size_t)(128 + chg[ch]) * HWP + spq];
}

// ---------------- 7: halo block attention + gate ----------------
// Round-5 post-mortem chain: r2-r4 all pinned at ~77us = hbm_bytes/1.07TB/s.
// The K/V reads were wave-uniform s_load_dwordx16: 64B/request, ~4 in flight
// per wave -> Little's-law cap ~1.1 TB/s on the SCALAR path. Fix: stage the
// tile's K (6.4KB) + V (6.4KB) into LDS once via per-lane float4 VECTOR
// loads (16-64 cachelines in flight per instruction), then the 50-key inner
// loop reads LDS broadcasts (conflict-free) as direct FMA operands. OOB keys
// get V=0 at stage time -> no mask in the inner loop. The po/pw combine
// buffer OVERLAYS the dead kr region after a barrier -> LDS = 12.8KB ->
// 12 blocks/CU = 24 waves/CU. Numerics identical to round 4.
__global__ __launch_bounds__(128) void k_attn(
    const float* __restrict__ qkv, const int* __restrict__ idx,
    const float* __restrict__ khat, const float* __restrict__ vpk,
    const float* __restrict__ gate_w, const float* __restrict__ gate_b,
    const float* __restrict__ temp, float* __restrict__ attn_out) {
  int bi = blockIdx.x;
  int head = bi & 3;
  int wj = (bi >> 2) & 15;
  int hi = (bi >> 6) & 15;
  int b = bi >> 10;
  int tt = threadIdx.x;                            // 0..127
  int t = tt & 63;                                 // lane = query
  int w = __builtin_amdgcn_readfirstlane(tt >> 6); // wave 0/1
  __shared__ __align__(16) float smem[3200];       // kr[100][16] | vr[100][16]
  float* kr = smem;                                // 1600 floats
  float* vr = smem + 1600;                         // 1600 floats
  const size_t bb = (size_t)b * 192 * HWP;
  // ---- stage K: contiguous 6.4KB, fully coalesced float4 ----
  const float* kg = khat + (size_t)bi * 1600;
  for (int f = tt; f < 400; f += 128)
    ((float4*)kr)[f] = ((const float4*)kg)[f];
  // ---- stage V: per-lane float4 of scattered 64B rows (high MLP) ----
  const float* vb = vpk + (size_t)(b * 4 + head) * (16384 * 16);
  for (int f = tt; f < 400; f += 128) {
    int pos = f >> 2, comp = f & 3;
    int py = pos / 10, px = pos - py * 10;
    int ky = hi * 8 + py - 1, kx = wj * 8 + px - 1;
    bool ok = (ky >= 0) && (ky < 128) && (kx >= 0) && (kx < 128);
    float4 v = make_float4(0.f, 0.f, 0.f, 0.f);
    if (ok) v = ((const float4*)(vb + (size_t)(ky * 128 + kx) * 16))[comp];
    ((float4*)vr)[f] = v;                          // OOB rows -> zeros
  }
  // ---- per-query q (overlaps staging latency) ----
  int chg[16];
#pragma unroll
  for (int ch = 0; ch < 16; ++ch) chg[ch] = idx[b * 64 + head * 16 + ch];
  int qy = hi * 8 + (t >> 3), qx = wj * 8 + (t & 7);
  float q[16];
  float qs = 0.f;
#pragma unroll
  for (int ch = 0; ch < 16; ++ch) {
    q[ch] = qkv[bb + (size_t)chg[ch] * HWP + qy * 128 + qx];
    qs += q[ch] * q[ch];
  }
  float T = expf(temp[head]);
  float qnT = T / fmaxf(sqrtf(qs), 1e-12f);
  __syncthreads();
  // ---- 50 keys per wave, all operands from LDS broadcasts ----
  float out[16];
#pragma unroll
  for (int ch = 0; ch < 16; ++ch) out[ch] = 0.f;
  float wsum = 0.f;
  for (int pyl = 0; pyl < 5; ++pyl) {
    int py = w * 5 + pyl;
    const float* kp0 = kr + py * 160;
    const float* vp0 = vr + py * 160;
    for (int px = 0; px < 10; ++px) {
      const float* kp = kp0 + px * 16;
      const float* vp = vp0 + px * 16;
      float d0 = 0.f, d1 = 0.f, d2 = 0.f, d3 = 0.f;
#pragma unroll
      for (int ch = 0; ch < 4; ++ch) {
        d0 = fmaf(q[ch], kp[ch], d0);
        d1 = fmaf(q[ch + 4], kp[ch + 4], d1);
        d2 = fmaf(q[ch + 8], kp[ch + 8], d2);
        d3 = fmaf(q[ch + 12], kp[ch + 12], d3);
      }
      float dacc = (d0 + d1) + (d2 + d3);
      float e = __expf(fmaf(dacc, qnT, -T));      // exp(d - T): exact softmax shift
      wsum += e;                                  // OOB keys count in denominator
#pragma unroll
      for (int ch = 0; ch < 16; ++ch)
        out[ch] = fmaf(e, vp[ch], out[ch]);       // OOB rows are zero -> no mask
    }
  }
  // ---- cross-wave combine: po/pw overlay the dead kr region ----
  __syncthreads();                 // both waves done reading kr/vr
  float* po = smem;                // [2][16][64] = 2048 floats
  float* pwp = smem + 2048;        // [2][64]
  pwp[w * 64 + t] = wsum;
#pragma unroll
  for (int ch = 0; ch < 16; ++ch) po[(w * 16 + ch) * 64 + t] = out[ch];
  __syncthreads();
  float winv = 1.f / (pwp[t] + pwp[64 + t]);
  int ob = w * 8;                                 // this wave's 8 outputs
#pragma unroll
  for (int i = 0; i < 8; ++i) {
    int o = ob + i;
    float oc = po[o * 64 + t] + po[(16 + o) * 64 + t];
    float gsv = gate_b[head * 16 + o];
#pragma unroll
    for (int c = 0; c < 16; ++c)
      gsv = fmaf(gate_w[head * 256 + o * 16 + c], q[c], gsv);
    float sig = 1.f / (1.f + __expf(-gsv));
    attn_out[bb + (size_t)(128 + chg[o]) * HWP + qy * 128 + qx] = oc * winv * sig;
  }
}

// ---------------- 8: mixed -> gating -> down -> up -> (+attn) -> proj ----
// attn lives in the qkv V planes: channel c of batch b at (b*192+128+c)*HWP.
// 256 threads = 4 waves per block, 64 pixels per block (lane = pixel).
// Output channels are SPLIT ACROSS WAVES (16/wave; 8/wave for down): raises
// waves/CU from 4 to 16. Per-channel accumulator chain order (d ascending)
// is unchanged -> bitwise-identical results.
__global__ __launch_bounds__(256) void k_post(
    const float* __restrict__ attn, const float* __restrict__ qkv,
    const float* __restrict__ gT, const float* __restrict__ gating_b,
    const float* __restrict__ dT, const float* __restrict__ down_b,
    const float* __restrict__ uT, const float* __restrict__ up_b,
    const float* __restrict__ pT, float* __restrict__ out3) {
  __shared__ float xs[64 * 64];     // [c][pix]
  int t = threadIdx.x;
  int lane = t & 63;                // pixel within block
  int w = t >> 6;                   // wave 0..3 (uniform)
  int p = blockIdx.x * 64 + lane;   // global pooled pixel id
  int b = p >> 14;
  int pix = p & 16383;
  const float* ap = attn + ((size_t)b * 192 + 128) * HWP + pix;
  const float* qp = qkv + (size_t)b * 192 * HWP + pix;
  float* op = out3 + (size_t)b * 64 * HWP + pix;
  int ob16 = __builtin_amdgcn_readfirstlane(w * 16);
  int ob8  = __builtin_amdgcn_readfirstlane(w * 8);
  // mixed = attn_out + (q + k): each wave loads its 16 channels (concurrent)
#pragma unroll
  for (int i = 0; i < 16; ++i) {
    int c = ob16 + i;
    xs[c * 64 + lane] = ap[(size_t)c * HWP] + qp[(size_t)c * HWP] + qp[(size_t)(64 + c) * HWP];
  }
  __syncthreads();
  // ---- gating conv + exact gelu, * mixed ----
  {
    float acc[16];
#pragma unroll
    for (int o = 0; o < 16; ++o) acc[o] = gating_b[ob16 + o];
    for (int d = 0; d < 64; ++d) {
      float xv = xs[d * 64 + lane];
      const float* wd = gT + d * 64 + ob16;   // wave-uniform -> s_load
#pragma unroll
      for (int o = 0; o < 16; ++o) acc[o] = fmaf(wd[o], xv, acc[o]);
    }
    __syncthreads();                 // all reads done before any overwrite
#pragma unroll
    for (int o = 0; o < 16; ++o) {
      float a = acc[o];
      float ge = 0.5f * a * (1.f + erff(a * 0.70710678118654752f));
      xs[(ob16 + o) * 64 + lane] = ge * xs[(ob16 + o) * 64 + lane];
    }
    __syncthreads();
  }
  // ---- down 64->32 (8 outputs/wave) ----
  {
    float acc[8];
#pragma unroll
    for (int o = 0; o < 8; ++o) acc[o] = down_b[ob8 + o];
    for (int d = 0; d < 64; ++d) {
      float xv = xs[d * 64 + lane];
      const float* wd = dT + d * 32 + ob8;
#pragma unroll
      for (int o = 0; o < 8; ++o) acc[o] = fmaf(wd[o], xv, acc[o]);
    }
    __syncthreads();
#pragma unroll
    for (int o = 0; o < 8; ++o) xs[(ob8 + o) * 64 + lane] = acc[o];
    __syncthreads();
  }
  // ---- up 32->64, + attn residual ----
  {
    float acc[16];
#pragma unroll
    for (int o = 0; o < 16; ++o) acc[o] = up_b[ob16 + o];
    for (int d = 0; d < 32; ++d) {
      float xv = xs[d * 64 + lane];
      const float* wd = uT + d * 64 + ob16;
#pragma unroll
      for (int o = 0; o < 16; ++o) acc[o] = fmaf(wd[o], xv, acc[o]);
    }
    __syncthreads();
#pragma unroll
    for (int o = 0; o < 16; ++o)
      xs[(ob16 + o) * 64 + lane] = acc[o] + ap[(size_t)(ob16 + o) * HWP];
    __syncthreads();
  }
  // ---- proj (no bias) ----
  {
    float acc[16];
#pragma unroll
    for (int o = 0; o < 16; ++o) acc[o] = 0.f;
    for (int d = 0; d < 64; ++d) {
      float xv = xs[d * 64 + lane];
      const float* wd = pT + d * 64 + ob16;
#pragma unroll
      for (int o = 0; o < 16; ++o) acc[o] = fmaf(wd[o], xv, acc[o]);
    }
#pragma unroll
    for (int o = 0; o < 16; ++o) op[(size_t)(ob16 + o) * HWP] = acc[o];
  }
}

// ---------------- 9: dw3x3 reflect + bias + bilinear x2 (align-corners) ----
__global__ __launch_bounds__(256) void k_final(
    const float* __restrict__ out3, const float* __restrict__ lp_w,
    const float* __restrict__ lp_b, float* __restrict__ out) {
  int bi = blockIdx.x;                 // (b*64+ch)*8 + rt
  int rt = bi & 7;
  int bc = bi >> 3;
  int ch = bc & 63;
  int r0 = rt * 16;
  __shared__ float tin[20 * 128];      // input rows r0-2 .. r0+17 (reflected)
  __shared__ float tdw[18 * 128];      // dw rows r0-1 .. r0+16
  int t = threadIdx.x;
  const float* src = out3 + (size_t)bc * HWP;
  for (int i = 0; i < 10; ++i) {
    int f = i * 256 + t;               // 2560 exactly
    int r = f >> 7, xx = f & 127;
    int ry = r0 - 2 + r;
    ry = ry < 0 ? -ry : (ry > 127 ? 254 - ry : ry);
    tin[f] = src[ry * 128 + xx];
  }
  __syncthreads();
  float w0 = lp_w[ch * 9 + 0], w1 = lp_w[ch * 9 + 1], w2 = lp_w[ch * 9 + 2];
  float w3 = lp_w[ch * 9 + 3], w4 = lp_w[ch * 9 + 4], w5 = lp_w[ch * 9 + 5];
  float w6 = lp_w[ch * 9 + 6], w7 = lp_w[ch * 9 + 7], w8 = lp_w[ch * 9 + 8];
  float bias = lp_b[ch];
  for (int i = 0; i < 9; ++i) {
    int f = i * 256 + t;               // 2304 exactly
    int r = f >> 7, xx = f & 127;
    int xm = (xx == 0) ? 1 : xx - 1;
    int xp = (xx == 127) ? 126 : xx + 1;
    const float* r0p = tin + r * 128;
    const float* r1p = r0p + 128;
    const float* r2p = r1p + 128;
    float acc = bias;
    acc = fmaf(w0, r0p[xm], acc); acc = fmaf(w1, r0p[xx], acc); acc = fmaf(w2, r0p[xp], acc);
    acc = fmaf(w3, r1p[xm], acc); acc = fmaf(w4, r1p[xx], acc); acc = fmaf(w5, r1p[xp], acc);
    acc = fmaf(w6, r2p[xm], acc); acc = fmaf(w7, r2p[xx], acc); acc = fmaf(w8, r2p[xp], acc);
    tdw[f] = acc;
  }
  __syncthreads();
  const float s = (float)(127.0 / 255.0);
  float* dst = out + (size_t)bc * 65536;
  for (int i = 0; i < 32; ++i) {
    int f = i * 256 + t;               // 8192 exactly: rows 2r0..2r0+31, cols 0..255
    int vr = f >> 8, vx = f & 255;
    int v = 2 * r0 + vr;
    float cy = (float)v * s;
    int ly = (int)floorf(cy); if (ly > 126) ly = 126;
    float wy = cy - (float)ly;
    float cx = (float)vx * s;
    int lx = (int)floorf(cx); if (lx > 126) lx = 126;
    float wx = cx - (float)lx;
    int lr = ly - r0 + 1;              // tdw row index
    float a  = tdw[lr * 128 + lx];
    float bq = tdw[lr * 128 + lx + 1];
    float c2 = tdw[(lr + 1) * 128 + lx];
    float d2 = tdw[(lr + 1) * 128 + lx + 1];
    float t0 = a  * (1.f - wy) + c2 * wy;   // y-lerp first (matches ref order)
    float t1 = bq * (1.f - wy) + d2 * wy;
    dst[v * 256 + vx] = t0 * (1.f - wx) + t1 * wx;
  }
}

extern "C" void kernel_launch(void* const* d_in, const int* in_sizes, int n_in,
                              void* d_out, int out_size, void* d_ws, size_t ws_size,
                              hipStream_t stream) {
  (void)in_sizes; (void)n_in; (void)out_size; (void)ws_size;
  const float* x        = (const float*)d_in[0];
  const float* qkv_w    = (const float*)d_in[1];
  const float* lce_w    = (const float*)d_in[2];
  const float* gate_w   = (const float*)d_in[3];
  const float* gate_b   = (const float*)d_in[4];
  const float* temp     = (const float*)d_in[5];
  const float* rel_h    = (const float*)d_in[6];
  const float* rel_w    = (const float*)d_in[7];
  const float* down_w   = (const float*)d_in[8];
  const float* down_b   = (const float*)d_in[9];
  const float* up_w     = (const float*)d_in[10];
  const float* up_b     = (const float*)d_in[11];
  const float* gating_w = (const float*)d_in[12];
  const float* gating_b = (const float*)d_in[13];
  const float* proj_w   = (const float*)d_in[14];
  const float* lp_w     = (const float*)d_in[15];
  const float* lp_b     = (const float*)d_in[16];
  float* fws = (float*)d_ws;
  float* outp = (float*)d_out;

  float* pre  = fws + PRE_OFF;
  float* qkv  = fws + QKV_OFF;
  float* khat = fws + KHAT_OFF;
  float* vpk  = fws + VPK_OFF;
  float* out3 = fws + OUT3_OFF;
  float* covp = fws + COVP_OFF;
  float* mean = fws + MEAN_OFF;
  int* idx = (int*)(fws + IDX_OFF);
  int* inv = (int*)(fws + INV_OFF);
  float* covs = fws + COVS_OFF;
  float* wT   = fws + WT_OFF;
  float* gT   = fws + GT2_OFF;
  float* dT   = fws + DT2_OFF;
  float* uT   = fws + UT2_OFF;
  float* pT   = fws + PT2_OFF;

  k_prep_wt<<<48, 256, 0, stream>>>(qkv_w, wT);
  k_pool_conv<<<1024, 256, 0, stream>>>(x, wT, pre);
  k_dw3x3_zero<<<49152, 256, 0, stream>>>(pre, lce_w, qkv);
  k_prep2<<<16, 256, 0, stream>>>(gating_w, down_w, up_w, proj_w, gT, dT, uT, pT);
  k_mean<<<256, 256, 0, stream>>>(qkv, mean);
  k_covpart<<<512, 256, 0, stream>>>(qkv, mean, covp);
  k_covred<<<64, 256, 0, stream>>>(covp, covs);
  k_simsort<<<4, 256, 0, stream>>>(covs, idx, inv);
  k_stage<<<4096, 64, 0, stream>>>(qkv, idx, rel_h, rel_w, khat, vpk);
  k_attn<<<4096, 128, 0, stream>>>(qkv, idx, khat, vpk, gate_w, gate_b, temp, qkv);
  k_post<<<1024, 256, 0, stream>>>(qkv, qkv, gT, gating_b, dT, down_b,
                                   uT, up_b, pT, out3);
  k_final<<<2048, 256, 0, stream>>>(out3, lp_w, lp_b, outp);
  (void)inv;
}

// Round 7
// 399.312 us; speedup vs baseline: 1.2047x; 1.0253x over previous
//
#include <hip/hip_runtime.h>
#include <math.h>

#define HWP 16384   // 128*128 pooled plane

// ---------------- workspace layout (float offsets) ----------------
// Lifetimes (same-stream serialization):
//   pre   [0, 12,582,912)          pool_conv -> dw3x3
//   cov   [0, ~2.12M)              mean -> simsort      (inside dead pre)
//   khat  [0, 6,553,600)           stage -> attn        (inside dead pre)
//   vpk   [6,553,600, 10,747,904)  stage -> attn        (inside dead pre)
//   out3  [0, 4,194,304)           post -> final        (staging dead)
//   tail  [12,570,112, 12,582,912) idx/inv + MLP weights, written only
//                                  after dw3x3, live through post
//   qkv   [12,582,912, 25,165,824) dw3x3 -> post; its V planes are dead
//                                  after k_stage and are overwritten IN
//                                  PLACE by k_attn's output (read by post).
static const size_t PRE_OFF  = 0;          // 12,582,912
static const size_t QKV_OFF  = 12582912;
// wT lives at the START of the QKV region: written by k_prep_wt, read only by
// k_pool_conv (which writes PRE only), then overwritten by k_dw3x3_zero.
static const size_t WT_OFF   = QKV_OFF;    // 12,288 floats
static const size_t COVP_OFF = 0;          // 2,097,152
static const size_t MEAN_OFF = 2097152;    // 256
static const size_t COVS_OFF = 2097408;    // 16,384 -> ends 2,113,792
static const size_t KHAT_OFF = 0;          // 6,553,600 (4096 tiles *100*16)
static const size_t VPK_OFF  = 6553600;    // 4,194,304 -> ends 10,747,904
static const size_t OUT3_OFF = 0;          // 4,194,304
static const size_t IDX_OFF  = 12570112;   // 256 ints
static const size_t INV_OFF  = 12570368;   // 256 ints
static const size_t GT2_OFF  = 12570624;   // 4096
static const size_t DT2_OFF  = 12574720;   // 2048
static const size_t UT2_OFF  = 12576768;   // 2048
static const size_t PT2_OFF  = 12578816;   // 4096 -> ends 12,582,912 exactly

// ---------------- 0: transpose qkv_w -> wT[c*192+o] ----------------
__global__ __launch_bounds__(256) void k_prep_wt(
    const float* __restrict__ qkv_w, float* __restrict__ wT) {
  int i = blockIdx.x * 256 + threadIdx.x;   // 12288
  int o = i >> 6, c = i & 63;
  wT[c * 192 + o] = qkv_w[i];
}

// ---------------- 0b: transpose MLP weights to d-major ----------------
__global__ __launch_bounds__(256) void k_prep2(
    const float* __restrict__ gating_w, const float* __restrict__ down_w,
    const float* __restrict__ up_w, const float* __restrict__ proj_w,
    float* __restrict__ gT, float* __restrict__ dT,
    float* __restrict__ uT, float* __restrict__ pT) {
  int t = blockIdx.x * 256 + threadIdx.x;
  if (t < 4096) {
    int o = t >> 6, d = t & 63;
    gT[d * 64 + o] = gating_w[t];
    pT[d * 64 + o] = proj_w[t];
  }
  if (t < 2048) {
    int o = t >> 6, d = t & 63;      // down_w (32,64)
    dT[d * 32 + o] = down_w[t];
    int o2 = t >> 5, d2 = t & 31;    // up_w (64,32)
    uT[d2 * 64 + o2] = up_w[t];
  }
}

// ---------------- 1: maxpool2 + conv1x1 (x -> qkv_pre) ----------------
__global__ __launch_bounds__(256) void k_pool_conv(
    const float* __restrict__ x, const float* __restrict__ wT,
    float* __restrict__ pre) {
  int b = blockIdx.x >> 8;          // 256 tiles / batch
  int pix0 = (blockIdx.x & 255) * 64;
  __shared__ float xt[64 * 64];     // [c][p]
  int t = threadIdx.x;
  for (int i = 0; i < 16; ++i) {
    int f = i * 256 + t;
    int c = f >> 6, p = f & 63;
    int pix = pix0 + p;
    int y = pix >> 7, xx = pix & 127;
    const float* src = x + ((size_t)(b * 64 + c) * 65536) + (2 * y) * 256 + 2 * xx;
    float2 v01 = *(const float2*)src;
    float2 v23 = *(const float2*)(src + 256);
    xt[c * 64 + p] = fmaxf(fmaxf(v01.x, v01.y), fmaxf(v23.x, v23.y));
  }
  __syncthreads();
  int p = t & 63;
  int obase = __builtin_amdgcn_readfirstlane((t >> 6) * 48);  // wave-uniform
  const float* wbase = wT + obase;
  float acc[48];
#pragma unroll
  for (int j = 0; j < 48; ++j) acc[j] = 0.f;
  for (int c = 0; c < 64; ++c) {
    float xv = xt[c * 64 + p];
    const float* wc = wbase + c * 192;    // uniform -> s_load_dwordx16 x3
#pragma unroll
    for (int j = 0; j < 48; ++j) acc[j] = fmaf(wc[j], xv, acc[j]);
  }
  float* dst = pre + ((size_t)b * 192 + obase) * HWP + pix0 + p;
#pragma unroll
  for (int j = 0; j < 48; ++j) dst[(size_t)j * HWP] = acc[j];
}

// ---------------- 2: depthwise 3x3, zero pad (pre -> qkv) ----------------
// Round-6: float4 per thread (4 pixels). Old version: 9 scalar loads + 1
// scalar store per pixel ran at 1.42 TB/s (22% of copy ceiling) — VMEM-issue
// bound, not byte bound (FETCH+WRITE were already minimal). Now: 3 dwordx4 +
// 6 dword loads + 1 dwordx4 store per 4 pixels (4x fewer VMEM instrs).
// Boundary zeros are fed through the SAME fmaf chain order as the original
// skip logic -> fmaf(w,0,acc)==acc -> bitwise-identical output.
__global__ __launch_bounds__(256) void k_dw3x3_zero(
    const float* __restrict__ pre, const float* __restrict__ lce_w,
    float* __restrict__ qkv) {
  int gid = blockIdx.x * 256 + threadIdx.x;   // over 768*128*32 float4s
  int c4 = gid & 31;
  int y  = (gid >> 5) & 127;
  int bc = gid >> 12;                          // b*192 + ch
  int ch = bc % 192;
  int x0 = c4 * 4;
  const float* base = pre + (size_t)bc * HWP;
  const float* w = lce_w + ch * 9;
  const float4 z4 = make_float4(0.f, 0.f, 0.f, 0.f);
  bool ym = y > 0, yp = y < 127;
  bool xl = x0 > 0, xr = x0 < 124;
  const float* rowm = base + (y - 1) * 128;
  const float* rowc = base + y * 128;
  const float* rowp = base + (y + 1) * 128;
  float4 vm = ym ? *(const float4*)(rowm + x0) : z4;
  float  lm = (ym && xl) ? rowm[x0 - 1] : 0.f;
  float  rm = (ym && xr) ? rowm[x0 + 4] : 0.f;
  float4 vc = *(const float4*)(rowc + x0);
  float  lc = xl ? rowc[x0 - 1] : 0.f;
  float  rc = xr ? rowc[x0 + 4] : 0.f;
  float4 vp = yp ? *(const float4*)(rowp + x0) : z4;
  float  lp = (yp && xl) ? rowp[x0 - 1] : 0.f;
  float  rp = (yp && xr) ? rowp[x0 + 4] : 0.f;
  float w0 = w[0], w1 = w[1], w2 = w[2], w3 = w[3], w4 = w[4],
        w5 = w[5], w6 = w[6], w7 = w[7], w8 = w[8];
  // exact original accumulation order: dy=-1 (w0,w1,w2), dy=0 (w3,w4,w5),
  // dy=+1 (w6,w7,w8), each left->center->right.
  float4 o;
  o.x = fmaf(w8, vp.y, fmaf(w7, vp.x, fmaf(w6, lp,
        fmaf(w5, vc.y, fmaf(w4, vc.x, fmaf(w3, lc,
        fmaf(w2, vm.y, fmaf(w1, vm.x, fmaf(w0, lm, 0.f)))))))));
  o.y = fmaf(w8, vp.z, fmaf(w7, vp.y, fmaf(w6, vp.x,
        fmaf(w5, vc.z, fmaf(w4, vc.y, fmaf(w3, vc.x,
        fmaf(w2, vm.z, fmaf(w1, vm.y, fmaf(w0, vm.x, 0.f)))))))));
  o.z = fmaf(w8, vp.w, fmaf(w7, vp.z, fmaf(w6, vp.y,
        fmaf(w5, vc.w, fmaf(w4, vc.z, fmaf(w3, vc.y,
        fmaf(w2, vm.w, fmaf(w1, vm.z, fmaf(w0, vm.y, 0.f)))))))));
  o.w = fmaf(w8, rp,   fmaf(w7, vp.w, fmaf(w6, vp.z,
        fmaf(w5, rc,   fmaf(w4, vc.w, fmaf(w3, vc.z,
        fmaf(w2, rm,   fmaf(w1, vm.w, fmaf(w0, vm.z, 0.f)))))))));
  *(float4*)(qkv + (size_t)bc * HWP + y * 128 + x0) = o;
}

// ---------------- 3a: per-channel mean of q ----------------
__global__ __launch_bounds__(256) void k_mean(
    const float* __restrict__ qkv, float* __restrict__ mean) {
  int bc = blockIdx.x;              // b*64 + c
  int b = bc >> 6, c = bc & 63;
  const float* src = qkv + ((size_t)b * 192 + c) * HWP;
  float s = 0.f;
  for (int i = threadIdx.x; i < HWP; i += 256) s += src[i];
  __shared__ float red[4];
  for (int off = 32; off > 0; off >>= 1) s += __shfl_down(s, off);
  int t = threadIdx.x;
  if ((t & 63) == 0) red[t >> 6] = s;
  __syncthreads();
  if (t == 0) mean[bc] = (red[0] + red[1] + red[2] + red[3]) * (1.f / 16384.f);
}

// ---------------- 3b: centered cov partials (chunks of 128) ----------------
__global__ __launch_bounds__(256) void k_covpart(
    const float* __restrict__ qkv, const float* __restrict__ mean,
    float* __restrict__ covp) {
  int blk = blockIdx.x;             // b*128 + chunk
  int b = blk >> 7, chunk = blk & 127;
  int e0 = chunk * 128;
  __shared__ float qc[64 * 129];    // +1 pad breaks stride conflicts
  int t = threadIdx.x;
  for (int i = 0; i < 32; ++i) {
    int f = i * 256 + t;
    int c = f >> 7, e = f & 127;
    qc[c * 129 + e] = qkv[((size_t)b * 192 + c) * HWP + e0 + e] - mean[b * 64 + c];
  }
  __syncthreads();
  int d = t & 63;
  int crow = t >> 6;                // wave-uniform
  float acc[16];
#pragma unroll
  for (int i = 0; i < 16; ++i) acc[i] = 0.f;
  for (int e = 0; e < 128; ++e) {
    float qd = qc[d * 129 + e];
#pragma unroll
    for (int i = 0; i < 16; ++i) {
      int c = crow + 4 * i;
      acc[i] = fmaf(qc[c * 129 + e], qd, acc[i]);
    }
  }
  float* dst = covp + (size_t)blk * 4096;
#pragma unroll
  for (int i = 0; i < 16; ++i) {
    int c = crow + 4 * i;
    dst[c * 64 + d] = acc[i];       // == dst[i*256 + t], coalesced
  }
}

// ---------------- 3b2: reduce cov partials over 128 chunks ----------------
__global__ __launch_bounds__(256) void k_covred(
    const float* __restrict__ covp, float* __restrict__ covs) {
  int blk = blockIdx.x;             // b*16 + j
  int b = blk >> 4;
  int pp = (blk & 15) * 256 + threadIdx.x;
  const float* src = covp + (size_t)b * 524288 + pp;
  float s = 0.f;
  for (int ch = 0; ch < 128; ++ch) s += src[ch * 4096];   // chunk order preserved
  covs[b * 4096 + pp] = s;
}

// ---------------- 3c: correlation-mean sim, stable rank ----------------
__global__ __launch_bounds__(256) void k_simsort(
    const float* __restrict__ covs_g, int* __restrict__ idx, int* __restrict__ inv) {
  int b = blockIdx.x;               // 4 blocks
  __shared__ float covs[4096];
  __shared__ float stds[64];
  __shared__ float sims[64];
  int t = threadIdx.x;
  for (int i = 0; i < 16; ++i) covs[i * 256 + t] = covs_g[b * 4096 + i * 256 + t];
  __syncthreads();
  if (t < 64) stds[t] = sqrtf(covs[t * 64 + t] + 1e-8f);
  __syncthreads();
  if (t < 64) {
    float s = 0.f;
    float sc = stds[t];
    for (int d2 = 0; d2 < 64; ++d2) {
      float denom = fmaxf(sc * stds[d2], 1e-8f);
      s += covs[d2 * 64 + t] / denom;   // symmetric matrix: bitwise equal to [t][d2]
    }
    sims[t] = s * (1.f / 64.f);
  }
  __syncthreads();
  if (t < 64) {
    float sv = sims[t];
    int r = 0;
    for (int d2 = 0; d2 < 64; ++d2) {
      float o = sims[d2];
      if (o > sv || (o == sv && d2 < t)) r++;
    }
    idx[b * 64 + r] = t;
    inv[b * 64 + t] = r;
  }
}

// ---------------- 6: stage K-hat (rel-added, l2-normalized) + packed V ----
// khat: [tile=bi][key 0..99][16ch]  (64B rows)
// vpk : [b*4+head][pos 0..16383][16ch] (no halo duplication; each pooled
//       position is interior to exactly one tile -> that tile writes it)
__global__ __launch_bounds__(64) void k_stage(
    const float* __restrict__ qkv, const int* __restrict__ idx,
    const float* __restrict__ rel_h, const float* __restrict__ rel_w,
    float* __restrict__ khat, float* __restrict__ vpk) {
  int bi = blockIdx.x;
  int head = bi & 3;
  int wj = (bi >> 2) & 15;
  int hi = (bi >> 6) & 15;
  int b = bi >> 10;
  int t = threadIdx.x;
  const size_t bb = (size_t)b * 192 * HWP;
  int chg[16];
#pragma unroll
  for (int ch = 0; ch < 16; ++ch) chg[ch] = idx[b * 64 + head * 16 + ch];
  // K rows: 100 halo positions
  for (int i = 0; i < 2; ++i) {
    int pos = i * 64 + t;
    if (pos < 100) {
      int py = pos / 10, px = pos - py * 10;
      int ky = hi * 8 + py - 1, kx = wj * 8 + px - 1;
      bool ok = (ky >= 0) && (ky < 128) && (kx >= 0) && (kx < 128);
      int sp = ky * 128 + kx;
      float kv[16];
      float s = 0.f;
#pragma unroll
      for (int ch = 0; ch < 16; ++ch) {
        float k = ok ? qkv[bb + (size_t)(64 + chg[ch]) * HWP + sp] : 0.f;
        k += (ch < 8) ? rel_h[(head * 10 + py) * 8 + ch]
                      : rel_w[(head * 10 + px) * 8 + (ch - 8)];
        kv[ch] = k;
        s += k * k;
      }
      float rn = 1.f / fmaxf(sqrtf(s), 1e-12f);   // ref: l2norm(k+rel) before dot
      float* kd = khat + ((size_t)bi * 100 + pos) * 16;
#pragma unroll
      for (int ch = 0; ch < 16; ++ch) kd[ch] = kv[ch] * rn;
    }
  }
  // V rows: this tile's 64 interior positions, gathered channel-packed
  int qy = hi * 8 + (t >> 3), qx = wj * 8 + (t & 7);
  int spq = qy * 128 + qx;
  float* vd = vpk + ((size_t)(b * 4 + head) * 16384 + spq) * 16;
#pragma unroll
  for (int ch = 0; ch < 16; ++ch)
    vd[ch] = qkv[bb + (size_t)(128 + chg[ch]) * HWP + spq];
}

// ---------------- 7: halo block attention + gate ----------------
// LDS-staged K/V (r5): tile K (6.4KB, coalesced float4) + V (6.4KB, per-lane
// float4 of scattered 64B rows) staged once via VECTOR loads; the 50-key
// inner loop reads LDS broadcasts as direct FMA operands. OOB keys get V=0
// at stage time. po/pw combine buffer overlays dead kr after a barrier.
__global__ __launch_bounds__(128) void k_attn(
    const float* __restrict__ qkv, const int* __restrict__ idx,
    const float* __restrict__ khat, const float* __restrict__ vpk,
    const float* __restrict__ gate_w, const float* __restrict__ gate_b,
    const float* __restrict__ temp, float* __restrict__ attn_out) {
  int bi = blockIdx.x;
  int head = bi & 3;
  int wj = (bi >> 2) & 15;
  int hi = (bi >> 6) & 15;
  int b = bi >> 10;
  int tt = threadIdx.x;                            // 0..127
  int t = tt & 63;                                 // lane = query
  int w = __builtin_amdgcn_readfirstlane(tt >> 6); // wave 0/1
  __shared__ __align__(16) float smem[3200];       // kr[100][16] | vr[100][16]
  float* kr = smem;                                // 1600 floats
  float* vr = smem + 1600;                         // 1600 floats
  const size_t bb = (size_t)b * 192 * HWP;
  // ---- stage K: contiguous 6.4KB, fully coalesced float4 ----
  const float* kg = khat + (size_t)bi * 1600;
  for (int f = tt; f < 400; f += 128)
    ((float4*)kr)[f] = ((const float4*)kg)[f];
  // ---- stage V: per-lane float4 of scattered 64B rows (high MLP) ----
  const float* vb = vpk + (size_t)(b * 4 + head) * (16384 * 16);
  for (int f = tt; f < 400; f += 128) {
    int pos = f >> 2, comp = f & 3;
    int py = pos / 10, px = pos - py * 10;
    int ky = hi * 8 + py - 1, kx = wj * 8 + px - 1;
    bool ok = (ky >= 0) && (ky < 128) && (kx >= 0) && (kx < 128);
    float4 v = make_float4(0.f, 0.f, 0.f, 0.f);
    if (ok) v = ((const float4*)(vb + (size_t)(ky * 128 + kx) * 16))[comp];
    ((float4*)vr)[f] = v;                          // OOB rows -> zeros
  }
  // ---- per-query q (overlaps staging latency) ----
  int chg[16];
#pragma unroll
  for (int ch = 0; ch < 16; ++ch) chg[ch] = idx[b * 64 + head * 16 + ch];
  int qy = hi * 8 + (t >> 3), qx = wj * 8 + (t & 7);
  float q[16];
  float qs = 0.f;
#pragma unroll
  for (int ch = 0; ch < 16; ++ch) {
    q[ch] = qkv[bb + (size_t)chg[ch] * HWP + qy * 128 + qx];
    qs += q[ch] * q[ch];
  }
  float T = expf(temp[head]);
  float qnT = T / fmaxf(sqrtf(qs), 1e-12f);
  __syncthreads();
  // ---- 50 keys per wave, all operands from LDS broadcasts ----
  float out[16];
#pragma unroll
  for (int ch = 0; ch < 16; ++ch) out[ch] = 0.f;
  float wsum = 0.f;
  for (int pyl = 0; pyl < 5; ++pyl) {
    int py = w * 5 + pyl;
    const float* kp0 = kr + py * 160;
    const float* vp0 = vr + py * 160;
    for (int px = 0; px < 10; ++px) {
      const float* kp = kp0 + px * 16;
      const float* vp = vp0 + px * 16;
      float d0 = 0.f, d1 = 0.f, d2 = 0.f, d3 = 0.f;
#pragma unroll
      for (int ch = 0; ch < 4; ++ch) {
        d0 = fmaf(q[ch], kp[ch], d0);
        d1 = fmaf(q[ch + 4], kp[ch + 4], d1);
        d2 = fmaf(q[ch + 8], kp[ch + 8], d2);
        d3 = fmaf(q[ch + 12], kp[ch + 12], d3);
      }
      float dacc = (d0 + d1) + (d2 + d3);
      float e = __expf(fmaf(dacc, qnT, -T));      // exp(d - T): exact softmax shift
      wsum += e;                                  // OOB keys count in denominator
#pragma unroll
      for (int ch = 0; ch < 16; ++ch)
        out[ch] = fmaf(e, vp[ch], out[ch]);       // OOB rows are zero -> no mask
    }
  }
  // ---- cross-wave combine: po/pw overlay the dead kr region ----
  __syncthreads();                 // both waves done reading kr/vr
  float* po = smem;                // [2][16][64] = 2048 floats
  float* pwp = smem + 2048;        // [2][64]
  pwp[w * 64 + t] = wsum;
#pragma unroll
  for (int ch = 0; ch < 16; ++ch) po[(w * 16 + ch) * 64 + t] = out[ch];
  __syncthreads();
  float winv = 1.f / (pwp[t] + pwp[64 + t]);
  int ob = w * 8;                                 // this wave's 8 outputs
#pragma unroll
  for (int i = 0; i < 8; ++i) {
    int o = ob + i;
    float oc = po[o * 64 + t] + po[(16 + o) * 64 + t];
    float gsv = gate_b[head * 16 + o];
#pragma unroll
    for (int c = 0; c < 16; ++c)
      gsv = fmaf(gate_w[head * 256 + o * 16 + c], q[c], gsv);
    float sig = 1.f / (1.f + __expf(-gsv));
    attn_out[bb + (size_t)(128 + chg[o]) * HWP + qy * 128 + qx] = oc * winv * sig;
  }
}

// ---------------- 8: mixed -> gating -> down -> up -> (+attn) -> proj ----
// attn lives in the qkv V planes: channel c of batch b at (b*192+128+c)*HWP.
// 256 threads = 4 waves per block, 64 pixels per block (lane = pixel).
// Output channels are SPLIT ACROSS WAVES (16/wave; 8/wave for down): raises
// waves/CU from 4 to 16. Per-channel accumulator chain order (d ascending)
// is unchanged -> bitwise-identical results.
__global__ __launch_bounds__(256) void k_post(
    const float* __restrict__ attn, const float* __restrict__ qkv,
    const float* __restrict__ gT, const float* __restrict__ gating_b,
    const float* __restrict__ dT, const float* __restrict__ down_b,
    const float* __restrict__ uT, const float* __restrict__ up_b,
    const float* __restrict__ pT, float* __restrict__ out3) {
  __shared__ float xs[64 * 64];     // [c][pix]
  int t = threadIdx.x;
  int lane = t & 63;                // pixel within block
  int w = t >> 6;                   // wave 0..3 (uniform)
  int p = blockIdx.x * 64 + lane;   // global pooled pixel id
  int b = p >> 14;
  int pix = p & 16383;
  const float* ap = attn + ((size_t)b * 192 + 128) * HWP + pix;
  const float* qp = qkv + (size_t)b * 192 * HWP + pix;
  float* op = out3 + (size_t)b * 64 * HWP + pix;
  int ob16 = __builtin_amdgcn_readfirstlane(w * 16);
  int ob8  = __builtin_amdgcn_readfirstlane(w * 8);
  // mixed = attn_out + (q + k): each wave loads its 16 channels (concurrent)
#pragma unroll
  for (int i = 0; i < 16; ++i) {
    int c = ob16 + i;
    xs[c * 64 + lane] = ap[(size_t)c * HWP] + qp[(size_t)c * HWP] + qp[(size_t)(64 + c) * HWP];
  }
  __syncthreads();
  // ---- gating conv + exact gelu, * mixed ----
  {
    float acc[16];
#pragma unroll
    for (int o = 0; o < 16; ++o) acc[o] = gating_b[ob16 + o];
    for (int d = 0; d < 64; ++d) {
      float xv = xs[d * 64 + lane];
      const float* wd = gT + d * 64 + ob16;   // wave-uniform -> s_load
#pragma unroll
      for (int o = 0; o < 16; ++o) acc[o] = fmaf(wd[o], xv, acc[o]);
    }
    __syncthreads();                 // all reads done before any overwrite
#pragma unroll
    for (int o = 0; o < 16; ++o) {
      float a = acc[o];
      float ge = 0.5f * a * (1.f + erff(a * 0.70710678118654752f));
      xs[(ob16 + o) * 64 + lane] = ge * xs[(ob16 + o) * 64 + lane];
    }
    __syncthreads();
  }
  // ---- down 64->32 (8 outputs/wave) ----
  {
    float acc[8];
#pragma unroll
    for (int o = 0; o < 8; ++o) acc[o] = down_b[ob8 + o];
    for (int d = 0; d < 64; ++d) {
      float xv = xs[d * 64 + lane];
      const float* wd = dT + d * 32 + ob8;
#pragma unroll
      for (int o = 0; o < 8; ++o) acc[o] = fmaf(wd[o], xv, acc[o]);
    }
    __syncthreads();
#pragma unroll
    for (int o = 0; o < 8; ++o) xs[(ob8 + o) * 64 + lane] = acc[o];
    __syncthreads();
  }
  // ---- up 32->64, + attn residual ----
  {
    float acc[16];
#pragma unroll
    for (int o = 0; o < 16; ++o) acc[o] = up_b[ob16 + o];
    for (int d = 0; d < 32; ++d) {
      float xv = xs[d * 64 + lane];
      const float* wd = uT + d * 64 + ob16;
#pragma unroll
      for (int o = 0; o < 16; ++o) acc[o] = fmaf(wd[o], xv, acc[o]);
    }
    __syncthreads();
#pragma unroll
    for (int o = 0; o < 16; ++o)
      xs[(ob16 + o) * 64 + lane] = acc[o] + ap[(size_t)(ob16 + o) * HWP];
    __syncthreads();
  }
  // ---- proj (no bias) ----
  {
    float acc[16];
#pragma unroll
    for (int o = 0; o < 16; ++o) acc[o] = 0.f;
    for (int d = 0; d < 64; ++d) {
      float xv = xs[d * 64 + lane];
      const float* wd = pT + d * 64 + ob16;
#pragma unroll
      for (int o = 0; o < 16; ++o) acc[o] = fmaf(wd[o], xv, acc[o]);
    }
#pragma unroll
    for (int o = 0; o < 16; ++o) op[(size_t)(ob16 + o) * HWP] = acc[o];
  }
}

// ---------------- 9: dw3x3 reflect + bias + bilinear x2 (align-corners) ----
__global__ __launch_bounds__(256) void k_final(
    const float* __restrict__ out3, const float* __restrict__ lp_w,
    const float* __restrict__ lp_b, float* __restrict__ out) {
  int bi = blockIdx.x;                 // (b*64+ch)*8 + rt
  int rt = bi & 7;
  int bc = bi >> 3;
  int ch = bc & 63;
  int r0 = rt * 16;
  __shared__ float tin[20 * 128];      // input rows r0-2 .. r0+17 (reflected)
  __shared__ float tdw[18 * 128];      // dw rows r0-1 .. r0+16
  int t = threadIdx.x;
  const float* src = out3 + (size_t)bc * HWP;
  for (int i = 0; i < 10; ++i) {
    int f = i * 256 + t;               // 2560 exactly
    int r = f >> 7, xx = f & 127;
    int ry = r0 - 2 + r;
    ry = ry < 0 ? -ry : (ry > 127 ? 254 - ry : ry);
    tin[f] = src[ry * 128 + xx];
  }
  __syncthreads();
  float w0 = lp_w[ch * 9 + 0], w1 = lp_w[ch * 9 + 1], w2 = lp_w[ch * 9 + 2];
  float w3 = lp_w[ch * 9 + 3], w4 = lp_w[ch * 9 + 4], w5 = lp_w[ch * 9 + 5];
  float w6 = lp_w[ch * 9 + 6], w7 = lp_w[ch * 9 + 7], w8 = lp_w[ch * 9 + 8];
  float bias = lp_b[ch];
  for (int i = 0; i < 9; ++i) {
    int f = i * 256 + t;               // 2304 exactly
    int r = f >> 7, xx = f & 127;
    int xm = (xx == 0) ? 1 : xx - 1;
    int xp = (xx == 127) ? 126 : xx + 1;
    const float* r0p = tin + r * 128;
    const float* r1p = r0p + 128;
    const float* r2p = r1p + 128;
    float acc = bias;
    acc = fmaf(w0, r0p[xm], acc); acc = fmaf(w1, r0p[xx], acc); acc = fmaf(w2, r0p[xp], acc);
    acc = fmaf(w3, r1p[xm], acc); acc = fmaf(w4, r1p[xx], acc); acc = fmaf(w5, r1p[xp], acc);
    acc = fmaf(w6, r2p[xm], acc); acc = fmaf(w7, r2p[xx], acc); acc = fmaf(w8, r2p[xp], acc);
    tdw[f] = acc;
  }
  __syncthreads();
  const float s = (float)(127.0 / 255.0);
  float* dst = out + (size_t)bc * 65536;
  for (int i = 0; i < 32; ++i) {
    int f = i * 256 + t;               // 8192 exactly: rows 2r0..2r0+31, cols 0..255
    int vr = f >> 8, vx = f & 255;
    int v = 2 * r0 + vr;
    float cy = (float)v * s;
    int ly = (int)floorf(cy); if (ly > 126) ly = 126;
    float wy = cy - (float)ly;
    float cx = (float)vx * s;
    int lx = (int)floorf(cx); if (lx > 126) lx = 126;
    float wx = cx - (float)lx;
    int lr = ly - r0 + 1;              // tdw row index
    float a  = tdw[lr * 128 + lx];
    float bq = tdw[lr * 128 + lx + 1];
    float c2 = tdw[(lr + 1) * 128 + lx];
    float d2 = tdw[(lr + 1) * 128 + lx + 1];
    float t0 = a  * (1.f - wy) + c2 * wy;   // y-lerp first (matches ref order)
    float t1 = bq * (1.f - wy) + d2 * wy;
    dst[v * 256 + vx] = t0 * (1.f - wx) + t1 * wx;
  }
}

extern "C" void kernel_launch(void* const* d_in, const int* in_sizes, int n_in,
                              void* d_out, int out_size, void* d_ws, size_t ws_size,
                              hipStream_t stream) {
  (void)in_sizes; (void)n_in; (void)out_size; (void)ws_size;
  const float* x        = (const float*)d_in[0];
  const float* qkv_w    = (const float*)d_in[1];
  const float* lce_w    = (const float*)d_in[2];
  const float* gate_w   = (const float*)d_in[3];
  const float* gate_b   = (const float*)d_in[4];
  const float* temp     = (const float*)d_in[5];
  const float* rel_h    = (const float*)d_in[6];
  const float* rel_w    = (const float*)d_in[7];
  const float* down_w   = (const float*)d_in[8];
  const float* down_b   = (const float*)d_in[9];
  const float* up_w     = (const float*)d_in[10];
  const float* up_b     = (const float*)d_in[11];
  const float* gating_w = (const float*)d_in[12];
  const float* gating_b = (const float*)d_in[13];
  const float* proj_w   = (const float*)d_in[14];
  const float* lp_w     = (const float*)d_in[15];
  const float* lp_b     = (const float*)d_in[16];
  float* fws = (float*)d_ws;
  float* outp = (float*)d_out;

  float* pre  = fws + PRE_OFF;
  float* qkv  = fws + QKV_OFF;
  float* khat = fws + KHAT_OFF;
  float* vpk  = fws + VPK_OFF;
  float* out3 = fws + OUT3_OFF;
  float* covp = fws + COVP_OFF;
  float* mean = fws + MEAN_OFF;
  int* idx = (int*)(fws + IDX_OFF);
  int* inv = (int*)(fws + INV_OFF);
  float* covs = fws + COVS_OFF;
  float* wT   = fws + WT_OFF;
  float* gT   = fws + GT2_OFF;
  float* dT   = fws + DT2_OFF;
  float* uT   = fws + UT2_OFF;
  float* pT   = fws + PT2_OFF;

  k_prep_wt<<<48, 256, 0, stream>>>(qkv_w, wT);
  k_pool_conv<<<1024, 256, 0, stream>>>(x, wT, pre);
  k_dw3x3_zero<<<12288, 256, 0, stream>>>(pre, lce_w, qkv);
  k_prep2<<<16, 256, 0, stream>>>(gating_w, down_w, up_w, proj_w, gT, dT, uT, pT);
  k_mean<<<256, 256, 0, stream>>>(qkv, mean);
  k_covpart<<<512, 256, 0, stream>>>(qkv, mean, covp);
  k_covred<<<64, 256, 0, stream>>>(covp, covs);
  k_simsort<<<4, 256, 0, stream>>>(covs, idx, inv);
  k_stage<<<4096, 64, 0, stream>>>(qkv, idx, rel_h, rel_w, khat, vpk);
  k_attn<<<4096, 128, 0, stream>>>(qkv, idx, khat, vpk, gate_w, gate_b, temp, qkv);
  k_post<<<1024, 256, 0, stream>>>(qkv, qkv, gT, gating_b, dT, down_b,
                                   uT, up_b, pT, out3);
  k_final<<<2048, 256, 0, stream>>>(out3, lp_w, lp_b, outp);
  (void)inv;
}

// Round 8
// 369.685 us; speedup vs baseline: 1.3013x; 1.0801x over previous
//
#include <hip/hip_runtime.h>
#include <math.h>

#define HWP 16384   // 128*128 pooled plane

// ---------------- workspace layout (float offsets) ----------------
// Lifetimes (same-stream serialization):
//   pre   [0, 12,582,912)          pool_conv -> dw3x3
//   cov   [0, ~2.12M)              mean -> simsort      (inside dead pre)
//   attn  [0, 4,194,304)           attn -> post         (inside dead pre)
//   out3  [4,194,304, 8,388,608)   post -> final        (inside dead pre)
//   tail  [12,570,112, 12,582,912) idx/inv + MLP weights, written only
//                                  after dw3x3, live through post
//   qkv   [12,582,912, 25,165,824) dw3x3 -> post; READ-ONLY after dw3x3
//                                  (r8: attn no longer writes V planes in
//                                  place -> no inter-tile halo race).
static const size_t PRE_OFF  = 0;          // 12,582,912
static const size_t QKV_OFF  = 12582912;
// wT lives at the START of the QKV region: written by k_prep_wt, read only by
// k_pool_conv (which writes PRE only), then overwritten by k_dw3x3_zero.
static const size_t WT_OFF   = QKV_OFF;    // 12,288 floats
static const size_t COVP_OFF = 0;          // 2,097,152
static const size_t MEAN_OFF = 2097152;    // 256
static const size_t COVS_OFF = 2097408;    // 16,384 -> ends 2,113,792
static const size_t ATTN_OFF = 0;          // 4,194,304 (cov dead by attn)
static const size_t OUT3_OFF = 4194304;    // 4,194,304 -> ends 8,388,608
static const size_t IDX_OFF  = 12570112;   // 256 ints
static const size_t INV_OFF  = 12570368;   // 256 ints
static const size_t GT2_OFF  = 12570624;   // 4096
static const size_t DT2_OFF  = 12574720;   // 2048
static const size_t UT2_OFF  = 12576768;   // 2048
static const size_t PT2_OFF  = 12578816;   // 4096 -> ends 12,582,912 exactly

// ---------------- 0: transpose qkv_w -> wT[c*192+o] ----------------
__global__ __launch_bounds__(256) void k_prep_wt(
    const float* __restrict__ qkv_w, float* __restrict__ wT) {
  int i = blockIdx.x * 256 + threadIdx.x;   // 12288
  int o = i >> 6, c = i & 63;
  wT[c * 192 + o] = qkv_w[i];
}

// ---------------- 0b: transpose MLP weights to d-major ----------------
__global__ __launch_bounds__(256) void k_prep2(
    const float* __restrict__ gating_w, const float* __restrict__ down_w,
    const float* __restrict__ up_w, const float* __restrict__ proj_w,
    float* __restrict__ gT, float* __restrict__ dT,
    float* __restrict__ uT, float* __restrict__ pT) {
  int t = blockIdx.x * 256 + threadIdx.x;
  if (t < 4096) {
    int o = t >> 6, d = t & 63;
    gT[d * 64 + o] = gating_w[t];
    pT[d * 64 + o] = proj_w[t];
  }
  if (t < 2048) {
    int o = t >> 6, d = t & 63;      // down_w (32,64)
    dT[d * 32 + o] = down_w[t];
    int o2 = t >> 5, d2 = t & 31;    // up_w (64,32)
    uT[d2 * 64 + o2] = up_w[t];
  }
}

// ---------------- 1: maxpool2 + conv1x1 (x -> qkv_pre) ----------------
__global__ __launch_bounds__(256) void k_pool_conv(
    const float* __restrict__ x, const float* __restrict__ wT,
    float* __restrict__ pre) {
  int b = blockIdx.x >> 8;          // 256 tiles / batch
  int pix0 = (blockIdx.x & 255) * 64;
  __shared__ float xt[64 * 64];     // [c][p]
  int t = threadIdx.x;
  for (int i = 0; i < 16; ++i) {
    int f = i * 256 + t;
    int c = f >> 6, p = f & 63;
    int pix = pix0 + p;
    int y = pix >> 7, xx = pix & 127;
    const float* src = x + ((size_t)(b * 64 + c) * 65536) + (2 * y) * 256 + 2 * xx;
    float2 v01 = *(const float2*)src;
    float2 v23 = *(const float2*)(src + 256);
    xt[c * 64 + p] = fmaxf(fmaxf(v01.x, v01.y), fmaxf(v23.x, v23.y));
  }
  __syncthreads();
  int p = t & 63;
  int obase = __builtin_amdgcn_readfirstlane((t >> 6) * 48);  // wave-uniform
  const float* wbase = wT + obase;
  float acc[48];
#pragma unroll
  for (int j = 0; j < 48; ++j) acc[j] = 0.f;
  for (int c = 0; c < 64; ++c) {
    float xv = xt[c * 64 + p];
    const float* wc = wbase + c * 192;    // uniform -> s_load_dwordx16 x3
#pragma unroll
    for (int j = 0; j < 48; ++j) acc[j] = fmaf(wc[j], xv, acc[j]);
  }
  float* dst = pre + ((size_t)b * 192 + obase) * HWP + pix0 + p;
#pragma unroll
  for (int j = 0; j < 48; ++j) dst[(size_t)j * HWP] = acc[j];
}

// ---------------- 2: depthwise 3x3, zero pad (pre -> qkv) ----------------
// float4 per thread (4 pixels); boundary zeros fed through the SAME fmaf
// chain order as scalar skip logic -> bitwise-identical output.
__global__ __launch_bounds__(256) void k_dw3x3_zero(
    const float* __restrict__ pre, const float* __restrict__ lce_w,
    float* __restrict__ qkv) {
  int gid = blockIdx.x * 256 + threadIdx.x;   // over 768*128*32 float4s
  int c4 = gid & 31;
  int y  = (gid >> 5) & 127;
  int bc = gid >> 12;                          // b*192 + ch
  int ch = bc % 192;
  int x0 = c4 * 4;
  const float* base = pre + (size_t)bc * HWP;
  const float* w = lce_w + ch * 9;
  const float4 z4 = make_float4(0.f, 0.f, 0.f, 0.f);
  bool ym = y > 0, yp = y < 127;
  bool xl = x0 > 0, xr = x0 < 124;
  const float* rowm = base + (y - 1) * 128;
  const float* rowc = base + y * 128;
  const float* rowp = base + (y + 1) * 128;
  float4 vm = ym ? *(const float4*)(rowm + x0) : z4;
  float  lm = (ym && xl) ? rowm[x0 - 1] : 0.f;
  float  rm = (ym && xr) ? rowm[x0 + 4] : 0.f;
  float4 vc = *(const float4*)(rowc + x0);
  float  lc = xl ? rowc[x0 - 1] : 0.f;
  float  rc = xr ? rowc[x0 + 4] : 0.f;
  float4 vp = yp ? *(const float4*)(rowp + x0) : z4;
  float  lp = (yp && xl) ? rowp[x0 - 1] : 0.f;
  float  rp = (yp && xr) ? rowp[x0 + 4] : 0.f;
  float w0 = w[0], w1 = w[1], w2 = w[2], w3 = w[3], w4 = w[4],
        w5 = w[5], w6 = w[6], w7 = w[7], w8 = w[8];
  float4 o;
  o.x = fmaf(w8, vp.y, fmaf(w7, vp.x, fmaf(w6, lp,
        fmaf(w5, vc.y, fmaf(w4, vc.x, fmaf(w3, lc,
        fmaf(w2, vm.y, fmaf(w1, vm.x, fmaf(w0, lm, 0.f)))))))));
  o.y = fmaf(w8, vp.z, fmaf(w7, vp.y, fmaf(w6, vp.x,
        fmaf(w5, vc.z, fmaf(w4, vc.y, fmaf(w3, vc.x,
        fmaf(w2, vm.z, fmaf(w1, vm.y, fmaf(w0, vm.x, 0.f)))))))));
  o.z = fmaf(w8, vp.w, fmaf(w7, vp.z, fmaf(w6, vp.y,
        fmaf(w5, vc.w, fmaf(w4, vc.z, fmaf(w3, vc.y,
        fmaf(w2, vm.w, fmaf(w1, vm.z, fmaf(w0, vm.y, 0.f)))))))));
  o.w = fmaf(w8, rp,   fmaf(w7, vp.w, fmaf(w6, vp.z,
        fmaf(w5, rc,   fmaf(w4, vc.w, fmaf(w3, vc.z,
        fmaf(w2, rm,   fmaf(w1, vm.w, fmaf(w0, vm.z, 0.f)))))))));
  *(float4*)(qkv + (size_t)bc * HWP + y * 128 + x0) = o;
}

// ---------------- 3a: per-channel mean of q ----------------
__global__ __launch_bounds__(256) void k_mean(
    const float* __restrict__ qkv, float* __restrict__ mean) {
  int bc = blockIdx.x;              // b*64 + c
  int b = bc >> 6, c = bc & 63;
  const float* src = qkv + ((size_t)b * 192 + c) * HWP;
  float s = 0.f;
  for (int i = threadIdx.x; i < HWP; i += 256) s += src[i];
  __shared__ float red[4];
  for (int off = 32; off > 0; off >>= 1) s += __shfl_down(s, off);
  int t = threadIdx.x;
  if ((t & 63) == 0) red[t >> 6] = s;
  __syncthreads();
  if (t == 0) mean[bc] = (red[0] + red[1] + red[2] + red[3]) * (1.f / 16384.f);
}

// ---------------- 3b: centered cov partials (chunks of 128) ----------------
__global__ __launch_bounds__(256) void k_covpart(
    const float* __restrict__ qkv, const float* __restrict__ mean,
    float* __restrict__ covp) {
  int blk = blockIdx.x;             // b*128 + chunk
  int b = blk >> 7, chunk = blk & 127;
  int e0 = chunk * 128;
  __shared__ float qc[64 * 129];    // +1 pad breaks stride conflicts
  int t = threadIdx.x;
  for (int i = 0; i < 32; ++i) {
    int f = i * 256 + t;
    int c = f >> 7, e = f & 127;
    qc[c * 129 + e] = qkv[((size_t)b * 192 + c) * HWP + e0 + e] - mean[b * 64 + c];
  }
  __syncthreads();
  int d = t & 63;
  int crow = t >> 6;                // wave-uniform
  float acc[16];
#pragma unroll
  for (int i = 0; i < 16; ++i) acc[i] = 0.f;
  for (int e = 0; e < 128; ++e) {
    float qd = qc[d * 129 + e];
#pragma unroll
    for (int i = 0; i < 16; ++i) {
      int c = crow + 4 * i;
      acc[i] = fmaf(qc[c * 129 + e], qd, acc[i]);
    }
  }
  float* dst = covp + (size_t)blk * 4096;
#pragma unroll
  for (int i = 0; i < 16; ++i) {
    int c = crow + 4 * i;
    dst[c * 64 + d] = acc[i];       // == dst[i*256 + t], coalesced
  }
}

// ---------------- 3b2: reduce cov partials over 128 chunks ----------------
__global__ __launch_bounds__(256) void k_covred(
    const float* __restrict__ covp, float* __restrict__ covs) {
  int blk = blockIdx.x;             // b*16 + j
  int b = blk >> 4;
  int pp = (blk & 15) * 256 + threadIdx.x;
  const float* src = covp + (size_t)b * 524288 + pp;
  float s = 0.f;
  for (int ch = 0; ch < 128; ++ch) s += src[ch * 4096];   // chunk order preserved
  covs[b * 4096 + pp] = s;
}

// ---------------- 3c: correlation-mean sim, stable rank ----------------
__global__ __launch_bounds__(256) void k_simsort(
    const float* __restrict__ covs_g, int* __restrict__ idx, int* __restrict__ inv) {
  int b = blockIdx.x;               // 4 blocks
  __shared__ float covs[4096];
  __shared__ float stds[64];
  __shared__ float sims[64];
  int t = threadIdx.x;
  for (int i = 0; i < 16; ++i) covs[i * 256 + t] = covs_g[b * 4096 + i * 256 + t];
  __syncthreads();
  if (t < 64) stds[t] = sqrtf(covs[t * 64 + t] + 1e-8f);
  __syncthreads();
  if (t < 64) {
    float s = 0.f;
    float sc = stds[t];
    for (int d2 = 0; d2 < 64; ++d2) {
      float denom = fmaxf(sc * stds[d2], 1e-8f);
      s += covs[d2 * 64 + t] / denom;   // symmetric matrix: bitwise equal to [t][d2]
    }
    sims[t] = s * (1.f / 64.f);
  }
  __syncthreads();
  if (t < 64) {
    float sv = sims[t];
    int r = 0;
    for (int d2 = 0; d2 < 64; ++d2) {
      float o = sims[d2];
      if (o > sv || (o == sv && d2 < t)) r++;
    }
    idx[b * 64 + r] = t;
    inv[b * 64 + t] = r;
  }
}

// ---------------- 7: FUSED stage + halo block attention + gate ----------
// Round-8: k_stage is fused in. The khat/vpk global round-trip (43 MB
// written + 43 MB read) existed only to (a) pre-gather channels and (b)
// dodge the in-place V-plane overwrite race. (a) is done here directly into
// LDS (identical gather pattern + identical arithmetic: rel add + l2norm at
// fp32); (b) is fixed by writing attn output to the dead pre region instead
// of the V planes -> qkv is READ-ONLY here, no inter-tile race.
// Staging: one halo position per thread (tt<100): 16-ch K gather + rel +
// norm -> kr; 16-ch V gather (OOB->0) -> vr. Then the r7 50-keys-per-wave
// LDS-broadcast loop, unchanged. po/pw combine overlays dead kr.
__global__ __launch_bounds__(128) void k_attn(
    const float* __restrict__ qkv, const int* __restrict__ idx,
    const float* __restrict__ rel_h, const float* __restrict__ rel_w,
    const float* __restrict__ gate_w, const float* __restrict__ gate_b,
    const float* __restrict__ temp, float* __restrict__ attn_out) {
  int bi = blockIdx.x;
  int head = bi & 3;
  int wj = (bi >> 2) & 15;
  int hi = (bi >> 6) & 15;
  int b = bi >> 10;
  int tt = threadIdx.x;                            // 0..127
  int t = tt & 63;                                 // lane = query
  int w = __builtin_amdgcn_readfirstlane(tt >> 6); // wave 0/1
  __shared__ __align__(16) float smem[3200];       // kr[100][16] | vr[100][16]
  float* kr = smem;                                // 1600 floats
  float* vr = smem + 1600;                         // 1600 floats
  const size_t bb = (size_t)b * 192 * HWP;
  int chg[16];
#pragma unroll
  for (int ch = 0; ch < 16; ++ch) chg[ch] = idx[b * 64 + head * 16 + ch];
  // ---- fused staging: one halo position per thread ----
  if (tt < 100) {
    int py = tt / 10, px = tt - py * 10;
    int ky = hi * 8 + py - 1, kx = wj * 8 + px - 1;
    bool ok = (ky >= 0) && (ky < 128) && (kx >= 0) && (kx < 128);
    int sp = ky * 128 + kx;
    float kv[16];
    float s = 0.f;
#pragma unroll
    for (int ch = 0; ch < 16; ++ch) {
      float k = ok ? qkv[bb + (size_t)(64 + chg[ch]) * HWP + sp] : 0.f;
      k += (ch < 8) ? rel_h[(head * 10 + py) * 8 + ch]
                    : rel_w[(head * 10 + px) * 8 + (ch - 8)];
      kv[ch] = k;
      s += k * k;
    }
    float rn = 1.f / fmaxf(sqrtf(s), 1e-12f);     // ref: l2norm(k+rel) pre-dot
#pragma unroll
    for (int ch = 0; ch < 16; ++ch) kr[tt * 16 + ch] = kv[ch] * rn;
#pragma unroll
    for (int ch = 0; ch < 16; ++ch)
      vr[tt * 16 + ch] = ok ? qkv[bb + (size_t)(128 + chg[ch]) * HWP + sp] : 0.f;
  }
  // ---- per-query q (overlaps staging latency) ----
  int qy = hi * 8 + (t >> 3), qx = wj * 8 + (t & 7);
  float q[16];
  float qs = 0.f;
#pragma unroll
  for (int ch = 0; ch < 16; ++ch) {
    q[ch] = qkv[bb + (size_t)chg[ch] * HWP + qy * 128 + qx];
    qs += q[ch] * q[ch];
  }
  float T = expf(temp[head]);
  float qnT = T / fmaxf(sqrtf(qs), 1e-12f);
  __syncthreads();
  // ---- 50 keys per wave, all operands from LDS broadcasts ----
  float out[16];
#pragma unroll
  for (int ch = 0; ch < 16; ++ch) out[ch] = 0.f;
  float wsum = 0.f;
  for (int pyl = 0; pyl < 5; ++pyl) {
    int py = w * 5 + pyl;
    const float* kp0 = kr + py * 160;
    const float* vp0 = vr + py * 160;
    for (int px = 0; px < 10; ++px) {
      const float* kp = kp0 + px * 16;
      const float* vp = vp0 + px * 16;
      float d0 = 0.f, d1 = 0.f, d2 = 0.f, d3 = 0.f;
#pragma unroll
      for (int ch = 0; ch < 4; ++ch) {
        d0 = fmaf(q[ch], kp[ch], d0);
        d1 = fmaf(q[ch + 4], kp[ch + 4], d1);
        d2 = fmaf(q[ch + 8], kp[ch + 8], d2);
        d3 = fmaf(q[ch + 12], kp[ch + 12], d3);
      }
      float dacc = (d0 + d1) + (d2 + d3);
      float e = __expf(fmaf(dacc, qnT, -T));      // exp(d - T): exact softmax shift
      wsum += e;                                  // OOB keys count in denominator
#pragma unroll
      for (int ch = 0; ch < 16; ++ch)
        out[ch] = fmaf(e, vp[ch], out[ch]);       // OOB rows are zero -> no mask
    }
  }
  // ---- cross-wave combine: po/pw overlay the dead kr region ----
  __syncthreads();                 // both waves done reading kr/vr
  float* po = smem;                // [2][16][64] = 2048 floats
  float* pwp = smem + 2048;        // [2][64]
  pwp[w * 64 + t] = wsum;
#pragma unroll
  for (int ch = 0; ch < 16; ++ch) po[(w * 16 + ch) * 64 + t] = out[ch];
  __syncthreads();
  float winv = 1.f / (pwp[t] + pwp[64 + t]);
  int ob = w * 8;                                 // this wave's 8 outputs
#pragma unroll
  for (int i = 0; i < 8; ++i) {
    int o = ob + i;
    float oc = po[o * 64 + t] + po[(16 + o) * 64 + t];
    float gsv = gate_b[head * 16 + o];
#pragma unroll
    for (int c = 0; c < 16; ++c)
      gsv = fmaf(gate_w[head * 256 + o * 16 + c], q[c], gsv);
    float sig = 1.f / (1.f + __expf(-gsv));
    attn_out[((size_t)b * 64 + chg[o]) * HWP + qy * 128 + qx] = oc * winv * sig;
  }
}

// ---------------- 8: mixed -> gating -> down -> up -> (+attn) -> proj ----
// attn now lives in its own buffer: channel c of batch b at (b*64+c)*HWP.
// 256 threads = 4 waves per block, 64 pixels per block (lane = pixel).
// Output channels are SPLIT ACROSS WAVES (16/wave; 8/wave for down).
// Per-channel accumulator chain order (d ascending) unchanged -> bitwise-
// identical results.
__global__ __launch_bounds__(256) void k_post(
    const float* __restrict__ attn, const float* __restrict__ qkv,
    const float* __restrict__ gT, const float* __restrict__ gating_b,
    const float* __restrict__ dT, const float* __restrict__ down_b,
    const float* __restrict__ uT, const float* __restrict__ up_b,
    const float* __restrict__ pT, float* __restrict__ out3) {
  __shared__ float xs[64 * 64];     // [c][pix]
  int t = threadIdx.x;
  int lane = t & 63;                // pixel within block
  int w = t >> 6;                   // wave 0..3 (uniform)
  int p = blockIdx.x * 64 + lane;   // global pooled pixel id
  int b = p >> 14;
  int pix = p & 16383;
  const float* ap = attn + (size_t)b * 64 * HWP + pix;
  const float* qp = qkv + (size_t)b * 192 * HWP + pix;
  float* op = out3 + (size_t)b * 64 * HWP + pix;
  int ob16 = __builtin_amdgcn_readfirstlane(w * 16);
  int ob8  = __builtin_amdgcn_readfirstlane(w * 8);
  // mixed = attn_out + (q + k): each wave loads its 16 channels (concurrent)
#pragma unroll
  for (int i = 0; i < 16; ++i) {
    int c = ob16 + i;
    xs[c * 64 + lane] = ap[(size_t)c * HWP] + qp[(size_t)c * HWP] + qp[(size_t)(64 + c) * HWP];
  }
  __syncthreads();
  // ---- gating conv + exact gelu, * mixed ----
  {
    float acc[16];
#pragma unroll
    for (int o = 0; o < 16; ++o) acc[o] = gating_b[ob16 + o];
    for (int d = 0; d < 64; ++d) {
      float xv = xs[d * 64 + lane];
      const float* wd = gT + d * 64 + ob16;   // wave-uniform -> s_load
#pragma unroll
      for (int o = 0; o < 16; ++o) acc[o] = fmaf(wd[o], xv, acc[o]);
    }
    __syncthreads();                 // all reads done before any overwrite
#pragma unroll
    for (int o = 0; o < 16; ++o) {
      float a = acc[o];
      float ge = 0.5f * a * (1.f + erff(a * 0.70710678118654752f));
      xs[(ob16 + o) * 64 + lane] = ge * xs[(ob16 + o) * 64 + lane];
    }
    __syncthreads();
  }
  // ---- down 64->32 (8 outputs/wave) ----
  {
    float acc[8];
#pragma unroll
    for (int o = 0; o < 8; ++o) acc[o] = down_b[ob8 + o];
    for (int d = 0; d < 64; ++d) {
      float xv = xs[d * 64 + lane];
      const float* wd = dT + d * 32 + ob8;
#pragma unroll
      for (int o = 0; o < 8; ++o) acc[o] = fmaf(wd[o], xv, acc[o]);
    }
    __syncthreads();
#pragma unroll
    for (int o = 0; o < 8; ++o) xs[(ob8 + o) * 64 + lane] = acc[o];
    __syncthreads();
  }
  // ---- up 32->64, + attn residual ----
  {
    float acc[16];
#pragma unroll
    for (int o = 0; o < 16; ++o) acc[o] = up_b[ob16 + o];
    for (int d = 0; d < 32; ++d) {
      float xv = xs[d * 64 + lane];
      const float* wd = uT + d * 64 + ob16;
#pragma unroll
      for (int o = 0; o < 16; ++o) acc[o] = fmaf(wd[o], xv, acc[o]);
    }
    __syncthreads();
#pragma unroll
    for (int o = 0; o < 16; ++o)
      xs[(ob16 + o) * 64 + lane] = acc[o] + ap[(size_t)(ob16 + o) * HWP];
    __syncthreads();
  }
  // ---- proj (no bias) ----
  {
    float acc[16];
#pragma unroll
    for (int o = 0; o < 16; ++o) acc[o] = 0.f;
    for (int d = 0; d < 64; ++d) {
      float xv = xs[d * 64 + lane];
      const float* wd = pT + d * 64 + ob16;
#pragma unroll
      for (int o = 0; o < 16; ++o) acc[o] = fmaf(wd[o], xv, acc[o]);
    }
#pragma unroll
    for (int o = 0; o < 16; ++o) op[(size_t)(ob16 + o) * HWP] = acc[o];
  }
}

// ---------------- 9: dw3x3 reflect + bias + bilinear x2 (align-corners) ----
__global__ __launch_bounds__(256) void k_final(
    const float* __restrict__ out3, const float* __restrict__ lp_w,
    const float* __restrict__ lp_b, float* __restrict__ out) {
  int bi = blockIdx.x;                 // (b*64+ch)*8 + rt
  int rt = bi & 7;
  int bc = bi >> 3;
  int ch = bc & 63;
  int r0 = rt * 16;
  __shared__ float tin[20 * 128];      // input rows r0-2 .. r0+17 (reflected)
  __shared__ float tdw[18 * 128];      // dw rows r0-1 .. r0+16
  int t = threadIdx.x;
  const float* src = out3 + (size_t)bc * HWP;
  for (int i = 0; i < 10; ++i) {
    int f = i * 256 + t;               // 2560 exactly
    int r = f >> 7, xx = f & 127;
    int ry = r0 - 2 + r;
    ry = ry < 0 ? -ry : (ry > 127 ? 254 - ry : ry);
    tin[f] = src[ry * 128 + xx];
  }
  __syncthreads();
  float w0 = lp_w[ch * 9 + 0], w1 = lp_w[ch * 9 + 1], w2 = lp_w[ch * 9 + 2];
  float w3 = lp_w[ch * 9 + 3], w4 = lp_w[ch * 9 + 4], w5 = lp_w[ch * 9 + 5];
  float w6 = lp_w[ch * 9 + 6], w7 = lp_w[ch * 9 + 7], w8 = lp_w[ch * 9 + 8];
  float bias = lp_b[ch];
  for (int i = 0; i < 9; ++i) {
    int f = i * 256 + t;               // 2304 exactly
    int r = f >> 7, xx = f & 127;
    int xm = (xx == 0) ? 1 : xx - 1;
    int xp = (xx == 127) ? 126 : xx + 1;
    const float* r0p = tin + r * 128;
    const float* r1p = r0p + 128;
    const float* r2p = r1p + 128;
    float acc = bias;
    acc = fmaf(w0, r0p[xm], acc); acc = fmaf(w1, r0p[xx], acc); acc = fmaf(w2, r0p[xp], acc);
    acc = fmaf(w3, r1p[xm], acc); acc = fmaf(w4, r1p[xx], acc); acc = fmaf(w5, r1p[xp], acc);
    acc = fmaf(w6, r2p[xm], acc); acc = fmaf(w7, r2p[xx], acc); acc = fmaf(w8, r2p[xp], acc);
    tdw[f] = acc;
  }
  __syncthreads();
  const float s = (float)(127.0 / 255.0);
  float* dst = out + (size_t)bc * 65536;
  for (int i = 0; i < 32; ++i) {
    int f = i * 256 + t;               // 8192 exactly: rows 2r0..2r0+31, cols 0..255
    int vr = f >> 8, vx = f & 255;
    int v = 2 * r0 + vr;
    float cy = (float)v * s;
    int ly = (int)floorf(cy); if (ly > 126) ly = 126;
    float wy = cy - (float)ly;
    float cx = (float)vx * s;
    int lx = (int)floorf(cx); if (lx > 126) lx = 126;
    float wx = cx - (float)lx;
    int lr = ly - r0 + 1;              // tdw row index
    float a  = tdw[lr * 128 + lx];
    float bq = tdw[lr * 128 + lx + 1];
    float c2 = tdw[(lr + 1) * 128 + lx];
    float d2 = tdw[(lr + 1) * 128 + lx + 1];
    float t0 = a  * (1.f - wy) + c2 * wy;   // y-lerp first (matches ref order)
    float t1 = bq * (1.f - wy) + d2 * wy;
    dst[v * 256 + vx] = t0 * (1.f - wx) + t1 * wx;
  }
}

extern "C" void kernel_launch(void* const* d_in, const int* in_sizes, int n_in,
                              void* d_out, int out_size, void* d_ws, size_t ws_size,
                              hipStream_t stream) {
  (void)in_sizes; (void)n_in; (void)out_size; (void)ws_size;
  const float* x        = (const float*)d_in[0];
  const float* qkv_w    = (const float*)d_in[1];
  const float* lce_w    = (const float*)d_in[2];
  const float* gate_w   = (const float*)d_in[3];
  const float* gate_b   = (const float*)d_in[4];
  const float* temp     = (const float*)d_in[5];
  const float* rel_h    = (const float*)d_in[6];
  const float* rel_w    = (const float*)d_in[7];
  const float* down_w   = (const float*)d_in[8];
  const float* down_b   = (const float*)d_in[9];
  const float* up_w     = (const float*)d_in[10];
  const float* up_b     = (const float*)d_in[11];
  const float* gating_w = (const float*)d_in[12];
  const float* gating_b = (const float*)d_in[13];
  const float* proj_w   = (const float*)d_in[14];
  const float* lp_w     = (const float*)d_in[15];
  const float* lp_b     = (const float*)d_in[16];
  float* fws = (float*)d_ws;
  float* outp = (float*)d_out;

  float* pre  = fws + PRE_OFF;
  float* qkv  = fws + QKV_OFF;
  float* attn = fws + ATTN_OFF;
  float* out3 = fws + OUT3_OFF;
  float* covp = fws + COVP_OFF;
  float* mean = fws + MEAN_OFF;
  int* idx = (int*)(fws + IDX_OFF);
  int* inv = (int*)(fws + INV_OFF);
  float* covs = fws + COVS_OFF;
  float* wT   = fws + WT_OFF;
  float* gT   = fws + GT2_OFF;
  float* dT   = fws + DT2_OFF;
  float* uT   = fws + UT2_OFF;
  float* pT   = fws + PT2_OFF;

  k_prep_wt<<<48, 256, 0, stream>>>(qkv_w, wT);
  k_pool_conv<<<1024, 256, 0, stream>>>(x, wT, pre);
  k_dw3x3_zero<<<12288, 256, 0, stream>>>(pre, lce_w, qkv);
  k_prep2<<<16, 256, 0, stream>>>(gating_w, down_w, up_w, proj_w, gT, dT, uT, pT);
  k_mean<<<256, 256, 0, stream>>>(qkv, mean);
  k_covpart<<<512, 256, 0, stream>>>(qkv, mean, covp);
  k_covred<<<64, 256, 0, stream>>>(covp, covs);
  k_simsort<<<4, 256, 0, stream>>>(covs, idx, inv);
  k_attn<<<4096, 128, 0, stream>>>(qkv, idx, rel_h, rel_w, gate_w, gate_b, temp, attn);
  k_post<<<1024, 256, 0, stream>>>(attn, qkv, gT, gating_b, dT, down_b,
                                   uT, up_b, pT, out3);
  k_final<<<2048, 256, 0, stream>>>(out3, lp_w, lp_b, outp);
  (void)inv;
}